// Round 1
// baseline (2306.220 us; speedup 1.0000x reference)
//
#include <hip/hip_runtime.h>

typedef unsigned short u16;
typedef __attribute__((ext_vector_type(8))) short bf16x8;
typedef __attribute__((ext_vector_type(4))) float floatx4;

#define NPIX 625
#define NCAPS 20000
#define K2 9216

__device__ __forceinline__ u16 f2bf(float f) {
  unsigned u = __float_as_uint(f);
  return (u16)((u + 0x7fffu + ((u >> 16) & 1u)) >> 16);
}

#define GLDS16(g, l) __builtin_amdgcn_global_load_lds( \
    (const __attribute__((address_space(1))) void*)(g), \
    (__attribute__((address_space(3))) void*)(l), 16, 0, 0)

// ---------- prep: weights -> bf16, conv2 reordered to [oc][tap][c] ----------
__global__ void prep_weights(const float* __restrict__ w2, const float* __restrict__ w3,
                             u16* __restrict__ A2, u16* __restrict__ A3) {
  int idx = blockIdx.x * 256 + threadIdx.x;
  if (idx < 256 * 36 * 256) {
    int oc = idx / 9216, r = idx % 9216;
    int t = r >> 8, c = r & 255;           // A2[oc][t*256+c] = w2[oc][c][t]
    A2[idx] = f2bf(w2[(oc * 256 + c) * 36 + t]);
  } else {
    int j = idx - 256 * 36 * 256;
    if (j < 256 * 512) A3[j] = f2bf(w3[j]);
  }
}

// ---------- conv1: (B,1,54,54) -> x1p padded NHWC bf16 (B,30,30,256) ----------
__global__ void conv1_kernel(const float* __restrict__ x, const float* __restrict__ w1,
                             const float* __restrict__ b1, u16* __restrict__ x1p) {
  int blk = blockIdx.x;                  // 800 = 32 b * 25 rows
  int b = blk / 25, i = blk % 25;
  int f = threadIdx.x;
  float wreg[36];
#pragma unroll
  for (int k = 0; k < 36; k++) wreg[k] = w1[f * 36 + k];
  float bias = b1[f];
  const float* xb = x + b * 54 * 54 + (2 * i) * 54;
  for (int j = 0; j < 25; j++) {
    float acc = bias;
#pragma unroll
    for (int ki = 0; ki < 6; ki++)
#pragma unroll
      for (int kj = 0; kj < 6; kj++)
        acc = fmaf(xb[ki * 54 + 2 * j + kj], wreg[ki * 6 + kj], acc);
    x1p[(((b * 30 + i + 2) * 30) + (j + 2)) * 256 + f] = f2bf(fmaxf(acc, 0.f));
  }
}

// ---------- conv2 implicit GEMM: M=256(oc) N=20000(pix) K=36*256 ----------
__global__ __launch_bounds__(256) void conv2_gemm(const u16* __restrict__ A2,
    const u16* __restrict__ x1p, const float* __restrict__ bias2, u16* __restrict__ y) {
  __shared__ u16 As[128 * 32];
  __shared__ u16 Bs[128 * 32];
  const int tid = threadIdx.x;
  const int lane = tid & 63, wave = tid >> 6;
  const int mtile = blockIdx.x, ntile = blockIdx.y;

  const int seg0 = tid, seg1 = tid + 256;
  const u16* ga0 = A2 + (mtile * 128 + (seg0 >> 2)) * K2 + (seg0 & 3) * 8;
  const u16* ga1 = A2 + (mtile * 128 + (seg1 >> 2)) * K2 + (seg1 & 3) * 8;

  auto pixbase = [&](int seg) {
    int n = ntile * 128 + (seg >> 2);
    if (n > NCAPS - 1) n = NCAPS - 1;
    int b = n / NPIX, p = n % NPIX;
    int i = p / 25, j = p % 25;
    return ((b * 30 + i) * 30 + j) * 256 + (seg & 3) * 8;
  };
  const u16* gb0 = x1p + pixbase(seg0);
  const u16* gb1 = x1p + pixbase(seg1);

  floatx4 acc[4][4] = {};
  const int wm = wave & 1, wn = wave >> 1;
  const int lrow = lane & 15, kgrp = lane >> 4;

  for (int kc = 0; kc < 288; kc++) {
    int t = kc >> 3, c0 = (kc & 7) * 32;
    int ki = t / 6, kj = t % 6;
    int boff = (ki * 30 + kj) * 256 + c0;
    int aoff = kc * 32;
    GLDS16(ga0 + aoff, As + seg0 * 8);
    GLDS16(ga1 + aoff, As + seg1 * 8);
    GLDS16(gb0 + boff, Bs + seg0 * 8);
    GLDS16(gb1 + boff, Bs + seg1 * 8);
    __syncthreads();
    bf16x8 af[4], bfr[4];
#pragma unroll
    for (int tt = 0; tt < 4; tt++) {
      af[tt]  = *(const bf16x8*)(As + (wm * 64 + tt * 16 + lrow) * 32 + kgrp * 8);
      bfr[tt] = *(const bf16x8*)(Bs + (wn * 64 + tt * 16 + lrow) * 32 + kgrp * 8);
    }
#pragma unroll
    for (int tm = 0; tm < 4; tm++)
#pragma unroll
      for (int tn = 0; tn < 4; tn++)
        acc[tm][tn] = __builtin_amdgcn_mfma_f32_16x16x32_bf16(af[tm], bfr[tn], acc[tm][tn], 0, 0, 0);
    __syncthreads();
  }

  const int nb = ntile * 128 + wn * 64;
  const int ocb = mtile * 128 + wm * 64 + kgrp * 4;
#pragma unroll
  for (int tn = 0; tn < 4; tn++) {
    int n = nb + tn * 16 + lrow;
    if (n < NCAPS) {
#pragma unroll
      for (int tm = 0; tm < 4; tm++) {
        int oc = ocb + tm * 16;
        ushort4 pk;
        pk.x = f2bf(fmaxf(acc[tm][tn][0] + bias2[oc + 0], 0.f));
        pk.y = f2bf(fmaxf(acc[tm][tn][1] + bias2[oc + 1], 0.f));
        pk.z = f2bf(fmaxf(acc[tm][tn][2] + bias2[oc + 2], 0.f));
        pk.w = f2bf(fmaxf(acc[tm][tn][3] + bias2[oc + 3], 0.f));
        *(ushort4*)(y + n * 256 + oc) = pk;
      }
    }
  }
}

// ---------- conv3 1x1 GEMM: M=256(f) N=20000 K=512 (x1 | y) ----------
__global__ __launch_bounds__(256) void conv3_gemm(const u16* __restrict__ A3,
    const u16* __restrict__ x1p, const u16* __restrict__ y,
    const float* __restrict__ bias3, float* __restrict__ z) {
  __shared__ u16 As[128 * 32];
  __shared__ u16 Bs[128 * 32];
  const int tid = threadIdx.x;
  const int lane = tid & 63, wave = tid >> 6;
  const int mtile = blockIdx.x, ntile = blockIdx.y;

  const int seg0 = tid, seg1 = tid + 256;
  const u16* ga0 = A3 + (mtile * 128 + (seg0 >> 2)) * 512 + (seg0 & 3) * 8;
  const u16* ga1 = A3 + (mtile * 128 + (seg1 >> 2)) * 512 + (seg1 & 3) * 8;

  auto mkbases = [&](int seg, const u16*& gx, const u16*& gy) {
    int n = ntile * 128 + (seg >> 2);
    if (n > NCAPS - 1) n = NCAPS - 1;
    int b = n / NPIX, p = n % NPIX;
    int i = p / 25, j = p % 25;
    gx = x1p + ((b * 30 + i + 2) * 30 + (j + 2)) * 256 + (seg & 3) * 8;
    gy = y + n * 256 + (seg & 3) * 8;
  };
  const u16 *gx0, *gy0, *gx1, *gy1;
  mkbases(seg0, gx0, gy0);
  mkbases(seg1, gx1, gy1);

  floatx4 acc[4][4] = {};
  const int wm = wave & 1, wn = wave >> 1;
  const int lrow = lane & 15, kgrp = lane >> 4;

  for (int kc = 0; kc < 16; kc++) {
    const u16* s0 = (kc < 8) ? (gx0 + kc * 32) : (gy0 + (kc - 8) * 32);
    const u16* s1 = (kc < 8) ? (gx1 + kc * 32) : (gy1 + (kc - 8) * 32);
    GLDS16(ga0 + kc * 32, As + seg0 * 8);
    GLDS16(ga1 + kc * 32, As + seg1 * 8);
    GLDS16(s0, Bs + seg0 * 8);
    GLDS16(s1, Bs + seg1 * 8);
    __syncthreads();
    bf16x8 af[4], bfr[4];
#pragma unroll
    for (int tt = 0; tt < 4; tt++) {
      af[tt]  = *(const bf16x8*)(As + (wm * 64 + tt * 16 + lrow) * 32 + kgrp * 8);
      bfr[tt] = *(const bf16x8*)(Bs + (wn * 64 + tt * 16 + lrow) * 32 + kgrp * 8);
    }
#pragma unroll
    for (int tm = 0; tm < 4; tm++)
#pragma unroll
      for (int tn = 0; tn < 4; tn++)
        acc[tm][tn] = __builtin_amdgcn_mfma_f32_16x16x32_bf16(af[tm], bfr[tn], acc[tm][tn], 0, 0, 0);
    __syncthreads();
  }

  const int nb = ntile * 128 + wn * 64;
  const int fb = mtile * 128 + wm * 64 + kgrp * 4;
#pragma unroll
  for (int tn = 0; tn < 4; tn++) {
    int n = nb + tn * 16 + lrow;
    if (n < NCAPS) {
#pragma unroll
      for (int tm = 0; tm < 4; tm++) {
        int f0 = fb + tm * 16;
        float4 v;
        v.x = acc[tm][tn][0] + bias3[f0 + 0];
        v.y = acc[tm][tn][1] + bias3[f0 + 1];
        v.z = acc[tm][tn][2] + bias3[f0 + 2];
        v.w = acc[tm][tn][3] + bias3[f0 + 3];
        *(float4*)(z + n * 256 + f0) = v;
      }
    }
  }
}

// ---------- caps pass 0: u = caps*pc_w + pc_b ; S0 = sum_n u_hat ----------
__global__ void caps_p0(const float* __restrict__ z, const float* __restrict__ pcw,
                        const float* __restrict__ pcb, const float* __restrict__ W,
                        float* __restrict__ u, float* __restrict__ S0g) {
  __shared__ float S[4096];  // [e*16+o][b]
  int tid = threadIdx.x;
  for (int idx = tid; idx < 4096; idx += 256) S[idx] = 0.f;
  __syncthreads();
  int b = tid & 31, s = tid >> 5;
#pragma unroll 1
  for (int it = 0; it < 4; it++) {
    int n = blockIdx.x * 32 + it * 8 + s;
    int g = n / 625, p = n % 625;
    const float* zp = z + (b * 625 + p) * 256 + g * 8;
    float cap[8];
#pragma unroll
    for (int i2 = 0; i2 < 8; i2++) cap[i2] = zp[i2];
    const float* pw = pcw + n * 64;
    float uu[8];
#pragma unroll
    for (int o = 0; o < 8; o++) {
      float a = pcb[n * 8 + o];
#pragma unroll
      for (int i2 = 0; i2 < 8; i2++) a = fmaf(cap[i2], pw[o * 8 + i2], a);
      uu[o] = a;
    }
    float* up = u + (n * 32 + b) * 8;
#pragma unroll
    for (int o = 0; o < 8; o++) up[o] = uu[o];
    const float* Wn = W + n * 1024;
#pragma unroll
    for (int e = 0; e < 8; e++)
#pragma unroll
      for (int o = 0; o < 16; o++) {
        const float* wp = Wn + (e * 16 + o) * 8;
        float a = 0.f;
#pragma unroll
        for (int i2 = 0; i2 < 8; i2++) a = fmaf(uu[i2], wp[i2], a);
        atomicAdd(&S[(e * 16 + o) * 32 + b], a);
      }
  }
  __syncthreads();
  for (int idx = tid; idx < 4096; idx += 256) {
    int eo = idx >> 5, bb = idx & 31;
    atomicAdd(&S0g[bb * 128 + eo], S[idx]);
  }
}

// ---------- caps routing pass (iters 1,2): blog = u_hat . vsum ----------
__global__ void caps_p12(const float* __restrict__ u, const float* __restrict__ W,
                         const float* __restrict__ vsum, float* __restrict__ Sg) {
  __shared__ float S[4096];
  __shared__ float V[4096];  // vsum swizzled [eo][b]
  int tid = threadIdx.x;
  for (int idx = tid; idx < 4096; idx += 256) {
    S[idx] = 0.f;
    int eo = idx >> 5, bb = idx & 31;
    V[idx] = vsum[bb * 128 + eo];
  }
  __syncthreads();
  int b = tid & 31, s = tid >> 5;
#pragma unroll 1
  for (int it = 0; it < 4; it++) {
    int n = blockIdx.x * 32 + it * 8 + s;
    const float* up = u + (n * 32 + b) * 8;
    float uu[8];
#pragma unroll
    for (int i2 = 0; i2 < 8; i2++) uu[i2] = up[i2];
    const float* Wn = W + n * 1024;
    float uh[8][16];
    float blog[8];
#pragma unroll
    for (int e = 0; e < 8; e++) {
      float accv = 0.f;
#pragma unroll
      for (int o = 0; o < 16; o++) {
        const float* wp = Wn + (e * 16 + o) * 8;
        float a = 0.f;
#pragma unroll
        for (int i2 = 0; i2 < 8; i2++) a = fmaf(uu[i2], wp[i2], a);
        uh[e][o] = a;
        accv = fmaf(a, V[(e * 16 + o) * 32 + b], accv);
      }
      blog[e] = accv;
    }
    float m = blog[0];
#pragma unroll
    for (int e = 1; e < 8; e++) m = fmaxf(m, blog[e]);
    float ex[8], sum = 0.f;
#pragma unroll
    for (int e = 0; e < 8; e++) { ex[e] = __expf(blog[e] - m); sum += ex[e]; }
    float inv = 1.f / sum;
#pragma unroll
    for (int e = 0; e < 8; e++) {
      float c = ex[e] * inv;
#pragma unroll
      for (int o = 0; o < 16; o++)
        atomicAdd(&S[(e * 16 + o) * 32 + b], c * uh[e][o]);
    }
  }
  __syncthreads();
  for (int idx = tid; idx < 4096; idx += 256) {
    int eo = idx >> 5, bb = idx & 31;
    atomicAdd(&Sg[bb * 128 + eo], S[idx]);
  }
}

// ---------- squash + vsum update ----------
__global__ void caps_v(const float* __restrict__ Sg, float* __restrict__ vsum,
                       float prescale, int add) {
  int t = threadIdx.x;               // 256 = 32 b * 8 e
  int bb = t >> 3, e = t & 7;
  const float* sp = Sg + bb * 128 + e * 16;
  float sv[16], n2 = 0.f;
#pragma unroll
  for (int o = 0; o < 16; o++) { sv[o] = sp[o] * prescale; n2 = fmaf(sv[o], sv[o], n2); }
  float n = sqrtf(n2);
  float scale = n2 / ((1.f + n2) * (n + 1e-8f));
  float* vp = vsum + bb * 128 + e * 16;
#pragma unroll
  for (int o = 0; o < 16; o++) {
    float vo = sv[o] * scale;
    if (add) vp[o] += vo; else vp[o] = vo;
  }
}

// ---------- final: out = ||squash(S2)|| ----------
__global__ void caps_out(const float* __restrict__ Sg, float* __restrict__ out) {
  int t = threadIdx.x;
  int bb = t >> 3, e = t & 7;
  const float* sp = Sg + bb * 128 + e * 16;
  float n2 = 0.f;
#pragma unroll
  for (int o = 0; o < 16; o++) { float xv = sp[o]; n2 = fmaf(xv, xv, n2); }
  float n = sqrtf(n2);
  out[bb * 8 + e] = n * n2 / ((1.f + n2) * (n + 1e-8f));
}

extern "C" void kernel_launch(void* const* d_in, const int* in_sizes, int n_in,
                              void* d_out, int out_size, void* d_ws, size_t ws_size,
                              hipStream_t stream) {
  const float* x   = (const float*)d_in[0];
  const float* w1  = (const float*)d_in[1];
  const float* b1  = (const float*)d_in[2];
  const float* w2  = (const float*)d_in[3];
  const float* b2  = (const float*)d_in[4];
  const float* w3  = (const float*)d_in[5];
  const float* b3  = (const float*)d_in[6];
  const float* pcw = (const float*)d_in[7];
  const float* pcb = (const float*)d_in[8];
  const float* W   = (const float*)d_in[9];
  float* out = (float*)d_out;

  char* ws = (char*)d_ws;
  u16*   x1p = (u16*)(ws + 0);           // 32*30*30*256 bf16 = 14,745,600
  u16*   A2  = (u16*)(ws + 14745600);    // 256*9216 bf16     =  4,718,592
  u16*   A3  = (u16*)(ws + 19464192);    // 256*512 bf16      =    262,144
  u16*   y   = (u16*)(ws + 19726336);    // 20000*256 bf16    = 10,240,000
  float* z   = (float*)(ws + 29966336);  // 20000*256 f32     = 20,480,000
  float* u   = (float*)(ws + 50446336);  // 20000*32*8 f32    = 20,480,000
  float* S0  = (float*)(ws + 70926336);  // 3 x 16 KB (contiguous)
  float* S1  = (float*)(ws + 70942720);
  float* S2  = (float*)(ws + 70959104);
  float* vs  = (float*)(ws + 70975488);  // 16 KB

  hipMemsetAsync(x1p, 0, 14745600, stream);
  hipMemsetAsync(S0, 0, 3 * 16384, stream);

  prep_weights<<<9728, 256, 0, stream>>>(w2, w3, A2, A3);
  conv1_kernel<<<800, 256, 0, stream>>>(x, w1, b1, x1p);
  conv2_gemm<<<dim3(2, 157), 256, 0, stream>>>(A2, x1p, b2, y);
  conv3_gemm<<<dim3(2, 157), 256, 0, stream>>>(A3, x1p, y, b3, z);
  caps_p0<<<625, 256, 0, stream>>>(z, pcw, pcb, W, u, S0);
  caps_v<<<1, 256, 0, stream>>>(S0, vs, 0.125f, 0);
  caps_p12<<<625, 256, 0, stream>>>(u, W, vs, S1);
  caps_v<<<1, 256, 0, stream>>>(S1, vs, 1.0f, 1);
  caps_p12<<<625, 256, 0, stream>>>(u, W, vs, S2);
  caps_out<<<1, 256, 0, stream>>>(S2, out);
}

// Round 2
// 1915.183 us; speedup vs baseline: 1.2042x; 1.2042x over previous
//
#include <hip/hip_runtime.h>

typedef unsigned short u16;
typedef __attribute__((ext_vector_type(8))) short bf16x8;
typedef __attribute__((ext_vector_type(4))) float floatx4;

#define NPIX 625
#define NCAPS 20000
#define K2 9216

__device__ __forceinline__ u16 f2bf(float f) {
  unsigned u = __float_as_uint(f);
  return (u16)((u + 0x7fffu + ((u >> 16) & 1u)) >> 16);
}

#define GLDS16(g, l) __builtin_amdgcn_global_load_lds( \
    (const __attribute__((address_space(1))) void*)(g), \
    (__attribute__((address_space(3))) void*)(l), 16, 0, 0)

// ---------- prep: weights -> bf16, conv2 reordered to [oc][tap][c] ----------
__global__ void prep_weights(const float* __restrict__ w2, const float* __restrict__ w3,
                             u16* __restrict__ A2, u16* __restrict__ A3) {
  int idx = blockIdx.x * 256 + threadIdx.x;
  if (idx < 256 * 36 * 256) {
    int oc = idx / 9216, r = idx % 9216;
    int t = r >> 8, c = r & 255;           // A2[oc][t*256+c] = w2[oc][c][t]
    A2[idx] = f2bf(w2[(oc * 256 + c) * 36 + t]);
  } else {
    int j = idx - 256 * 36 * 256;
    if (j < 256 * 512) A3[j] = f2bf(w3[j]);
  }
}

// ---------- conv1: (B,1,54,54) -> x1p padded NHWC bf16 (B,30,30,256) ----------
__global__ void conv1_kernel(const float* __restrict__ x, const float* __restrict__ w1,
                             const float* __restrict__ b1, u16* __restrict__ x1p) {
  int blk = blockIdx.x;                  // 800 = 32 b * 25 rows
  int b = blk / 25, i = blk % 25;
  int f = threadIdx.x;
  float wreg[36];
#pragma unroll
  for (int k = 0; k < 36; k++) wreg[k] = w1[f * 36 + k];
  float bias = b1[f];
  const float* xb = x + b * 54 * 54 + (2 * i) * 54;
  for (int j = 0; j < 25; j++) {
    float acc = bias;
#pragma unroll
    for (int ki = 0; ki < 6; ki++)
#pragma unroll
      for (int kj = 0; kj < 6; kj++)
        acc = fmaf(xb[ki * 54 + 2 * j + kj], wreg[ki * 6 + kj], acc);
    x1p[(((b * 30 + i + 2) * 30) + (j + 2)) * 256 + f] = f2bf(fmaxf(acc, 0.f));
  }
}

// ---------- conv2 implicit GEMM: M=256(oc) N=20000(pix) K=36*256 ----------
__global__ __launch_bounds__(256) void conv2_gemm(const u16* __restrict__ A2,
    const u16* __restrict__ x1p, const float* __restrict__ bias2, u16* __restrict__ y) {
  __shared__ u16 As[128 * 32];
  __shared__ u16 Bs[128 * 32];
  const int tid = threadIdx.x;
  const int lane = tid & 63, wave = tid >> 6;
  const int mtile = blockIdx.x, ntile = blockIdx.y;

  const int seg0 = tid, seg1 = tid + 256;
  const u16* ga0 = A2 + (mtile * 128 + (seg0 >> 2)) * K2 + (seg0 & 3) * 8;
  const u16* ga1 = A2 + (mtile * 128 + (seg1 >> 2)) * K2 + (seg1 & 3) * 8;

  auto pixbase = [&](int seg) {
    int n = ntile * 128 + (seg >> 2);
    if (n > NCAPS - 1) n = NCAPS - 1;
    int b = n / NPIX, p = n % NPIX;
    int i = p / 25, j = p % 25;
    return ((b * 30 + i) * 30 + j) * 256 + (seg & 3) * 8;
  };
  const u16* gb0 = x1p + pixbase(seg0);
  const u16* gb1 = x1p + pixbase(seg1);

  floatx4 acc[4][4] = {};
  const int wm = wave & 1, wn = wave >> 1;
  const int lrow = lane & 15, kgrp = lane >> 4;

  for (int kc = 0; kc < 288; kc++) {
    int t = kc >> 3, c0 = (kc & 7) * 32;
    int ki = t / 6, kj = t % 6;
    int boff = (ki * 30 + kj) * 256 + c0;
    int aoff = kc * 32;
    GLDS16(ga0 + aoff, As + seg0 * 8);
    GLDS16(ga1 + aoff, As + seg1 * 8);
    GLDS16(gb0 + boff, Bs + seg0 * 8);
    GLDS16(gb1 + boff, Bs + seg1 * 8);
    __syncthreads();
    bf16x8 af[4], bfr[4];
#pragma unroll
    for (int tt = 0; tt < 4; tt++) {
      af[tt]  = *(const bf16x8*)(As + (wm * 64 + tt * 16 + lrow) * 32 + kgrp * 8);
      bfr[tt] = *(const bf16x8*)(Bs + (wn * 64 + tt * 16 + lrow) * 32 + kgrp * 8);
    }
#pragma unroll
    for (int tm = 0; tm < 4; tm++)
#pragma unroll
      for (int tn = 0; tn < 4; tn++)
        acc[tm][tn] = __builtin_amdgcn_mfma_f32_16x16x32_bf16(af[tm], bfr[tn], acc[tm][tn], 0, 0, 0);
    __syncthreads();
  }

  const int nb = ntile * 128 + wn * 64;
  const int ocb = mtile * 128 + wm * 64 + kgrp * 4;
#pragma unroll
  for (int tn = 0; tn < 4; tn++) {
    int n = nb + tn * 16 + lrow;
    if (n < NCAPS) {
#pragma unroll
      for (int tm = 0; tm < 4; tm++) {
        int oc = ocb + tm * 16;
        ushort4 pk;
        pk.x = f2bf(fmaxf(acc[tm][tn][0] + bias2[oc + 0], 0.f));
        pk.y = f2bf(fmaxf(acc[tm][tn][1] + bias2[oc + 1], 0.f));
        pk.z = f2bf(fmaxf(acc[tm][tn][2] + bias2[oc + 2], 0.f));
        pk.w = f2bf(fmaxf(acc[tm][tn][3] + bias2[oc + 3], 0.f));
        *(ushort4*)(y + n * 256 + oc) = pk;
      }
    }
  }
}

// ---------- conv3 1x1 GEMM: M=256(f) N=20000 K=512 (x1 | y) ----------
__global__ __launch_bounds__(256) void conv3_gemm(const u16* __restrict__ A3,
    const u16* __restrict__ x1p, const u16* __restrict__ y,
    const float* __restrict__ bias3, float* __restrict__ z) {
  __shared__ u16 As[128 * 32];
  __shared__ u16 Bs[128 * 32];
  const int tid = threadIdx.x;
  const int lane = tid & 63, wave = tid >> 6;
  const int mtile = blockIdx.x, ntile = blockIdx.y;

  const int seg0 = tid, seg1 = tid + 256;
  const u16* ga0 = A3 + (mtile * 128 + (seg0 >> 2)) * 512 + (seg0 & 3) * 8;
  const u16* ga1 = A3 + (mtile * 128 + (seg1 >> 2)) * 512 + (seg1 & 3) * 8;

  auto mkbases = [&](int seg, const u16*& gx, const u16*& gy) {
    int n = ntile * 128 + (seg >> 2);
    if (n > NCAPS - 1) n = NCAPS - 1;
    int b = n / NPIX, p = n % NPIX;
    int i = p / 25, j = p % 25;
    gx = x1p + ((b * 30 + i + 2) * 30 + (j + 2)) * 256 + (seg & 3) * 8;
    gy = y + n * 256 + (seg & 3) * 8;
  };
  const u16 *gx0, *gy0, *gx1, *gy1;
  mkbases(seg0, gx0, gy0);
  mkbases(seg1, gx1, gy1);

  floatx4 acc[4][4] = {};
  const int wm = wave & 1, wn = wave >> 1;
  const int lrow = lane & 15, kgrp = lane >> 4;

  for (int kc = 0; kc < 16; kc++) {
    const u16* s0 = (kc < 8) ? (gx0 + kc * 32) : (gy0 + (kc - 8) * 32);
    const u16* s1 = (kc < 8) ? (gx1 + kc * 32) : (gy1 + (kc - 8) * 32);
    GLDS16(ga0 + kc * 32, As + seg0 * 8);
    GLDS16(ga1 + kc * 32, As + seg1 * 8);
    GLDS16(s0, Bs + seg0 * 8);
    GLDS16(s1, Bs + seg1 * 8);
    __syncthreads();
    bf16x8 af[4], bfr[4];
#pragma unroll
    for (int tt = 0; tt < 4; tt++) {
      af[tt]  = *(const bf16x8*)(As + (wm * 64 + tt * 16 + lrow) * 32 + kgrp * 8);
      bfr[tt] = *(const bf16x8*)(Bs + (wn * 64 + tt * 16 + lrow) * 32 + kgrp * 8);
    }
#pragma unroll
    for (int tm = 0; tm < 4; tm++)
#pragma unroll
      for (int tn = 0; tn < 4; tn++)
        acc[tm][tn] = __builtin_amdgcn_mfma_f32_16x16x32_bf16(af[tm], bfr[tn], acc[tm][tn], 0, 0, 0);
    __syncthreads();
  }

  const int nb = ntile * 128 + wn * 64;
  const int fb = mtile * 128 + wm * 64 + kgrp * 4;
#pragma unroll
  for (int tn = 0; tn < 4; tn++) {
    int n = nb + tn * 16 + lrow;
    if (n < NCAPS) {
#pragma unroll
      for (int tm = 0; tm < 4; tm++) {
        int f0 = fb + tm * 16;
        float4 v;
        v.x = acc[tm][tn][0] + bias3[f0 + 0];
        v.y = acc[tm][tn][1] + bias3[f0 + 1];
        v.z = acc[tm][tn][2] + bias3[f0 + 2];
        v.w = acc[tm][tn][3] + bias3[f0 + 3];
        *(float4*)(z + n * 256 + f0) = v;
      }
    }
  }
}

// ============ caps kernels: thread = (b, e); tid = b*8+e ============
// Each thread exclusively owns S[b][e][o=0..15] in registers; no LDS, no
// intra-block atomics. uu gathered via 8-lane shuffles; softmax over e via
// __shfl_xor 1/2/4 within the aligned 8-lane group.

__device__ __forceinline__ float dot8(float4 a0, float4 a1, const float* u8) {
  float s = a0.x * u8[0];
  s = fmaf(a0.y, u8[1], s);
  s = fmaf(a0.z, u8[2], s);
  s = fmaf(a0.w, u8[3], s);
  s = fmaf(a1.x, u8[4], s);
  s = fmaf(a1.y, u8[5], s);
  s = fmaf(a1.z, u8[6], s);
  s = fmaf(a1.w, u8[7], s);
  return s;
}

// pass 0: u = caps*pc_w + pc_b ; S0 = sum_n u_hat  (uniform c folded in later)
__global__ __launch_bounds__(256) void caps_p0(const float* __restrict__ z,
    const float* __restrict__ pcw, const float* __restrict__ pcb,
    const float* __restrict__ W, float* __restrict__ u, float* __restrict__ S0g) {
  const int tid = threadIdx.x;
  const int b = tid >> 3, e = tid & 7;
  const int lane = tid & 63;
  const int gbase = lane & ~7;  // first lane of my 8-lane e-group
  float Sreg[16] = {0.f, 0.f, 0.f, 0.f, 0.f, 0.f, 0.f, 0.f,
                    0.f, 0.f, 0.f, 0.f, 0.f, 0.f, 0.f, 0.f};

  for (int it = 0; it < 32; it++) {
    int n = blockIdx.x * 32 + it;
    int g = n / NPIX, p = n % NPIX;
    // caps[b][n][0..8] from z (same for all 8 e-lanes -> L1 broadcast)
    const float* zp = z + (b * NPIX + p) * 256 + g * 8;
    float4 c0 = *(const float4*)zp;
    float4 c1 = *(const float4*)(zp + 4);
    // my u component: o = e
    const float* pw = pcw + n * 64 + e * 8;
    float4 w0 = *(const float4*)pw;
    float4 w1 = *(const float4*)(pw + 4);
    float cap8[8] = {c0.x, c0.y, c0.z, c0.w, c1.x, c1.y, c1.z, c1.w};
    float myu = pcb[n * 8 + e] + dot8(w0, w1, cap8);
    u[n * 256 + tid] = myu;  // u[n][b][o=e], coalesced
    // gather full uu[0..8] from the 8-lane group
    float uu[8];
#pragma unroll
    for (int i = 0; i < 8; i++) uu[i] = __shfl(myu, gbase + i, 64);
    // uh[o] = uu . W[n][e][o][:]  -> accumulate plain sum (c uniform)
    const float* Wn = W + n * 1024 + e * 128;
#pragma unroll
    for (int o = 0; o < 16; o++) {
      float4 a0 = *(const float4*)(Wn + o * 8);
      float4 a1 = *(const float4*)(Wn + o * 8 + 4);
      Sreg[o] += dot8(a0, a1, uu);
    }
  }
#pragma unroll
  for (int o = 0; o < 16; o++)
    atomicAdd(&S0g[b * 128 + e * 16 + o], Sreg[o]);
}

// passes 1,2: logits = u_hat . vsum ; softmax over e ; S = sum c*u_hat
__global__ __launch_bounds__(256) void caps_p12(const float* __restrict__ u,
    const float* __restrict__ W, const float* __restrict__ vsum,
    float* __restrict__ Sg) {
  const int tid = threadIdx.x;
  const int b = tid >> 3, e = tid & 7;
  const int lane = tid & 63;
  const int gbase = lane & ~7;
  float V[16];
  const float* vp = vsum + b * 128 + e * 16;
#pragma unroll
  for (int o = 0; o < 16; o++) V[o] = vp[o];
  float Sreg[16] = {0.f, 0.f, 0.f, 0.f, 0.f, 0.f, 0.f, 0.f,
                    0.f, 0.f, 0.f, 0.f, 0.f, 0.f, 0.f, 0.f};

  for (int it = 0; it < 32; it++) {
    int n = blockIdx.x * 32 + it;
    float myu = u[n * 256 + tid];  // coalesced
    float uu[8];
#pragma unroll
    for (int i = 0; i < 8; i++) uu[i] = __shfl(myu, gbase + i, 64);
    const float* Wn = W + n * 1024 + e * 128;
    float uh[16];
    float blog = 0.f;
#pragma unroll
    for (int o = 0; o < 16; o++) {
      float4 a0 = *(const float4*)(Wn + o * 8);
      float4 a1 = *(const float4*)(Wn + o * 8 + 4);
      float h = dot8(a0, a1, uu);
      uh[o] = h;
      blog = fmaf(h, V[o], blog);
    }
    // softmax over the 8 e-lanes
    float m = blog;
    m = fmaxf(m, __shfl_xor(m, 1, 64));
    m = fmaxf(m, __shfl_xor(m, 2, 64));
    m = fmaxf(m, __shfl_xor(m, 4, 64));
    float ex = __expf(blog - m);
    float s = ex;
    s += __shfl_xor(s, 1, 64);
    s += __shfl_xor(s, 2, 64);
    s += __shfl_xor(s, 4, 64);
    float c = ex / s;
#pragma unroll
    for (int o = 0; o < 16; o++) Sreg[o] = fmaf(c, uh[o], Sreg[o]);
  }
#pragma unroll
  for (int o = 0; o < 16; o++)
    atomicAdd(&Sg[b * 128 + e * 16 + o], Sreg[o]);
}

// ---------- squash + vsum update ----------
__global__ void caps_v(const float* __restrict__ Sg, float* __restrict__ vsum,
                       float prescale, int add) {
  int t = threadIdx.x;               // 256 = 32 b * 8 e
  int bb = t >> 3, e = t & 7;
  const float* sp = Sg + bb * 128 + e * 16;
  float sv[16], n2 = 0.f;
#pragma unroll
  for (int o = 0; o < 16; o++) { sv[o] = sp[o] * prescale; n2 = fmaf(sv[o], sv[o], n2); }
  float n = sqrtf(n2);
  float scale = n2 / ((1.f + n2) * (n + 1e-8f));
  float* vp = vsum + bb * 128 + e * 16;
#pragma unroll
  for (int o = 0; o < 16; o++) {
    float vo = sv[o] * scale;
    if (add) vp[o] += vo; else vp[o] = vo;
  }
}

// ---------- final: out = ||squash(S2)|| ----------
__global__ void caps_out(const float* __restrict__ Sg, float* __restrict__ out) {
  int t = threadIdx.x;
  int bb = t >> 3, e = t & 7;
  const float* sp = Sg + bb * 128 + e * 16;
  float n2 = 0.f;
#pragma unroll
  for (int o = 0; o < 16; o++) { float xv = sp[o]; n2 = fmaf(xv, xv, n2); }
  float n = sqrtf(n2);
  out[bb * 8 + e] = n * n2 / ((1.f + n2) * (n + 1e-8f));
}

extern "C" void kernel_launch(void* const* d_in, const int* in_sizes, int n_in,
                              void* d_out, int out_size, void* d_ws, size_t ws_size,
                              hipStream_t stream) {
  const float* x   = (const float*)d_in[0];
  const float* w1  = (const float*)d_in[1];
  const float* b1  = (const float*)d_in[2];
  const float* w2  = (const float*)d_in[3];
  const float* b2  = (const float*)d_in[4];
  const float* w3  = (const float*)d_in[5];
  const float* b3  = (const float*)d_in[6];
  const float* pcw = (const float*)d_in[7];
  const float* pcb = (const float*)d_in[8];
  const float* W   = (const float*)d_in[9];
  float* out = (float*)d_out;

  char* ws = (char*)d_ws;
  u16*   x1p = (u16*)(ws + 0);           // 32*30*30*256 bf16 = 14,745,600
  u16*   A2  = (u16*)(ws + 14745600);    // 256*9216 bf16     =  4,718,592
  u16*   A3  = (u16*)(ws + 19464192);    // 256*512 bf16      =    262,144
  u16*   y   = (u16*)(ws + 19726336);    // 20000*256 bf16    = 10,240,000
  float* z   = (float*)(ws + 29966336);  // 20000*256 f32     = 20,480,000
  float* u   = (float*)(ws + 50446336);  // 20000*32*8 f32    = 20,480,000
  float* S0  = (float*)(ws + 70926336);  // 3 x 16 KB (contiguous)
  float* S1  = (float*)(ws + 70942720);
  float* S2  = (float*)(ws + 70959104);
  float* vs  = (float*)(ws + 70975488);  // 16 KB

  hipMemsetAsync(x1p, 0, 14745600, stream);
  hipMemsetAsync(S0, 0, 3 * 16384, stream);

  prep_weights<<<9728, 256, 0, stream>>>(w2, w3, A2, A3);
  conv1_kernel<<<800, 256, 0, stream>>>(x, w1, b1, x1p);
  conv2_gemm<<<dim3(2, 157), 256, 0, stream>>>(A2, x1p, b2, y);
  conv3_gemm<<<dim3(2, 157), 256, 0, stream>>>(A3, x1p, y, b3, z);
  caps_p0<<<625, 256, 0, stream>>>(z, pcw, pcb, W, u, S0);
  caps_v<<<1, 256, 0, stream>>>(S0, vs, 0.125f, 0);
  caps_p12<<<625, 256, 0, stream>>>(u, W, vs, S1);
  caps_v<<<1, 256, 0, stream>>>(S1, vs, 1.0f, 1);
  caps_p12<<<625, 256, 0, stream>>>(u, W, vs, S2);
  caps_out<<<1, 256, 0, stream>>>(S2, out);
}

// Round 3
// 1446.336 us; speedup vs baseline: 1.5945x; 1.3242x over previous
//
#include <hip/hip_runtime.h>

typedef unsigned short u16;
typedef __attribute__((ext_vector_type(8))) short bf16x8;
typedef __attribute__((ext_vector_type(4))) float floatx4;

#define NPIX 625
#define NCAPS 20000
#define K2 9216

__device__ __forceinline__ u16 f2bf(float f) {
  unsigned u = __float_as_uint(f);
  return (u16)((u + 0x7fffu + ((u >> 16) & 1u)) >> 16);
}

#define GLDS16(g, l) __builtin_amdgcn_global_load_lds( \
    (const __attribute__((address_space(1))) void*)(g), \
    (__attribute__((address_space(3))) void*)(l), 16, 0, 0)

// ---------- prep: weights -> bf16, conv2 reordered to [oc][tap][c] ----------
__global__ void prep_weights(const float* __restrict__ w2, const float* __restrict__ w3,
                             u16* __restrict__ A2, u16* __restrict__ A3) {
  int idx = blockIdx.x * 256 + threadIdx.x;
  if (idx < 256 * 36 * 256) {
    int oc = idx / 9216, r = idx % 9216;
    int t = r >> 8, c = r & 255;           // A2[oc][t*256+c] = w2[oc][c][t]
    A2[idx] = f2bf(w2[(oc * 256 + c) * 36 + t]);
  } else {
    int j = idx - 256 * 36 * 256;
    if (j < 256 * 512) A3[j] = f2bf(w3[j]);
  }
}

// ---------- conv1: (B,1,54,54) -> x1p padded NHWC bf16 (B,30,30,256) ----------
__global__ void conv1_kernel(const float* __restrict__ x, const float* __restrict__ w1,
                             const float* __restrict__ b1, u16* __restrict__ x1p) {
  int blk = blockIdx.x;                  // 800 = 32 b * 25 rows
  int b = blk / 25, i = blk % 25;
  int f = threadIdx.x;
  float wreg[36];
#pragma unroll
  for (int k = 0; k < 36; k++) wreg[k] = w1[f * 36 + k];
  float bias = b1[f];
  const float* xb = x + b * 54 * 54 + (2 * i) * 54;
  for (int j = 0; j < 25; j++) {
    float acc = bias;
#pragma unroll
    for (int ki = 0; ki < 6; ki++)
#pragma unroll
      for (int kj = 0; kj < 6; kj++)
        acc = fmaf(xb[ki * 54 + 2 * j + kj], wreg[ki * 6 + kj], acc);
    x1p[(((b * 30 + i + 2) * 30) + (j + 2)) * 256 + f] = f2bf(fmaxf(acc, 0.f));
  }
}

// ---------- conv2 implicit GEMM: M=256(oc) N=20000(pix) K=36*256 ----------
__global__ __launch_bounds__(256) void conv2_gemm(const u16* __restrict__ A2,
    const u16* __restrict__ x1p, const float* __restrict__ bias2, u16* __restrict__ y) {
  __shared__ u16 As[128 * 32];
  __shared__ u16 Bs[128 * 32];
  const int tid = threadIdx.x;
  const int lane = tid & 63, wave = tid >> 6;
  const int mtile = blockIdx.x, ntile = blockIdx.y;

  const int seg0 = tid, seg1 = tid + 256;
  const u16* ga0 = A2 + (mtile * 128 + (seg0 >> 2)) * K2 + (seg0 & 3) * 8;
  const u16* ga1 = A2 + (mtile * 128 + (seg1 >> 2)) * K2 + (seg1 & 3) * 8;

  auto pixbase = [&](int seg) {
    int n = ntile * 128 + (seg >> 2);
    if (n > NCAPS - 1) n = NCAPS - 1;
    int b = n / NPIX, p = n % NPIX;
    int i = p / 25, j = p % 25;
    return ((b * 30 + i) * 30 + j) * 256 + (seg & 3) * 8;
  };
  const u16* gb0 = x1p + pixbase(seg0);
  const u16* gb1 = x1p + pixbase(seg1);

  floatx4 acc[4][4] = {};
  const int wm = wave & 1, wn = wave >> 1;
  const int lrow = lane & 15, kgrp = lane >> 4;

  for (int kc = 0; kc < 288; kc++) {
    int t = kc >> 3, c0 = (kc & 7) * 32;
    int ki = t / 6, kj = t % 6;
    int boff = (ki * 30 + kj) * 256 + c0;
    int aoff = kc * 32;
    GLDS16(ga0 + aoff, As + seg0 * 8);
    GLDS16(ga1 + aoff, As + seg1 * 8);
    GLDS16(gb0 + boff, Bs + seg0 * 8);
    GLDS16(gb1 + boff, Bs + seg1 * 8);
    __syncthreads();
    bf16x8 af[4], bfr[4];
#pragma unroll
    for (int tt = 0; tt < 4; tt++) {
      af[tt]  = *(const bf16x8*)(As + (wm * 64 + tt * 16 + lrow) * 32 + kgrp * 8);
      bfr[tt] = *(const bf16x8*)(Bs + (wn * 64 + tt * 16 + lrow) * 32 + kgrp * 8);
    }
#pragma unroll
    for (int tm = 0; tm < 4; tm++)
#pragma unroll
      for (int tn = 0; tn < 4; tn++)
        acc[tm][tn] = __builtin_amdgcn_mfma_f32_16x16x32_bf16(af[tm], bfr[tn], acc[tm][tn], 0, 0, 0);
    __syncthreads();
  }

  const int nb = ntile * 128 + wn * 64;
  const int ocb = mtile * 128 + wm * 64 + kgrp * 4;
#pragma unroll
  for (int tn = 0; tn < 4; tn++) {
    int n = nb + tn * 16 + lrow;
    if (n < NCAPS) {
#pragma unroll
      for (int tm = 0; tm < 4; tm++) {
        int oc = ocb + tm * 16;
        ushort4 pk;
        pk.x = f2bf(fmaxf(acc[tm][tn][0] + bias2[oc + 0], 0.f));
        pk.y = f2bf(fmaxf(acc[tm][tn][1] + bias2[oc + 1], 0.f));
        pk.z = f2bf(fmaxf(acc[tm][tn][2] + bias2[oc + 2], 0.f));
        pk.w = f2bf(fmaxf(acc[tm][tn][3] + bias2[oc + 3], 0.f));
        *(ushort4*)(y + n * 256 + oc) = pk;
      }
    }
  }
}

// ---------- conv3 1x1 GEMM: M=256(f) N=20000 K=512 (x1 | y) ----------
__global__ __launch_bounds__(256) void conv3_gemm(const u16* __restrict__ A3,
    const u16* __restrict__ x1p, const u16* __restrict__ y,
    const float* __restrict__ bias3, float* __restrict__ z) {
  __shared__ u16 As[128 * 32];
  __shared__ u16 Bs[128 * 32];
  const int tid = threadIdx.x;
  const int lane = tid & 63, wave = tid >> 6;
  const int mtile = blockIdx.x, ntile = blockIdx.y;

  const int seg0 = tid, seg1 = tid + 256;
  const u16* ga0 = A3 + (mtile * 128 + (seg0 >> 2)) * 512 + (seg0 & 3) * 8;
  const u16* ga1 = A3 + (mtile * 128 + (seg1 >> 2)) * 512 + (seg1 & 3) * 8;

  auto mkbases = [&](int seg, const u16*& gx, const u16*& gy) {
    int n = ntile * 128 + (seg >> 2);
    if (n > NCAPS - 1) n = NCAPS - 1;
    int b = n / NPIX, p = n % NPIX;
    int i = p / 25, j = p % 25;
    gx = x1p + ((b * 30 + i + 2) * 30 + (j + 2)) * 256 + (seg & 3) * 8;
    gy = y + n * 256 + (seg & 3) * 8;
  };
  const u16 *gx0, *gy0, *gx1, *gy1;
  mkbases(seg0, gx0, gy0);
  mkbases(seg1, gx1, gy1);

  floatx4 acc[4][4] = {};
  const int wm = wave & 1, wn = wave >> 1;
  const int lrow = lane & 15, kgrp = lane >> 4;

  for (int kc = 0; kc < 16; kc++) {
    const u16* s0 = (kc < 8) ? (gx0 + kc * 32) : (gy0 + (kc - 8) * 32);
    const u16* s1 = (kc < 8) ? (gx1 + kc * 32) : (gy1 + (kc - 8) * 32);
    GLDS16(ga0 + kc * 32, As + seg0 * 8);
    GLDS16(ga1 + kc * 32, As + seg1 * 8);
    GLDS16(s0, Bs + seg0 * 8);
    GLDS16(s1, Bs + seg1 * 8);
    __syncthreads();
    bf16x8 af[4], bfr[4];
#pragma unroll
    for (int tt = 0; tt < 4; tt++) {
      af[tt]  = *(const bf16x8*)(As + (wm * 64 + tt * 16 + lrow) * 32 + kgrp * 8);
      bfr[tt] = *(const bf16x8*)(Bs + (wn * 64 + tt * 16 + lrow) * 32 + kgrp * 8);
    }
#pragma unroll
    for (int tm = 0; tm < 4; tm++)
#pragma unroll
      for (int tn = 0; tn < 4; tn++)
        acc[tm][tn] = __builtin_amdgcn_mfma_f32_16x16x32_bf16(af[tm], bfr[tn], acc[tm][tn], 0, 0, 0);
    __syncthreads();
  }

  const int nb = ntile * 128 + wn * 64;
  const int fb = mtile * 128 + wm * 64 + kgrp * 4;
#pragma unroll
  for (int tn = 0; tn < 4; tn++) {
    int n = nb + tn * 16 + lrow;
    if (n < NCAPS) {
#pragma unroll
      for (int tm = 0; tm < 4; tm++) {
        int f0 = fb + tm * 16;
        float4 v;
        v.x = acc[tm][tn][0] + bias3[f0 + 0];
        v.y = acc[tm][tn][1] + bias3[f0 + 1];
        v.z = acc[tm][tn][2] + bias3[f0 + 2];
        v.w = acc[tm][tn][3] + bias3[f0 + 3];
        *(float4*)(z + n * 256 + f0) = v;
      }
    }
  }
}

// ============ caps section ============
// u layout: u[n][b*8+o]  (n-major, 256 floats per n)
// Routing thread = (b, e), tid = b*8+e. All state in explicit scalars/float4.

__device__ __forceinline__ float dot8v(float4 a0, float4 a1, float4 b0, float4 b1) {
  float s = a0.x * b0.x;
  s = fmaf(a0.y, b0.y, s);
  s = fmaf(a0.z, b0.z, s);
  s = fmaf(a0.w, b0.w, s);
  s = fmaf(a1.x, b1.x, s);
  s = fmaf(a1.y, b1.y, s);
  s = fmaf(a1.z, b1.z, s);
  s = fmaf(a1.w, b1.w, s);
  return s;
}

// u[n][b*8+o] = pcb[n][o] + caps[b][n][:] . pcw[n][o][:]
__global__ void caps_u(const float* __restrict__ z, const float* __restrict__ pcw,
                       const float* __restrict__ pcb, float* __restrict__ u) {
  const int tid = threadIdx.x;
  const int b = tid >> 3, o = tid & 7;
  for (int k = 0; k < 8; k++) {
    const int n = blockIdx.x * 8 + k;
    const int g = n / NPIX, p = n % NPIX;
    const float* zp = z + (b * NPIX + p) * 256 + g * 8;
    float4 c0 = *(const float4*)zp;
    float4 c1 = *(const float4*)(zp + 4);
    const float* pw = pcw + n * 64 + o * 8;
    float4 w0 = *(const float4*)pw;
    float4 w1 = *(const float4*)(pw + 4);
    u[n * 256 + tid] = pcb[n * 8 + o] + dot8v(w0, w1, c0, c1);
  }
}

// one routing accumulation pass: c = softmax_e(u_hat . vsum); Spart += c*u_hat
// pass 0 is the same kernel with vsum == 0 (softmax(0) = 1/8 exactly).
__global__ void caps_acc(const float* __restrict__ u, const float* __restrict__ W,
                         const float* __restrict__ vsum, float* __restrict__ Spart) {
  const int tid = threadIdx.x;
  const int b = tid >> 3, e = tid & 7;
  const float* vp = vsum + tid * 16;
  const float4 V0 = *(const float4*)vp;
  const float4 V1 = *(const float4*)(vp + 4);
  const float4 V2 = *(const float4*)(vp + 8);
  const float4 V3 = *(const float4*)(vp + 12);
  float s0 = 0.f, s1 = 0.f, s2 = 0.f, s3 = 0.f, s4 = 0.f, s5 = 0.f, s6 = 0.f, s7 = 0.f;
  float s8 = 0.f, s9 = 0.f, s10 = 0.f, s11 = 0.f, s12 = 0.f, s13 = 0.f, s14 = 0.f, s15 = 0.f;
  const int n0 = blockIdx.x * 32;
  for (int it = 0; it < 32; it++) {
    const int n = n0 + it;
    const float* un = u + n * 256 + (b << 3);
    const float4 u0 = *(const float4*)un;
    const float4 u1 = *(const float4*)(un + 4);
    const float* Wn = W + n * 1024 + e * 128;
    float h0, h1, h2, h3, h4, h5, h6, h7, h8, h9, h10, h11, h12, h13, h14, h15;
#define OST(o, H) { float4 wa = *(const float4*)(Wn + (o) * 8); \
                    float4 wb = *(const float4*)(Wn + (o) * 8 + 4); \
                    H = dot8v(wa, wb, u0, u1); }
    OST(0, h0)  OST(1, h1)  OST(2, h2)  OST(3, h3)
    OST(4, h4)  OST(5, h5)  OST(6, h6)  OST(7, h7)
    OST(8, h8)  OST(9, h9)  OST(10, h10) OST(11, h11)
    OST(12, h12) OST(13, h13) OST(14, h14) OST(15, h15)
#undef OST
    float blog = h0 * V0.x;
    blog = fmaf(h1, V0.y, blog);  blog = fmaf(h2, V0.z, blog);  blog = fmaf(h3, V0.w, blog);
    blog = fmaf(h4, V1.x, blog);  blog = fmaf(h5, V1.y, blog);  blog = fmaf(h6, V1.z, blog);
    blog = fmaf(h7, V1.w, blog);  blog = fmaf(h8, V2.x, blog);  blog = fmaf(h9, V2.y, blog);
    blog = fmaf(h10, V2.z, blog); blog = fmaf(h11, V2.w, blog); blog = fmaf(h12, V3.x, blog);
    blog = fmaf(h13, V3.y, blog); blog = fmaf(h14, V3.z, blog); blog = fmaf(h15, V3.w, blog);
    // softmax over the 8 e-lanes (aligned group within the wave)
    float m = blog;
    m = fmaxf(m, __shfl_xor(m, 1, 64));
    m = fmaxf(m, __shfl_xor(m, 2, 64));
    m = fmaxf(m, __shfl_xor(m, 4, 64));
    float ex = __expf(blog - m);
    float ss = ex;
    ss += __shfl_xor(ss, 1, 64);
    ss += __shfl_xor(ss, 2, 64);
    ss += __shfl_xor(ss, 4, 64);
    const float c = ex / ss;
    s0 = fmaf(c, h0, s0);   s1 = fmaf(c, h1, s1);   s2 = fmaf(c, h2, s2);   s3 = fmaf(c, h3, s3);
    s4 = fmaf(c, h4, s4);   s5 = fmaf(c, h5, s5);   s6 = fmaf(c, h6, s6);   s7 = fmaf(c, h7, s7);
    s8 = fmaf(c, h8, s8);   s9 = fmaf(c, h9, s9);   s10 = fmaf(c, h10, s10); s11 = fmaf(c, h11, s11);
    s12 = fmaf(c, h12, s12); s13 = fmaf(c, h13, s13); s14 = fmaf(c, h14, s14); s15 = fmaf(c, h15, s15);
  }
  float* Sp = Spart + blockIdx.x * 4096 + tid * 16;
  *(float4*)(Sp + 0)  = make_float4(s0, s1, s2, s3);
  *(float4*)(Sp + 4)  = make_float4(s4, s5, s6, s7);
  *(float4*)(Sp + 8)  = make_float4(s8, s9, s10, s11);
  *(float4*)(Sp + 12) = make_float4(s12, s13, s14, s15);
}

// sum 625 block-partials -> S[4096]
__global__ void caps_red(const float* __restrict__ Spart, float* __restrict__ S) {
  const int j = blockIdx.x * 256 + threadIdx.x;
  float a0 = 0.f, a1 = 0.f, a2 = 0.f, a3 = 0.f;
  int r = 0;
  for (; r + 4 <= 625; r += 4) {
    a0 += Spart[(r + 0) * 4096 + j];
    a1 += Spart[(r + 1) * 4096 + j];
    a2 += Spart[(r + 2) * 4096 + j];
    a3 += Spart[(r + 3) * 4096 + j];
  }
  for (; r < 625; r++) a0 += Spart[r * 4096 + j];
  S[j] = (a0 + a1) + (a2 + a3);
}

// squash(S) and set/accumulate vsum
__global__ void caps_v(const float* __restrict__ S, float* __restrict__ vsum, int add) {
  const int t = threadIdx.x;           // 256 = 32 b x 8 e
  const float* sp = S + t * 16;
  const float4 a0 = *(const float4*)sp;
  const float4 a1 = *(const float4*)(sp + 4);
  const float4 a2 = *(const float4*)(sp + 8);
  const float4 a3 = *(const float4*)(sp + 12);
  float n2 = a0.x * a0.x;
  n2 = fmaf(a0.y, a0.y, n2); n2 = fmaf(a0.z, a0.z, n2); n2 = fmaf(a0.w, a0.w, n2);
  n2 = fmaf(a1.x, a1.x, n2); n2 = fmaf(a1.y, a1.y, n2); n2 = fmaf(a1.z, a1.z, n2); n2 = fmaf(a1.w, a1.w, n2);
  n2 = fmaf(a2.x, a2.x, n2); n2 = fmaf(a2.y, a2.y, n2); n2 = fmaf(a2.z, a2.z, n2); n2 = fmaf(a2.w, a2.w, n2);
  n2 = fmaf(a3.x, a3.x, n2); n2 = fmaf(a3.y, a3.y, n2); n2 = fmaf(a3.z, a3.z, n2); n2 = fmaf(a3.w, a3.w, n2);
  const float n = sqrtf(n2);
  const float scale = n2 / ((1.f + n2) * (n + 1e-8f));
  float* vp = vsum + t * 16;
  float4 o0, o1, o2, o3;
  if (add) {
    o0 = *(float4*)(vp + 0); o1 = *(float4*)(vp + 4); o2 = *(float4*)(vp + 8); o3 = *(float4*)(vp + 12);
  } else {
    o0 = make_float4(0.f, 0.f, 0.f, 0.f); o1 = o0; o2 = o0; o3 = o0;
  }
  o0.x = fmaf(a0.x, scale, o0.x); o0.y = fmaf(a0.y, scale, o0.y);
  o0.z = fmaf(a0.z, scale, o0.z); o0.w = fmaf(a0.w, scale, o0.w);
  o1.x = fmaf(a1.x, scale, o1.x); o1.y = fmaf(a1.y, scale, o1.y);
  o1.z = fmaf(a1.z, scale, o1.z); o1.w = fmaf(a1.w, scale, o1.w);
  o2.x = fmaf(a2.x, scale, o2.x); o2.y = fmaf(a2.y, scale, o2.y);
  o2.z = fmaf(a2.z, scale, o2.z); o2.w = fmaf(a2.w, scale, o2.w);
  o3.x = fmaf(a3.x, scale, o3.x); o3.y = fmaf(a3.y, scale, o3.y);
  o3.z = fmaf(a3.z, scale, o3.z); o3.w = fmaf(a3.w, scale, o3.w);
  *(float4*)(vp + 0) = o0; *(float4*)(vp + 4) = o1;
  *(float4*)(vp + 8) = o2; *(float4*)(vp + 12) = o3;
}

// out[b*8+e] = || squash(S) ||
__global__ void caps_out(const float* __restrict__ S, float* __restrict__ out) {
  const int t = threadIdx.x;
  const float* sp = S + t * 16;
  const float4 a0 = *(const float4*)sp;
  const float4 a1 = *(const float4*)(sp + 4);
  const float4 a2 = *(const float4*)(sp + 8);
  const float4 a3 = *(const float4*)(sp + 12);
  float n2 = a0.x * a0.x;
  n2 = fmaf(a0.y, a0.y, n2); n2 = fmaf(a0.z, a0.z, n2); n2 = fmaf(a0.w, a0.w, n2);
  n2 = fmaf(a1.x, a1.x, n2); n2 = fmaf(a1.y, a1.y, n2); n2 = fmaf(a1.z, a1.z, n2); n2 = fmaf(a1.w, a1.w, n2);
  n2 = fmaf(a2.x, a2.x, n2); n2 = fmaf(a2.y, a2.y, n2); n2 = fmaf(a2.z, a2.z, n2); n2 = fmaf(a2.w, a2.w, n2);
  n2 = fmaf(a3.x, a3.x, n2); n2 = fmaf(a3.y, a3.y, n2); n2 = fmaf(a3.z, a3.z, n2); n2 = fmaf(a3.w, a3.w, n2);
  const float n = sqrtf(n2);
  out[t] = n * n2 / ((1.f + n2) * (n + 1e-8f));
}

extern "C" void kernel_launch(void* const* d_in, const int* in_sizes, int n_in,
                              void* d_out, int out_size, void* d_ws, size_t ws_size,
                              hipStream_t stream) {
  const float* x   = (const float*)d_in[0];
  const float* w1  = (const float*)d_in[1];
  const float* b1  = (const float*)d_in[2];
  const float* w2  = (const float*)d_in[3];
  const float* b2  = (const float*)d_in[4];
  const float* w3  = (const float*)d_in[5];
  const float* b3  = (const float*)d_in[6];
  const float* pcw = (const float*)d_in[7];
  const float* pcb = (const float*)d_in[8];
  const float* W   = (const float*)d_in[9];
  float* out = (float*)d_out;

  char* ws = (char*)d_ws;
  u16*   x1p   = (u16*)(ws + 0);           // 32*30*30*256 bf16 = 14,745,600
  u16*   A2    = (u16*)(ws + 14745600);    // 256*9216 bf16     =  4,718,592
  u16*   A3    = (u16*)(ws + 19464192);    // 256*512 bf16      =    262,144
  u16*   y     = (u16*)(ws + 19726336);    // 20000*256 bf16    = 10,240,000
  float* z     = (float*)(ws + 29966336);  // 20000*256 f32     = 20,480,000
  float* Spart = (float*)(ws + 29966336);  // 625*4096 f32 = 10,240,000 (reuses z; z dead after caps_u)
  float* u     = (float*)(ws + 50446336);  // 20000*32*8 f32    = 20,480,000
  float* S     = (float*)(ws + 70926336);  // 16 KB
  float* vs    = (float*)(ws + 70942720);  // 16 KB

  hipMemsetAsync(x1p, 0, 14745600, stream);
  hipMemsetAsync(vs, 0, 16384, stream);

  prep_weights<<<9728, 256, 0, stream>>>(w2, w3, A2, A3);
  conv1_kernel<<<800, 256, 0, stream>>>(x, w1, b1, x1p);
  conv2_gemm<<<dim3(2, 157), 256, 0, stream>>>(A2, x1p, b2, y);
  conv3_gemm<<<dim3(2, 157), 256, 0, stream>>>(A3, x1p, y, b3, z);
  caps_u<<<2500, 256, 0, stream>>>(z, pcw, pcb, u);

  caps_acc<<<625, 256, 0, stream>>>(u, W, vs, Spart);   // pass 0 (vs == 0 -> c = 1/8)
  caps_red<<<16, 256, 0, stream>>>(Spart, S);
  caps_v<<<1, 256, 0, stream>>>(S, vs, 0);

  caps_acc<<<625, 256, 0, stream>>>(u, W, vs, Spart);   // pass 1
  caps_red<<<16, 256, 0, stream>>>(Spart, S);
  caps_v<<<1, 256, 0, stream>>>(S, vs, 1);

  caps_acc<<<625, 256, 0, stream>>>(u, W, vs, Spart);   // pass 2
  caps_red<<<16, 256, 0, stream>>>(Spart, S);
  caps_out<<<1, 256, 0, stream>>>(S, out);
}

// Round 5
// 950.595 us; speedup vs baseline: 2.4261x; 1.5215x over previous
//
#include <hip/hip_runtime.h>

typedef unsigned short u16;
typedef __attribute__((ext_vector_type(8))) short bf16x8;
typedef __attribute__((ext_vector_type(4))) float floatx4;

#define NPIX 625
#define NCAPS 20000
#define K2 9216

__device__ __forceinline__ u16 f2bf(float f) {
  unsigned u = __float_as_uint(f);
  return (u16)((u + 0x7fffu + ((u >> 16) & 1u)) >> 16);
}

#define GLDS16(g, l) __builtin_amdgcn_global_load_lds( \
    (const __attribute__((address_space(1))) void*)(g), \
    (__attribute__((address_space(3))) void*)(l), 16, 0, 0)

// ---------- prep: weights -> bf16, conv2 reordered to [oc][tap][c] ----------
__global__ void prep_weights(const float* __restrict__ w2, const float* __restrict__ w3,
                             u16* __restrict__ A2, u16* __restrict__ A3) {
  int idx = blockIdx.x * 256 + threadIdx.x;
  if (idx < 256 * 36 * 256) {
    int oc = idx / 9216, r = idx % 9216;
    int t = r >> 8, c = r & 255;           // A2[oc][t*256+c] = w2[oc][c][t]
    A2[idx] = f2bf(w2[(oc * 256 + c) * 36 + t]);
  } else {
    int j = idx - 256 * 36 * 256;
    if (j < 256 * 512) A3[j] = f2bf(w3[j]);
  }
}

// ---------- prep: routing weights W (fp32) -> Wb (bf16), same layout ----------
__global__ void prep_wb(const float* __restrict__ W, u16* __restrict__ Wb) {
  int idx = blockIdx.x * 256 + threadIdx.x;  // one thread per 4 elements
  const float4 v = *(const float4*)(W + idx * 4);
  ushort4 p;
  p.x = f2bf(v.x); p.y = f2bf(v.y); p.z = f2bf(v.z); p.w = f2bf(v.w);
  *(ushort4*)(Wb + idx * 4) = p;
}

// ---------- conv1: (B,1,54,54) -> x1p padded NHWC bf16 (B,30,30,256) ----------
__global__ void conv1_kernel(const float* __restrict__ x, const float* __restrict__ w1,
                             const float* __restrict__ b1, u16* __restrict__ x1p) {
  int blk = blockIdx.x;                  // 800 = 32 b * 25 rows
  int b = blk / 25, i = blk % 25;
  int f = threadIdx.x;
  float wreg[36];
#pragma unroll
  for (int k = 0; k < 36; k++) wreg[k] = w1[f * 36 + k];
  float bias = b1[f];
  const float* xb = x + b * 54 * 54 + (2 * i) * 54;
  for (int j = 0; j < 25; j++) {
    float acc = bias;
#pragma unroll
    for (int ki = 0; ki < 6; ki++)
#pragma unroll
      for (int kj = 0; kj < 6; kj++)
        acc = fmaf(xb[ki * 54 + 2 * j + kj], wreg[ki * 6 + kj], acc);
    x1p[(((b * 30 + i + 2) * 30) + (j + 2)) * 256 + f] = f2bf(fmaxf(acc, 0.f));
  }
}

// ---------- conv2 implicit GEMM: M=256(oc) N=20000(pix) K=36*256 ----------
__global__ __launch_bounds__(256) void conv2_gemm(const u16* __restrict__ A2,
    const u16* __restrict__ x1p, const float* __restrict__ bias2, u16* __restrict__ y) {
  __shared__ u16 As[128 * 32];
  __shared__ u16 Bs[128 * 32];
  const int tid = threadIdx.x;
  const int lane = tid & 63, wave = tid >> 6;
  const int mtile = blockIdx.x, ntile = blockIdx.y;

  const int seg0 = tid, seg1 = tid + 256;
  const u16* ga0 = A2 + (mtile * 128 + (seg0 >> 2)) * K2 + (seg0 & 3) * 8;
  const u16* ga1 = A2 + (mtile * 128 + (seg1 >> 2)) * K2 + (seg1 & 3) * 8;

  auto pixbase = [&](int seg) {
    int n = ntile * 128 + (seg >> 2);
    if (n > NCAPS - 1) n = NCAPS - 1;
    int b = n / NPIX, p = n % NPIX;
    int i = p / 25, j = p % 25;
    return ((b * 30 + i) * 30 + j) * 256 + (seg & 3) * 8;
  };
  const u16* gb0 = x1p + pixbase(seg0);
  const u16* gb1 = x1p + pixbase(seg1);

  floatx4 acc[4][4] = {};
  const int wm = wave & 1, wn = wave >> 1;
  const int lrow = lane & 15, kgrp = lane >> 4;

  for (int kc = 0; kc < 288; kc++) {
    int t = kc >> 3, c0 = (kc & 7) * 32;
    int ki = t / 6, kj = t % 6;
    int boff = (ki * 30 + kj) * 256 + c0;
    int aoff = kc * 32;
    GLDS16(ga0 + aoff, As + seg0 * 8);
    GLDS16(ga1 + aoff, As + seg1 * 8);
    GLDS16(gb0 + boff, Bs + seg0 * 8);
    GLDS16(gb1 + boff, Bs + seg1 * 8);
    __syncthreads();
    bf16x8 af[4], bfr[4];
#pragma unroll
    for (int tt = 0; tt < 4; tt++) {
      af[tt]  = *(const bf16x8*)(As + (wm * 64 + tt * 16 + lrow) * 32 + kgrp * 8);
      bfr[tt] = *(const bf16x8*)(Bs + (wn * 64 + tt * 16 + lrow) * 32 + kgrp * 8);
    }
#pragma unroll
    for (int tm = 0; tm < 4; tm++)
#pragma unroll
      for (int tn = 0; tn < 4; tn++)
        acc[tm][tn] = __builtin_amdgcn_mfma_f32_16x16x32_bf16(af[tm], bfr[tn], acc[tm][tn], 0, 0, 0);
    __syncthreads();
  }

  const int nb = ntile * 128 + wn * 64;
  const int ocb = mtile * 128 + wm * 64 + kgrp * 4;
#pragma unroll
  for (int tn = 0; tn < 4; tn++) {
    int n = nb + tn * 16 + lrow;
    if (n < NCAPS) {
#pragma unroll
      for (int tm = 0; tm < 4; tm++) {
        int oc = ocb + tm * 16;
        ushort4 pk;
        pk.x = f2bf(fmaxf(acc[tm][tn][0] + bias2[oc + 0], 0.f));
        pk.y = f2bf(fmaxf(acc[tm][tn][1] + bias2[oc + 1], 0.f));
        pk.z = f2bf(fmaxf(acc[tm][tn][2] + bias2[oc + 2], 0.f));
        pk.w = f2bf(fmaxf(acc[tm][tn][3] + bias2[oc + 3], 0.f));
        *(ushort4*)(y + n * 256 + oc) = pk;
      }
    }
  }
}

// ---------- conv3 1x1 GEMM: M=256(f) N=20000 K=512 (x1 | y) ----------
__global__ __launch_bounds__(256) void conv3_gemm(const u16* __restrict__ A3,
    const u16* __restrict__ x1p, const u16* __restrict__ y,
    const float* __restrict__ bias3, float* __restrict__ z) {
  __shared__ u16 As[128 * 32];
  __shared__ u16 Bs[128 * 32];
  const int tid = threadIdx.x;
  const int lane = tid & 63, wave = tid >> 6;
  const int mtile = blockIdx.x, ntile = blockIdx.y;

  const int seg0 = tid, seg1 = tid + 256;
  const u16* ga0 = A3 + (mtile * 128 + (seg0 >> 2)) * 512 + (seg0 & 3) * 8;
  const u16* ga1 = A3 + (mtile * 128 + (seg1 >> 2)) * 512 + (seg1 & 3) * 8;

  auto mkbases = [&](int seg, const u16*& gx, const u16*& gy) {
    int n = ntile * 128 + (seg >> 2);
    if (n > NCAPS - 1) n = NCAPS - 1;
    int b = n / NPIX, p = n % NPIX;
    int i = p / 25, j = p % 25;
    gx = x1p + ((b * 30 + i + 2) * 30 + (j + 2)) * 256 + (seg & 3) * 8;
    gy = y + n * 256 + (seg & 3) * 8;
  };
  const u16 *gx0, *gy0, *gx1, *gy1;
  mkbases(seg0, gx0, gy0);
  mkbases(seg1, gx1, gy1);

  floatx4 acc[4][4] = {};
  const int wm = wave & 1, wn = wave >> 1;
  const int lrow = lane & 15, kgrp = lane >> 4;

  for (int kc = 0; kc < 16; kc++) {
    const u16* s0 = (kc < 8) ? (gx0 + kc * 32) : (gy0 + (kc - 8) * 32);
    const u16* s1 = (kc < 8) ? (gx1 + kc * 32) : (gy1 + (kc - 8) * 32);
    GLDS16(ga0 + kc * 32, As + seg0 * 8);
    GLDS16(ga1 + kc * 32, As + seg1 * 8);
    GLDS16(s0, Bs + seg0 * 8);
    GLDS16(s1, Bs + seg1 * 8);
    __syncthreads();
    bf16x8 af[4], bfr[4];
#pragma unroll
    for (int tt = 0; tt < 4; tt++) {
      af[tt]  = *(const bf16x8*)(As + (wm * 64 + tt * 16 + lrow) * 32 + kgrp * 8);
      bfr[tt] = *(const bf16x8*)(Bs + (wn * 64 + tt * 16 + lrow) * 32 + kgrp * 8);
    }
#pragma unroll
    for (int tm = 0; tm < 4; tm++)
#pragma unroll
      for (int tn = 0; tn < 4; tn++)
        acc[tm][tn] = __builtin_amdgcn_mfma_f32_16x16x32_bf16(af[tm], bfr[tn], acc[tm][tn], 0, 0, 0);
    __syncthreads();
  }

  const int nb = ntile * 128 + wn * 64;
  const int fb = mtile * 128 + wm * 64 + kgrp * 4;
#pragma unroll
  for (int tn = 0; tn < 4; tn++) {
    int n = nb + tn * 16 + lrow;
    if (n < NCAPS) {
#pragma unroll
      for (int tm = 0; tm < 4; tm++) {
        int f0 = fb + tm * 16;
        float4 v;
        v.x = acc[tm][tn][0] + bias3[f0 + 0];
        v.y = acc[tm][tn][1] + bias3[f0 + 1];
        v.z = acc[tm][tn][2] + bias3[f0 + 2];
        v.w = acc[tm][tn][3] + bias3[f0 + 3];
        *(float4*)(z + n * 256 + f0) = v;
      }
    }
  }
}

// ============ caps section ============
// u layout: u[n][b*8+o]  (n-major, 256 floats per n)
// Routing thread = (b, e), tid = b*8+e.

__device__ __forceinline__ float dot8v(float4 a0, float4 a1, float4 b0, float4 b1) {
  float s = a0.x * b0.x;
  s = fmaf(a0.y, b0.y, s);
  s = fmaf(a0.z, b0.z, s);
  s = fmaf(a0.w, b0.w, s);
  s = fmaf(a1.x, b1.x, s);
  s = fmaf(a1.y, b1.y, s);
  s = fmaf(a1.z, b1.z, s);
  s = fmaf(a1.w, b1.w, s);
  return s;
}

// bf16 row (8 elements packed in uint4) dot fp32 u
__device__ __forceinline__ float dotrow(uint4 w, float4 ua, float4 ub) {
  float s = __uint_as_float(w.x << 16) * ua.x;
  s = fmaf(__uint_as_float(w.x & 0xffff0000u), ua.y, s);
  s = fmaf(__uint_as_float(w.y << 16), ua.z, s);
  s = fmaf(__uint_as_float(w.y & 0xffff0000u), ua.w, s);
  s = fmaf(__uint_as_float(w.z << 16), ub.x, s);
  s = fmaf(__uint_as_float(w.z & 0xffff0000u), ub.y, s);
  s = fmaf(__uint_as_float(w.w << 16), ub.z, s);
  s = fmaf(__uint_as_float(w.w & 0xffff0000u), ub.w, s);
  return s;
}

// u[n][b*8+o] = pcb[n][o] + caps[b][n][:] . pcw[n][o][:]
__global__ void caps_u(const float* __restrict__ z, const float* __restrict__ pcw,
                       const float* __restrict__ pcb, float* __restrict__ u) {
  const int tid = threadIdx.x;
  const int b = tid >> 3, o = tid & 7;
  for (int k = 0; k < 8; k++) {
    const int n = blockIdx.x * 8 + k;
    const int g = n / NPIX, p = n % NPIX;
    const float* zp = z + (b * NPIX + p) * 256 + g * 8;
    float4 c0 = *(const float4*)zp;
    float4 c1 = *(const float4*)(zp + 4);
    const float* pw = pcw + n * 64 + o * 8;
    float4 w0 = *(const float4*)pw;
    float4 w1 = *(const float4*)(pw + 4);
    u[n * 256 + tid] = pcb[n * 8 + o] + dot8v(w0, w1, c0, c1);
  }
}

// ---- routing pass, bf16 W: c = softmax_e(u_hat.vsum); Spart += c*u_hat ----
__global__ __launch_bounds__(256) void caps_accb(const float* __restrict__ u,
    const u16* __restrict__ Wb, const float* __restrict__ vsum,
    float* __restrict__ Spart) {
  const int tid = threadIdx.x;
  const int b = tid >> 3;
  const float* vp = vsum + tid * 16;
  const float4 V0 = *(const float4*)vp;
  const float4 V1 = *(const float4*)(vp + 4);
  const float4 V2 = *(const float4*)(vp + 8);
  const float4 V3 = *(const float4*)(vp + 12);
  float s0 = 0.f, s1 = 0.f, s2 = 0.f, s3 = 0.f, s4 = 0.f, s5 = 0.f, s6 = 0.f, s7 = 0.f;
  float s8 = 0.f, s9 = 0.f, s10 = 0.f, s11 = 0.f, s12 = 0.f, s13 = 0.f, s14 = 0.f, s15 = 0.f;
  const int n0 = blockIdx.x * 16;
  // preload u for first n
  const float* un = u + n0 * 256 + (b << 3);
  float4 u0 = *(const float4*)un;
  float4 u1 = *(const float4*)(un + 4);
  for (int it = 0; it < 16; it++) {
    const int n = n0 + it;
    const u16* Wn = Wb + n * 1024 + (tid & 7) * 128;
    // issue ALL 16 row loads up front (forces MLP)
    uint4 w0  = *(const uint4*)(Wn + 0);
    uint4 w1  = *(const uint4*)(Wn + 8);
    uint4 w2  = *(const uint4*)(Wn + 16);
    uint4 w3  = *(const uint4*)(Wn + 24);
    uint4 w4  = *(const uint4*)(Wn + 32);
    uint4 w5  = *(const uint4*)(Wn + 40);
    uint4 w6  = *(const uint4*)(Wn + 48);
    uint4 w7  = *(const uint4*)(Wn + 56);
    uint4 w8  = *(const uint4*)(Wn + 64);
    uint4 w9  = *(const uint4*)(Wn + 72);
    uint4 w10 = *(const uint4*)(Wn + 80);
    uint4 w11 = *(const uint4*)(Wn + 88);
    uint4 w12 = *(const uint4*)(Wn + 96);
    uint4 w13 = *(const uint4*)(Wn + 104);
    uint4 w14 = *(const uint4*)(Wn + 112);
    uint4 w15 = *(const uint4*)(Wn + 120);
    // prefetch next n's u
    const int np = (it < 15) ? (n + 1) : n;
    const float* unp = u + np * 256 + (b << 3);
    const float4 p0 = *(const float4*)unp;
    const float4 p1 = *(const float4*)(unp + 4);

    const float h0  = dotrow(w0, u0, u1);
    const float h1  = dotrow(w1, u0, u1);
    const float h2  = dotrow(w2, u0, u1);
    const float h3  = dotrow(w3, u0, u1);
    const float h4  = dotrow(w4, u0, u1);
    const float h5  = dotrow(w5, u0, u1);
    const float h6  = dotrow(w6, u0, u1);
    const float h7  = dotrow(w7, u0, u1);
    const float h8  = dotrow(w8, u0, u1);
    const float h9  = dotrow(w9, u0, u1);
    const float h10 = dotrow(w10, u0, u1);
    const float h11 = dotrow(w11, u0, u1);
    const float h12 = dotrow(w12, u0, u1);
    const float h13 = dotrow(w13, u0, u1);
    const float h14 = dotrow(w14, u0, u1);
    const float h15 = dotrow(w15, u0, u1);

    float blog = h0 * V0.x;
    blog = fmaf(h1, V0.y, blog);  blog = fmaf(h2, V0.z, blog);  blog = fmaf(h3, V0.w, blog);
    blog = fmaf(h4, V1.x, blog);  blog = fmaf(h5, V1.y, blog);  blog = fmaf(h6, V1.z, blog);
    blog = fmaf(h7, V1.w, blog);  blog = fmaf(h8, V2.x, blog);  blog = fmaf(h9, V2.y, blog);
    blog = fmaf(h10, V2.z, blog); blog = fmaf(h11, V2.w, blog); blog = fmaf(h12, V3.x, blog);
    blog = fmaf(h13, V3.y, blog); blog = fmaf(h14, V3.z, blog); blog = fmaf(h15, V3.w, blog);
    float m = blog;
    m = fmaxf(m, __shfl_xor(m, 1, 64));
    m = fmaxf(m, __shfl_xor(m, 2, 64));
    m = fmaxf(m, __shfl_xor(m, 4, 64));
    float ex = __expf(blog - m);
    float ss = ex;
    ss += __shfl_xor(ss, 1, 64);
    ss += __shfl_xor(ss, 2, 64);
    ss += __shfl_xor(ss, 4, 64);
    const float c = ex / ss;
    s0 = fmaf(c, h0, s0);   s1 = fmaf(c, h1, s1);   s2 = fmaf(c, h2, s2);   s3 = fmaf(c, h3, s3);
    s4 = fmaf(c, h4, s4);   s5 = fmaf(c, h5, s5);   s6 = fmaf(c, h6, s6);   s7 = fmaf(c, h7, s7);
    s8 = fmaf(c, h8, s8);   s9 = fmaf(c, h9, s9);   s10 = fmaf(c, h10, s10); s11 = fmaf(c, h11, s11);
    s12 = fmaf(c, h12, s12); s13 = fmaf(c, h13, s13); s14 = fmaf(c, h14, s14); s15 = fmaf(c, h15, s15);
    u0 = p0; u1 = p1;
  }
  float* Sp = Spart + blockIdx.x * 4096 + tid * 16;
  *(float4*)(Sp + 0)  = make_float4(s0, s1, s2, s3);
  *(float4*)(Sp + 4)  = make_float4(s4, s5, s6, s7);
  *(float4*)(Sp + 8)  = make_float4(s8, s9, s10, s11);
  *(float4*)(Sp + 12) = make_float4(s12, s13, s14, s15);
}

// ---- routing pass, fp32 W fallback (used when ws too small for Wb) ----
__global__ __launch_bounds__(256) void caps_acc(const float* __restrict__ u,
    const float* __restrict__ W, const float* __restrict__ vsum,
    float* __restrict__ Spart) {
  const int tid = threadIdx.x;
  const int b = tid >> 3, e = tid & 7;
  const float* vp = vsum + tid * 16;
  const float4 V0 = *(const float4*)vp;
  const float4 V1 = *(const float4*)(vp + 4);
  const float4 V2 = *(const float4*)(vp + 8);
  const float4 V3 = *(const float4*)(vp + 12);
  float s0 = 0.f, s1 = 0.f, s2 = 0.f, s3 = 0.f, s4 = 0.f, s5 = 0.f, s6 = 0.f, s7 = 0.f;
  float s8 = 0.f, s9 = 0.f, s10 = 0.f, s11 = 0.f, s12 = 0.f, s13 = 0.f, s14 = 0.f, s15 = 0.f;
  const int n0 = blockIdx.x * 16;
  for (int it = 0; it < 16; it++) {
    const int n = n0 + it;
    const float* un = u + n * 256 + (b << 3);
    const float4 u0 = *(const float4*)un;
    const float4 u1 = *(const float4*)(un + 4);
    const float* Wn = W + n * 1024 + e * 128;
    float h0, h1, h2, h3, h4, h5, h6, h7, h8, h9, h10, h11, h12, h13, h14, h15;
#define OST(o, H) { float4 wa = *(const float4*)(Wn + (o) * 8); \
                    float4 wb = *(const float4*)(Wn + (o) * 8 + 4); \
                    H = dot8v(wa, wb, u0, u1); }
    OST(0, h0)  OST(1, h1)  OST(2, h2)  OST(3, h3)
    OST(4, h4)  OST(5, h5)  OST(6, h6)  OST(7, h7)
    OST(8, h8)  OST(9, h9)  OST(10, h10) OST(11, h11)
    OST(12, h12) OST(13, h13) OST(14, h14) OST(15, h15)
#undef OST
    float blog = h0 * V0.x;
    blog = fmaf(h1, V0.y, blog);  blog = fmaf(h2, V0.z, blog);  blog = fmaf(h3, V0.w, blog);
    blog = fmaf(h4, V1.x, blog);  blog = fmaf(h5, V1.y, blog);  blog = fmaf(h6, V1.z, blog);
    blog = fmaf(h7, V1.w, blog);  blog = fmaf(h8, V2.x, blog);  blog = fmaf(h9, V2.y, blog);
    blog = fmaf(h10, V2.z, blog); blog = fmaf(h11, V2.w, blog); blog = fmaf(h12, V3.x, blog);
    blog = fmaf(h13, V3.y, blog); blog = fmaf(h14, V3.z, blog); blog = fmaf(h15, V3.w, blog);
    float m = blog;
    m = fmaxf(m, __shfl_xor(m, 1, 64));
    m = fmaxf(m, __shfl_xor(m, 2, 64));
    m = fmaxf(m, __shfl_xor(m, 4, 64));
    float ex = __expf(blog - m);
    float ss = ex;
    ss += __shfl_xor(ss, 1, 64);
    ss += __shfl_xor(ss, 2, 64);
    ss += __shfl_xor(ss, 4, 64);
    const float c = ex / ss;
    s0 = fmaf(c, h0, s0);   s1 = fmaf(c, h1, s1);   s2 = fmaf(c, h2, s2);   s3 = fmaf(c, h3, s3);
    s4 = fmaf(c, h4, s4);   s5 = fmaf(c, h5, s5);   s6 = fmaf(c, h6, s6);   s7 = fmaf(c, h7, s7);
    s8 = fmaf(c, h8, s8);   s9 = fmaf(c, h9, s9);   s10 = fmaf(c, h10, s10); s11 = fmaf(c, h11, s11);
    s12 = fmaf(c, h12, s12); s13 = fmaf(c, h13, s13); s14 = fmaf(c, h14, s14); s15 = fmaf(c, h15, s15);
  }
  float* Sp = Spart + blockIdx.x * 4096 + tid * 16;
  *(float4*)(Sp + 0)  = make_float4(s0, s1, s2, s3);
  *(float4*)(Sp + 4)  = make_float4(s4, s5, s6, s7);
  *(float4*)(Sp + 8)  = make_float4(s8, s9, s10, s11);
  *(float4*)(Sp + 12) = make_float4(s12, s13, s14, s15);
}

// sum 1250 block-partials -> S[4096]
__global__ void caps_red(const float* __restrict__ Spart, float* __restrict__ S) {
  const int j = blockIdx.x * 256 + threadIdx.x;
  float a0 = 0.f, a1 = 0.f, a2 = 0.f, a3 = 0.f;
  int r = 0;
  for (; r + 4 <= 1250; r += 4) {
    a0 += Spart[(r + 0) * 4096 + j];
    a1 += Spart[(r + 1) * 4096 + j];
    a2 += Spart[(r + 2) * 4096 + j];
    a3 += Spart[(r + 3) * 4096 + j];
  }
  for (; r < 1250; r++) a0 += Spart[r * 4096 + j];
  S[j] = (a0 + a1) + (a2 + a3);
}

// squash(S) and set/accumulate vsum
__global__ void caps_v(const float* __restrict__ S, float* __restrict__ vsum, int add) {
  const int t = threadIdx.x;           // 256 = 32 b x 8 e
  const float* sp = S + t * 16;
  const float4 a0 = *(const float4*)sp;
  const float4 a1 = *(const float4*)(sp + 4);
  const float4 a2 = *(const float4*)(sp + 8);
  const float4 a3 = *(const float4*)(sp + 12);
  float n2 = a0.x * a0.x;
  n2 = fmaf(a0.y, a0.y, n2); n2 = fmaf(a0.z, a0.z, n2); n2 = fmaf(a0.w, a0.w, n2);
  n2 = fmaf(a1.x, a1.x, n2); n2 = fmaf(a1.y, a1.y, n2); n2 = fmaf(a1.z, a1.z, n2); n2 = fmaf(a1.w, a1.w, n2);
  n2 = fmaf(a2.x, a2.x, n2); n2 = fmaf(a2.y, a2.y, n2); n2 = fmaf(a2.z, a2.z, n2); n2 = fmaf(a2.w, a2.w, n2);
  n2 = fmaf(a3.x, a3.x, n2); n2 = fmaf(a3.y, a3.y, n2); n2 = fmaf(a3.z, a3.z, n2); n2 = fmaf(a3.w, a3.w, n2);
  const float n = sqrtf(n2);
  const float scale = n2 / ((1.f + n2) * (n + 1e-8f));
  float* vp = vsum + t * 16;
  float4 o0, o1, o2, o3;
  if (add) {
    o0 = *(float4*)(vp + 0); o1 = *(float4*)(vp + 4); o2 = *(float4*)(vp + 8); o3 = *(float4*)(vp + 12);
  } else {
    o0 = make_float4(0.f, 0.f, 0.f, 0.f); o1 = o0; o2 = o0; o3 = o0;
  }
  o0.x = fmaf(a0.x, scale, o0.x); o0.y = fmaf(a0.y, scale, o0.y);
  o0.z = fmaf(a0.z, scale, o0.z); o0.w = fmaf(a0.w, scale, o0.w);
  o1.x = fmaf(a1.x, scale, o1.x); o1.y = fmaf(a1.y, scale, o1.y);
  o1.z = fmaf(a1.z, scale, o1.z); o1.w = fmaf(a1.w, scale, o1.w);
  o2.x = fmaf(a2.x, scale, o2.x); o2.y = fmaf(a2.y, scale, o2.y);
  o2.z = fmaf(a2.z, scale, o2.z); o2.w = fmaf(a2.w, scale, o2.w);
  o3.x = fmaf(a3.x, scale, o3.x); o3.y = fmaf(a3.y, scale, o3.y);
  o3.z = fmaf(a3.z, scale, o3.z); o3.w = fmaf(a3.w, scale, o3.w);
  *(float4*)(vp + 0) = o0; *(float4*)(vp + 4) = o1;
  *(float4*)(vp + 8) = o2; *(float4*)(vp + 12) = o3;
}

// out[b*8+e] = || squash(S) ||
__global__ void caps_out(const float* __restrict__ S, float* __restrict__ out) {
  const int t = threadIdx.x;
  const float* sp = S + t * 16;
  const float4 a0 = *(const float4*)sp;
  const float4 a1 = *(const float4*)(sp + 4);
  const float4 a2 = *(const float4*)(sp + 8);
  const float4 a3 = *(const float4*)(sp + 12);
  float n2 = a0.x * a0.x;
  n2 = fmaf(a0.y, a0.y, n2); n2 = fmaf(a0.z, a0.z, n2); n2 = fmaf(a0.w, a0.w, n2);
  n2 = fmaf(a1.x, a1.x, n2); n2 = fmaf(a1.y, a1.y, n2); n2 = fmaf(a1.z, a1.z, n2); n2 = fmaf(a1.w, a1.w, n2);
  n2 = fmaf(a2.x, a2.x, n2); n2 = fmaf(a2.y, a2.y, n2); n2 = fmaf(a2.z, a2.z, n2); n2 = fmaf(a2.w, a2.w, n2);
  n2 = fmaf(a3.x, a3.x, n2); n2 = fmaf(a3.y, a3.y, n2); n2 = fmaf(a3.z, a3.z, n2); n2 = fmaf(a3.w, a3.w, n2);
  const float n = sqrtf(n2);
  out[t] = n * n2 / ((1.f + n2) * (n + 1e-8f));
}

extern "C" void kernel_launch(void* const* d_in, const int* in_sizes, int n_in,
                              void* d_out, int out_size, void* d_ws, size_t ws_size,
                              hipStream_t stream) {
  const float* x   = (const float*)d_in[0];
  const float* w1  = (const float*)d_in[1];
  const float* b1  = (const float*)d_in[2];
  const float* w2  = (const float*)d_in[3];
  const float* b2  = (const float*)d_in[4];
  const float* w3  = (const float*)d_in[5];
  const float* b3  = (const float*)d_in[6];
  const float* pcw = (const float*)d_in[7];
  const float* pcb = (const float*)d_in[8];
  const float* W   = (const float*)d_in[9];
  float* out = (float*)d_out;

  char* ws = (char*)d_ws;
  const bool use_bf16w = (ws_size >= (size_t)82000000);

  // Common early buffers (live until conv3):
  u16*   x1p = (u16*)(ws + 0);           // 14,745,600
  u16*   A2  = (u16*)(ws + 14745600);    //  4,718,592
  u16*   A3  = (u16*)(ws + 19464192);    //    262,144
  u16*   y   = (u16*)(ws + 19726336);    // 10,240,000  (ends 29,966,336)

  u16*   Wb;
  float *z, *Spart, *u, *S, *vs;
  if (use_bf16w) {
    // Wb overlays x1p/A2/A3/y (all dead after conv3); written after conv3.
    Wb    = (u16*)(ws + 0);              // 40,960,000
    z     = (float*)(ws + 40960000);     // 20,480,000
    Spart = (float*)(ws + 40960000);     // reuses z (dead after caps_u)
    u     = (float*)(ws + 61440000);     // 20,480,000
    S     = (float*)(ws + 81920000);     // 16,384
    vs    = (float*)(ws + 81936384);     // 16,384
  } else {
    Wb    = nullptr;
    z     = (float*)(ws + 29966336);
    Spart = (float*)(ws + 29966336);
    u     = (float*)(ws + 50446336);
    S     = (float*)(ws + 70926336);
    vs    = (float*)(ws + 70942720);
  }

  hipMemsetAsync(x1p, 0, 14745600, stream);
  hipMemsetAsync(vs, 0, 16384, stream);

  prep_weights<<<9728, 256, 0, stream>>>(w2, w3, A2, A3);
  conv1_kernel<<<800, 256, 0, stream>>>(x, w1, b1, x1p);
  conv2_gemm<<<dim3(2, 157), 256, 0, stream>>>(A2, x1p, b2, y);
  conv3_gemm<<<dim3(2, 157), 256, 0, stream>>>(A3, x1p, y, b3, z);
  if (use_bf16w)
    prep_wb<<<20000, 256, 0, stream>>>(W, Wb);   // after conv3: x1p/A2/A3/y dead
  caps_u<<<2500, 256, 0, stream>>>(z, pcw, pcb, u);

  for (int pass = 0; pass < 3; pass++) {
    if (use_bf16w)
      caps_accb<<<1250, 256, 0, stream>>>(u, Wb, vs, Spart);
    else
      caps_acc<<<1250, 256, 0, stream>>>(u, W, vs, Spart);
    caps_red<<<16, 256, 0, stream>>>(Spart, S);
    if (pass == 0)      caps_v<<<1, 256, 0, stream>>>(S, vs, 0);
    else if (pass == 1) caps_v<<<1, 256, 0, stream>>>(S, vs, 1);
    else                caps_out<<<1, 256, 0, stream>>>(S, out);
  }
}

// Round 6
// 857.561 us; speedup vs baseline: 2.6893x; 1.1085x over previous
//
#include <hip/hip_runtime.h>

typedef unsigned short u16;
typedef __attribute__((ext_vector_type(8))) short bf16x8;
typedef __attribute__((ext_vector_type(4))) float floatx4;

#define NPIX 625
#define NCAPS 20000
#define K2 9216

__device__ __forceinline__ u16 f2bf(float f) {
  unsigned u = __float_as_uint(f);
  return (u16)((u + 0x7fffu + ((u >> 16) & 1u)) >> 16);
}

#define GLDS16(g, l) __builtin_amdgcn_global_load_lds( \
    (const __attribute__((address_space(1))) void*)(g), \
    (__attribute__((address_space(3))) void*)(l), 16, 0, 0)

// ---------- prep: weights -> bf16, conv2 reordered to [oc][tap][c] ----------
__global__ void prep_weights(const float* __restrict__ w2, const float* __restrict__ w3,
                             u16* __restrict__ A2, u16* __restrict__ A3) {
  int idx = blockIdx.x * 256 + threadIdx.x;
  if (idx < 256 * 36 * 256) {
    int oc = idx / 9216, r = idx % 9216;
    int t = r >> 8, c = r & 255;           // A2[oc][t*256+c] = w2[oc][c][t]
    A2[idx] = f2bf(w2[(oc * 256 + c) * 36 + t]);
  } else {
    int j = idx - 256 * 36 * 256;
    if (j < 256 * 512) A3[j] = f2bf(w3[j]);
  }
}

// ---------- prep: routing weights W (fp32) -> Wb (bf16), same layout ----------
__global__ void prep_wb(const float* __restrict__ W, u16* __restrict__ Wb) {
  int idx = blockIdx.x * 256 + threadIdx.x;  // one thread per 4 elements
  const float4 v = *(const float4*)(W + idx * 4);
  ushort4 p;
  p.x = f2bf(v.x); p.y = f2bf(v.y); p.z = f2bf(v.z); p.w = f2bf(v.w);
  *(ushort4*)(Wb + idx * 4) = p;
}

// ---------- conv1: (B,1,54,54) -> x1p padded NHWC bf16 (B,30,30,256) ----------
__global__ void conv1_kernel(const float* __restrict__ x, const float* __restrict__ w1,
                             const float* __restrict__ b1, u16* __restrict__ x1p) {
  int blk = blockIdx.x;                  // 800 = 32 b * 25 rows
  int b = blk / 25, i = blk % 25;
  int f = threadIdx.x;
  float wreg[36];
#pragma unroll
  for (int k = 0; k < 36; k++) wreg[k] = w1[f * 36 + k];
  float bias = b1[f];
  const float* xb = x + b * 54 * 54 + (2 * i) * 54;
  for (int j = 0; j < 25; j++) {
    float acc = bias;
#pragma unroll
    for (int ki = 0; ki < 6; ki++)
#pragma unroll
      for (int kj = 0; kj < 6; kj++)
        acc = fmaf(xb[ki * 54 + 2 * j + kj], wreg[ki * 6 + kj], acc);
    x1p[(((b * 30 + i + 2) * 30) + (j + 2)) * 256 + f] = f2bf(fmaxf(acc, 0.f));
  }
}

// ---------- conv2 implicit GEMM, split-K=2: partials P[kt][n][oc] fp32 ----------
__global__ __launch_bounds__(256) void conv2_gemm(const u16* __restrict__ A2,
    const u16* __restrict__ x1p, float* __restrict__ P) {
  __shared__ u16 As[128 * 32];
  __shared__ u16 Bs[128 * 32];
  const int tid = threadIdx.x;
  const int lane = tid & 63, wave = tid >> 6;
  const int mtile = blockIdx.x, ntile = blockIdx.y, kt = blockIdx.z;

  const int seg0 = tid, seg1 = tid + 256;
  const u16* ga0 = A2 + (mtile * 128 + (seg0 >> 2)) * K2 + (seg0 & 3) * 8;
  const u16* ga1 = A2 + (mtile * 128 + (seg1 >> 2)) * K2 + (seg1 & 3) * 8;

  auto pixbase = [&](int seg) {
    int n = ntile * 128 + (seg >> 2);
    if (n > NCAPS - 1) n = NCAPS - 1;
    int b = n / NPIX, p = n % NPIX;
    int i = p / 25, j = p % 25;
    return ((b * 30 + i) * 30 + j) * 256 + (seg & 3) * 8;
  };
  const u16* gb0 = x1p + pixbase(seg0);
  const u16* gb1 = x1p + pixbase(seg1);

  floatx4 acc[4][4] = {};
  const int wm = wave & 1, wn = wave >> 1;
  const int lrow = lane & 15, kgrp = lane >> 4;

  const int kc0 = kt * 144;
  for (int kc = kc0; kc < kc0 + 144; kc++) {
    int t = kc >> 3, c0 = (kc & 7) * 32;
    int ki = t / 6, kj = t % 6;
    int boff = (ki * 30 + kj) * 256 + c0;
    int aoff = kc * 32;
    GLDS16(ga0 + aoff, As + seg0 * 8);
    GLDS16(ga1 + aoff, As + seg1 * 8);
    GLDS16(gb0 + boff, Bs + seg0 * 8);
    GLDS16(gb1 + boff, Bs + seg1 * 8);
    __syncthreads();
    bf16x8 af[4], bfr[4];
#pragma unroll
    for (int tt = 0; tt < 4; tt++) {
      af[tt]  = *(const bf16x8*)(As + (wm * 64 + tt * 16 + lrow) * 32 + kgrp * 8);
      bfr[tt] = *(const bf16x8*)(Bs + (wn * 64 + tt * 16 + lrow) * 32 + kgrp * 8);
    }
#pragma unroll
    for (int tm = 0; tm < 4; tm++)
#pragma unroll
      for (int tn = 0; tn < 4; tn++)
        acc[tm][tn] = __builtin_amdgcn_mfma_f32_16x16x32_bf16(af[tm], bfr[tn], acc[tm][tn], 0, 0, 0);
    __syncthreads();
  }

  float* Pk = P + kt * 5120000;
  const int nb = ntile * 128 + wn * 64;
  const int ocb = mtile * 128 + wm * 64 + kgrp * 4;
#pragma unroll
  for (int tn = 0; tn < 4; tn++) {
    int n = nb + tn * 16 + lrow;
    if (n < NCAPS) {
#pragma unroll
      for (int tm = 0; tm < 4; tm++) {
        int oc = ocb + tm * 16;
        float4 v;
        v.x = acc[tm][tn][0]; v.y = acc[tm][tn][1];
        v.z = acc[tm][tn][2]; v.w = acc[tm][tn][3];
        *(float4*)(Pk + n * 256 + oc) = v;
      }
    }
  }
}

// ---------- conv2 split-K reduce: y = bf16(relu(P0+P1+bias)) ----------
__global__ void conv2_red(const float* __restrict__ P, const float* __restrict__ bias2,
                          u16* __restrict__ y) {
  const int idx = blockIdx.x * 256 + threadIdx.x;   // 1,280,000 groups of 4
  const float4 a = *(const float4*)(P + idx * 4);
  const float4 b = *(const float4*)(P + 5120000 + idx * 4);
  const float4 bs = *(const float4*)(bias2 + ((idx * 4) & 255));
  ushort4 pk;
  pk.x = f2bf(fmaxf(a.x + b.x + bs.x, 0.f));
  pk.y = f2bf(fmaxf(a.y + b.y + bs.y, 0.f));
  pk.z = f2bf(fmaxf(a.z + b.z + bs.z, 0.f));
  pk.w = f2bf(fmaxf(a.w + b.w + bs.w, 0.f));
  *(ushort4*)(y + idx * 4) = pk;
}

// ---------- conv3 1x1 GEMM: M=256(f) N=20000 K=512 (x1 | y) ----------
__global__ __launch_bounds__(256) void conv3_gemm(const u16* __restrict__ A3,
    const u16* __restrict__ x1p, const u16* __restrict__ y,
    const float* __restrict__ bias3, float* __restrict__ z) {
  __shared__ u16 As[128 * 32];
  __shared__ u16 Bs[128 * 32];
  const int tid = threadIdx.x;
  const int lane = tid & 63, wave = tid >> 6;
  const int mtile = blockIdx.x, ntile = blockIdx.y;

  const int seg0 = tid, seg1 = tid + 256;
  const u16* ga0 = A3 + (mtile * 128 + (seg0 >> 2)) * 512 + (seg0 & 3) * 8;
  const u16* ga1 = A3 + (mtile * 128 + (seg1 >> 2)) * 512 + (seg1 & 3) * 8;

  auto mkbases = [&](int seg, const u16*& gx, const u16*& gy) {
    int n = ntile * 128 + (seg >> 2);
    if (n > NCAPS - 1) n = NCAPS - 1;
    int b = n / NPIX, p = n % NPIX;
    int i = p / 25, j = p % 25;
    gx = x1p + ((b * 30 + i + 2) * 30 + (j + 2)) * 256 + (seg & 3) * 8;
    gy = y + n * 256 + (seg & 3) * 8;
  };
  const u16 *gx0, *gy0, *gx1, *gy1;
  mkbases(seg0, gx0, gy0);
  mkbases(seg1, gx1, gy1);

  floatx4 acc[4][4] = {};
  const int wm = wave & 1, wn = wave >> 1;
  const int lrow = lane & 15, kgrp = lane >> 4;

  for (int kc = 0; kc < 16; kc++) {
    const u16* s0 = (kc < 8) ? (gx0 + kc * 32) : (gy0 + (kc - 8) * 32);
    const u16* s1 = (kc < 8) ? (gx1 + kc * 32) : (gy1 + (kc - 8) * 32);
    GLDS16(ga0 + kc * 32, As + seg0 * 8);
    GLDS16(ga1 + kc * 32, As + seg1 * 8);
    GLDS16(s0, Bs + seg0 * 8);
    GLDS16(s1, Bs + seg1 * 8);
    __syncthreads();
    bf16x8 af[4], bfr[4];
#pragma unroll
    for (int tt = 0; tt < 4; tt++) {
      af[tt]  = *(const bf16x8*)(As + (wm * 64 + tt * 16 + lrow) * 32 + kgrp * 8);
      bfr[tt] = *(const bf16x8*)(Bs + (wn * 64 + tt * 16 + lrow) * 32 + kgrp * 8);
    }
#pragma unroll
    for (int tm = 0; tm < 4; tm++)
#pragma unroll
      for (int tn = 0; tn < 4; tn++)
        acc[tm][tn] = __builtin_amdgcn_mfma_f32_16x16x32_bf16(af[tm], bfr[tn], acc[tm][tn], 0, 0, 0);
    __syncthreads();
  }

  const int nb = ntile * 128 + wn * 64;
  const int fb = mtile * 128 + wm * 64 + kgrp * 4;
#pragma unroll
  for (int tn = 0; tn < 4; tn++) {
    int n = nb + tn * 16 + lrow;
    if (n < NCAPS) {
#pragma unroll
      for (int tm = 0; tm < 4; tm++) {
        int f0 = fb + tm * 16;
        float4 v;
        v.x = acc[tm][tn][0] + bias3[f0 + 0];
        v.y = acc[tm][tn][1] + bias3[f0 + 1];
        v.z = acc[tm][tn][2] + bias3[f0 + 2];
        v.w = acc[tm][tn][3] + bias3[f0 + 3];
        *(float4*)(z + n * 256 + f0) = v;
      }
    }
  }
}

// ============ caps section ============
// u layout: u[n][b*8+o]  (n-major, 256 floats per n)
// Routing thread = (b, e), tid = b*8+e.

__device__ __forceinline__ float dot8v(float4 a0, float4 a1, float4 b0, float4 b1) {
  float s = a0.x * b0.x;
  s = fmaf(a0.y, b0.y, s);
  s = fmaf(a0.z, b0.z, s);
  s = fmaf(a0.w, b0.w, s);
  s = fmaf(a1.x, b1.x, s);
  s = fmaf(a1.y, b1.y, s);
  s = fmaf(a1.z, b1.z, s);
  s = fmaf(a1.w, b1.w, s);
  return s;
}

// bf16 row (8 elements packed in uint4) dot fp32 u
__device__ __forceinline__ float dotrow(uint4 w, float4 ua, float4 ub) {
  float s = __uint_as_float(w.x << 16) * ua.x;
  s = fmaf(__uint_as_float(w.x & 0xffff0000u), ua.y, s);
  s = fmaf(__uint_as_float(w.y << 16), ua.z, s);
  s = fmaf(__uint_as_float(w.y & 0xffff0000u), ua.w, s);
  s = fmaf(__uint_as_float(w.z << 16), ub.x, s);
  s = fmaf(__uint_as_float(w.z & 0xffff0000u), ub.y, s);
  s = fmaf(__uint_as_float(w.w << 16), ub.z, s);
  s = fmaf(__uint_as_float(w.w & 0xffff0000u), ub.w, s);
  return s;
}

// u[n][b*8+o] = pcb[n][o] + caps[b][n][:] . pcw[n][o][:]
__global__ void caps_u(const float* __restrict__ z, const float* __restrict__ pcw,
                       const float* __restrict__ pcb, float* __restrict__ u) {
  const int tid = threadIdx.x;
  const int b = tid >> 3, o = tid & 7;
  for (int k = 0; k < 8; k++) {
    const int n = blockIdx.x * 8 + k;
    const int g = n / NPIX, p = n % NPIX;
    const float* zp = z + (b * NPIX + p) * 256 + g * 8;
    float4 c0 = *(const float4*)zp;
    float4 c1 = *(const float4*)(zp + 4);
    const float* pw = pcw + n * 64 + o * 8;
    float4 w0 = *(const float4*)pw;
    float4 w1 = *(const float4*)(pw + 4);
    u[n * 256 + tid] = pcb[n * 8 + o] + dot8v(w0, w1, c0, c1);
  }
}

// ---- routing pass, bf16 W: c = softmax_e(u_hat.vsum); Spart += c*u_hat ----
__global__ __launch_bounds__(256, 2) void caps_accb(const float* __restrict__ u,
    const u16* __restrict__ Wb, const float* __restrict__ vsum,
    float* __restrict__ Spart) {
  const int tid = threadIdx.x;
  const int b = tid >> 3;
  const float* vp = vsum + tid * 16;
  const float4 V0 = *(const float4*)vp;
  const float4 V1 = *(const float4*)(vp + 4);
  const float4 V2 = *(const float4*)(vp + 8);
  const float4 V3 = *(const float4*)(vp + 12);
  float s0 = 0.f, s1 = 0.f, s2 = 0.f, s3 = 0.f, s4 = 0.f, s5 = 0.f, s6 = 0.f, s7 = 0.f;
  float s8 = 0.f, s9 = 0.f, s10 = 0.f, s11 = 0.f, s12 = 0.f, s13 = 0.f, s14 = 0.f, s15 = 0.f;
  const int n0 = blockIdx.x * 16;
  // preload u for first n
  const float* un = u + n0 * 256 + (b << 3);
  float4 u0 = *(const float4*)un;
  float4 u1 = *(const float4*)(un + 4);
  for (int it = 0; it < 16; it++) {
    const int n = n0 + it;
    const u16* Wn = Wb + n * 1024 + (tid & 7) * 128;
    // issue ALL 16 row loads up front (forces MLP)
    uint4 w0  = *(const uint4*)(Wn + 0);
    uint4 w1  = *(const uint4*)(Wn + 8);
    uint4 w2  = *(const uint4*)(Wn + 16);
    uint4 w3  = *(const uint4*)(Wn + 24);
    uint4 w4  = *(const uint4*)(Wn + 32);
    uint4 w5  = *(const uint4*)(Wn + 40);
    uint4 w6  = *(const uint4*)(Wn + 48);
    uint4 w7  = *(const uint4*)(Wn + 56);
    uint4 w8  = *(const uint4*)(Wn + 64);
    uint4 w9  = *(const uint4*)(Wn + 72);
    uint4 w10 = *(const uint4*)(Wn + 80);
    uint4 w11 = *(const uint4*)(Wn + 88);
    uint4 w12 = *(const uint4*)(Wn + 96);
    uint4 w13 = *(const uint4*)(Wn + 104);
    uint4 w14 = *(const uint4*)(Wn + 112);
    uint4 w15 = *(const uint4*)(Wn + 120);
    // prefetch next n's u
    const int np = (it < 15) ? (n + 1) : n;
    const float* unp = u + np * 256 + (b << 3);
    const float4 p0 = *(const float4*)unp;
    const float4 p1 = *(const float4*)(unp + 4);

    const float h0  = dotrow(w0, u0, u1);
    const float h1  = dotrow(w1, u0, u1);
    const float h2  = dotrow(w2, u0, u1);
    const float h3  = dotrow(w3, u0, u1);
    const float h4  = dotrow(w4, u0, u1);
    const float h5  = dotrow(w5, u0, u1);
    const float h6  = dotrow(w6, u0, u1);
    const float h7  = dotrow(w7, u0, u1);
    const float h8  = dotrow(w8, u0, u1);
    const float h9  = dotrow(w9, u0, u1);
    const float h10 = dotrow(w10, u0, u1);
    const float h11 = dotrow(w11, u0, u1);
    const float h12 = dotrow(w12, u0, u1);
    const float h13 = dotrow(w13, u0, u1);
    const float h14 = dotrow(w14, u0, u1);
    const float h15 = dotrow(w15, u0, u1);

    float blog = h0 * V0.x;
    blog = fmaf(h1, V0.y, blog);  blog = fmaf(h2, V0.z, blog);  blog = fmaf(h3, V0.w, blog);
    blog = fmaf(h4, V1.x, blog);  blog = fmaf(h5, V1.y, blog);  blog = fmaf(h6, V1.z, blog);
    blog = fmaf(h7, V1.w, blog);  blog = fmaf(h8, V2.x, blog);  blog = fmaf(h9, V2.y, blog);
    blog = fmaf(h10, V2.z, blog); blog = fmaf(h11, V2.w, blog); blog = fmaf(h12, V3.x, blog);
    blog = fmaf(h13, V3.y, blog); blog = fmaf(h14, V3.z, blog); blog = fmaf(h15, V3.w, blog);
    float m = blog;
    m = fmaxf(m, __shfl_xor(m, 1, 64));
    m = fmaxf(m, __shfl_xor(m, 2, 64));
    m = fmaxf(m, __shfl_xor(m, 4, 64));
    float ex = __expf(blog - m);
    float ss = ex;
    ss += __shfl_xor(ss, 1, 64);
    ss += __shfl_xor(ss, 2, 64);
    ss += __shfl_xor(ss, 4, 64);
    const float c = ex / ss;
    s0 = fmaf(c, h0, s0);   s1 = fmaf(c, h1, s1);   s2 = fmaf(c, h2, s2);   s3 = fmaf(c, h3, s3);
    s4 = fmaf(c, h4, s4);   s5 = fmaf(c, h5, s5);   s6 = fmaf(c, h6, s6);   s7 = fmaf(c, h7, s7);
    s8 = fmaf(c, h8, s8);   s9 = fmaf(c, h9, s9);   s10 = fmaf(c, h10, s10); s11 = fmaf(c, h11, s11);
    s12 = fmaf(c, h12, s12); s13 = fmaf(c, h13, s13); s14 = fmaf(c, h14, s14); s15 = fmaf(c, h15, s15);
    u0 = p0; u1 = p1;
  }
  float* Sp = Spart + blockIdx.x * 4096 + tid * 16;
  *(float4*)(Sp + 0)  = make_float4(s0, s1, s2, s3);
  *(float4*)(Sp + 4)  = make_float4(s4, s5, s6, s7);
  *(float4*)(Sp + 8)  = make_float4(s8, s9, s10, s11);
  *(float4*)(Sp + 12) = make_float4(s12, s13, s14, s15);
}

// ---- routing pass, fp32 W fallback (used when ws too small for Wb) ----
__global__ __launch_bounds__(256, 2) void caps_acc(const float* __restrict__ u,
    const float* __restrict__ W, const float* __restrict__ vsum,
    float* __restrict__ Spart) {
  const int tid = threadIdx.x;
  const int b = tid >> 3, e = tid & 7;
  const float* vp = vsum + tid * 16;
  const float4 V0 = *(const float4*)vp;
  const float4 V1 = *(const float4*)(vp + 4);
  const float4 V2 = *(const float4*)(vp + 8);
  const float4 V3 = *(const float4*)(vp + 12);
  float s0 = 0.f, s1 = 0.f, s2 = 0.f, s3 = 0.f, s4 = 0.f, s5 = 0.f, s6 = 0.f, s7 = 0.f;
  float s8 = 0.f, s9 = 0.f, s10 = 0.f, s11 = 0.f, s12 = 0.f, s13 = 0.f, s14 = 0.f, s15 = 0.f;
  const int n0 = blockIdx.x * 16;
  for (int it = 0; it < 16; it++) {
    const int n = n0 + it;
    const float* un = u + n * 256 + (b << 3);
    const float4 u0 = *(const float4*)un;
    const float4 u1 = *(const float4*)(un + 4);
    const float* Wn = W + n * 1024 + e * 128;
    float h0, h1, h2, h3, h4, h5, h6, h7, h8, h9, h10, h11, h12, h13, h14, h15;
#define OST(o, H) { float4 wa = *(const float4*)(Wn + (o) * 8); \
                    float4 wb = *(const float4*)(Wn + (o) * 8 + 4); \
                    H = dot8v(wa, wb, u0, u1); }
    OST(0, h0)  OST(1, h1)  OST(2, h2)  OST(3, h3)
    OST(4, h4)  OST(5, h5)  OST(6, h6)  OST(7, h7)
    OST(8, h8)  OST(9, h9)  OST(10, h10) OST(11, h11)
    OST(12, h12) OST(13, h13) OST(14, h14) OST(15, h15)
#undef OST
    float blog = h0 * V0.x;
    blog = fmaf(h1, V0.y, blog);  blog = fmaf(h2, V0.z, blog);  blog = fmaf(h3, V0.w, blog);
    blog = fmaf(h4, V1.x, blog);  blog = fmaf(h5, V1.y, blog);  blog = fmaf(h6, V1.z, blog);
    blog = fmaf(h7, V1.w, blog);  blog = fmaf(h8, V2.x, blog);  blog = fmaf(h9, V2.y, blog);
    blog = fmaf(h10, V2.z, blog); blog = fmaf(h11, V2.w, blog); blog = fmaf(h12, V3.x, blog);
    blog = fmaf(h13, V3.y, blog); blog = fmaf(h14, V3.z, blog); blog = fmaf(h15, V3.w, blog);
    float m = blog;
    m = fmaxf(m, __shfl_xor(m, 1, 64));
    m = fmaxf(m, __shfl_xor(m, 2, 64));
    m = fmaxf(m, __shfl_xor(m, 4, 64));
    float ex = __expf(blog - m);
    float ss = ex;
    ss += __shfl_xor(ss, 1, 64);
    ss += __shfl_xor(ss, 2, 64);
    ss += __shfl_xor(ss, 4, 64);
    const float c = ex / ss;
    s0 = fmaf(c, h0, s0);   s1 = fmaf(c, h1, s1);   s2 = fmaf(c, h2, s2);   s3 = fmaf(c, h3, s3);
    s4 = fmaf(c, h4, s4);   s5 = fmaf(c, h5, s5);   s6 = fmaf(c, h6, s6);   s7 = fmaf(c, h7, s7);
    s8 = fmaf(c, h8, s8);   s9 = fmaf(c, h9, s9);   s10 = fmaf(c, h10, s10); s11 = fmaf(c, h11, s11);
    s12 = fmaf(c, h12, s12); s13 = fmaf(c, h13, s13); s14 = fmaf(c, h14, s14); s15 = fmaf(c, h15, s15);
  }
  float* Sp = Spart + blockIdx.x * 4096 + tid * 16;
  *(float4*)(Sp + 0)  = make_float4(s0, s1, s2, s3);
  *(float4*)(Sp + 4)  = make_float4(s4, s5, s6, s7);
  *(float4*)(Sp + 8)  = make_float4(s8, s9, s10, s11);
  *(float4*)(Sp + 12) = make_float4(s12, s13, s14, s15);
}

// sum 1250 block-partials -> S[4096] via per-chunk partial + atomicAdd
// grid: (16 j-tiles, 25 row-chunks of 50); S must be zeroed before.
__global__ void caps_redA(const float* __restrict__ Spart, float* __restrict__ S) {
  const int j = blockIdx.x * 256 + threadIdx.x;
  const int r0 = blockIdx.y * 50;
  float a0 = 0.f, a1 = 0.f;
  for (int r = 0; r < 50; r += 2) {
    a0 += Spart[(r0 + r) * 4096 + j];
    a1 += Spart[(r0 + r + 1) * 4096 + j];
  }
  atomicAdd(&S[j], a0 + a1);
}

// squash(S) and set/accumulate vsum
__global__ void caps_v(const float* __restrict__ S, float* __restrict__ vsum, int add) {
  const int t = threadIdx.x;           // 256 = 32 b x 8 e
  const float* sp = S + t * 16;
  const float4 a0 = *(const float4*)sp;
  const float4 a1 = *(const float4*)(sp + 4);
  const float4 a2 = *(const float4*)(sp + 8);
  const float4 a3 = *(const float4*)(sp + 12);
  float n2 = a0.x * a0.x;
  n2 = fmaf(a0.y, a0.y, n2); n2 = fmaf(a0.z, a0.z, n2); n2 = fmaf(a0.w, a0.w, n2);
  n2 = fmaf(a1.x, a1.x, n2); n2 = fmaf(a1.y, a1.y, n2); n2 = fmaf(a1.z, a1.z, n2); n2 = fmaf(a1.w, a1.w, n2);
  n2 = fmaf(a2.x, a2.x, n2); n2 = fmaf(a2.y, a2.y, n2); n2 = fmaf(a2.z, a2.z, n2); n2 = fmaf(a2.w, a2.w, n2);
  n2 = fmaf(a3.x, a3.x, n2); n2 = fmaf(a3.y, a3.y, n2); n2 = fmaf(a3.z, a3.z, n2); n2 = fmaf(a3.w, a3.w, n2);
  const float n = sqrtf(n2);
  const float scale = n2 / ((1.f + n2) * (n + 1e-8f));
  float* vp = vsum + t * 16;
  float4 o0, o1, o2, o3;
  if (add) {
    o0 = *(float4*)(vp + 0); o1 = *(float4*)(vp + 4); o2 = *(float4*)(vp + 8); o3 = *(float4*)(vp + 12);
  } else {
    o0 = make_float4(0.f, 0.f, 0.f, 0.f); o1 = o0; o2 = o0; o3 = o0;
  }
  o0.x = fmaf(a0.x, scale, o0.x); o0.y = fmaf(a0.y, scale, o0.y);
  o0.z = fmaf(a0.z, scale, o0.z); o0.w = fmaf(a0.w, scale, o0.w);
  o1.x = fmaf(a1.x, scale, o1.x); o1.y = fmaf(a1.y, scale, o1.y);
  o1.z = fmaf(a1.z, scale, o1.z); o1.w = fmaf(a1.w, scale, o1.w);
  o2.x = fmaf(a2.x, scale, o2.x); o2.y = fmaf(a2.y, scale, o2.y);
  o2.z = fmaf(a2.z, scale, o2.z); o2.w = fmaf(a2.w, scale, o2.w);
  o3.x = fmaf(a3.x, scale, o3.x); o3.y = fmaf(a3.y, scale, o3.y);
  o3.z = fmaf(a3.z, scale, o3.z); o3.w = fmaf(a3.w, scale, o3.w);
  *(float4*)(vp + 0) = o0; *(float4*)(vp + 4) = o1;
  *(float4*)(vp + 8) = o2; *(float4*)(vp + 12) = o3;
}

// out[b*8+e] = || squash(S) ||
__global__ void caps_out(const float* __restrict__ S, float* __restrict__ out) {
  const int t = threadIdx.x;
  const float* sp = S + t * 16;
  const float4 a0 = *(const float4*)sp;
  const float4 a1 = *(const float4*)(sp + 4);
  const float4 a2 = *(const float4*)(sp + 8);
  const float4 a3 = *(const float4*)(sp + 12);
  float n2 = a0.x * a0.x;
  n2 = fmaf(a0.y, a0.y, n2); n2 = fmaf(a0.z, a0.z, n2); n2 = fmaf(a0.w, a0.w, n2);
  n2 = fmaf(a1.x, a1.x, n2); n2 = fmaf(a1.y, a1.y, n2); n2 = fmaf(a1.z, a1.z, n2); n2 = fmaf(a1.w, a1.w, n2);
  n2 = fmaf(a2.x, a2.x, n2); n2 = fmaf(a2.y, a2.y, n2); n2 = fmaf(a2.z, a2.z, n2); n2 = fmaf(a2.w, a2.w, n2);
  n2 = fmaf(a3.x, a3.x, n2); n2 = fmaf(a3.y, a3.y, n2); n2 = fmaf(a3.z, a3.z, n2); n2 = fmaf(a3.w, a3.w, n2);
  const float n = sqrtf(n2);
  out[t] = n * n2 / ((1.f + n2) * (n + 1e-8f));
}

extern "C" void kernel_launch(void* const* d_in, const int* in_sizes, int n_in,
                              void* d_out, int out_size, void* d_ws, size_t ws_size,
                              hipStream_t stream) {
  const float* x   = (const float*)d_in[0];
  const float* w1  = (const float*)d_in[1];
  const float* b1  = (const float*)d_in[2];
  const float* w2  = (const float*)d_in[3];
  const float* b2  = (const float*)d_in[4];
  const float* w3  = (const float*)d_in[5];
  const float* b3  = (const float*)d_in[6];
  const float* pcw = (const float*)d_in[7];
  const float* pcb = (const float*)d_in[8];
  const float* W   = (const float*)d_in[9];
  float* out = (float*)d_out;

  char* ws = (char*)d_ws;
  const bool use_bf16w = (ws_size >= (size_t)82000000);

  // Common early buffers (live until conv3):
  u16*   x1p = (u16*)(ws + 0);           // 14,745,600
  u16*   A2  = (u16*)(ws + 14745600);    //  4,718,592
  u16*   A3  = (u16*)(ws + 19464192);    //    262,144
  u16*   y   = (u16*)(ws + 19726336);    // 10,240,000  (ends 29,966,336)
  // conv2 split-K partials: 2 x 20,480,000 = 40,960,000 (dead after conv2_red)
  float* P   = (float*)(ws + 29966336);  // ends 70,926,336

  u16*   Wb;
  float *z, *Spart, *u, *S, *vs;
  if (use_bf16w) {
    // Wb overlays x1p/A2/A3/y/P-head (all dead after conv3); written after conv3.
    Wb    = (u16*)(ws + 0);              // 40,960,000
    z     = (float*)(ws + 40960000);     // 20,480,000 (overlays P tail; P dead)
    Spart = (float*)(ws + 40960000);     // reuses z (dead after caps_u)
    u     = (float*)(ws + 61440000);     // 20,480,000
    S     = (float*)(ws + 81920000);     // 16,384
    vs    = (float*)(ws + 81936384);     // 16,384
  } else {
    Wb    = nullptr;
    z     = (float*)(ws + 29966336);     // overlays P (dead by conv3)
    Spart = (float*)(ws + 29966336);
    u     = (float*)(ws + 50446336);
    S     = (float*)(ws + 70926336);
    vs    = (float*)(ws + 70942720);
  }

  hipMemsetAsync(x1p, 0, 14745600, stream);
  hipMemsetAsync(vs, 0, 16384, stream);

  prep_weights<<<9728, 256, 0, stream>>>(w2, w3, A2, A3);
  conv1_kernel<<<800, 256, 0, stream>>>(x, w1, b1, x1p);
  conv2_gemm<<<dim3(2, 157, 2), 256, 0, stream>>>(A2, x1p, P);
  conv2_red<<<5000, 256, 0, stream>>>(P, b2, y);
  conv3_gemm<<<dim3(2, 157), 256, 0, stream>>>(A3, x1p, y, b3, z);
  if (use_bf16w)
    prep_wb<<<20000, 256, 0, stream>>>(W, Wb);   // after conv3: x1p/A2/A3/y/P dead
  caps_u<<<2500, 256, 0, stream>>>(z, pcw, pcb, u);

  for (int pass = 0; pass < 3; pass++) {
    if (use_bf16w)
      caps_accb<<<1250, 256, 0, stream>>>(u, Wb, vs, Spart);
    else
      caps_acc<<<1250, 256, 0, stream>>>(u, W, vs, Spart);
    hipMemsetAsync(S, 0, 16384, stream);
    caps_redA<<<dim3(16, 25), 256, 0, stream>>>(Spart, S);
    if (pass == 0)      caps_v<<<1, 256, 0, stream>>>(S, vs, 0);
    else if (pass == 1) caps_v<<<1, 256, 0, stream>>>(S, vs, 1);
    else                caps_out<<<1, 256, 0, stream>>>(S, out);
  }
}

// Round 7
// 823.901 us; speedup vs baseline: 2.7991x; 1.0409x over previous
//
#include <hip/hip_runtime.h>

typedef unsigned short u16;
typedef __attribute__((ext_vector_type(8))) short bf16x8;
typedef __attribute__((ext_vector_type(4))) float floatx4;

#define NPIX 625
#define NCAPS 20000
#define K2 9216

__device__ __forceinline__ u16 f2bf(float f) {
  unsigned u = __float_as_uint(f);
  return (u16)((u + 0x7fffu + ((u >> 16) & 1u)) >> 16);
}

#define GLDS16(g, l) __builtin_amdgcn_global_load_lds( \
    (const __attribute__((address_space(1))) void*)(g), \
    (__attribute__((address_space(3))) void*)(l), 16, 0, 0)

// ---------- prep: weights -> bf16, conv2 reordered to [oc][tap][c] ----------
__global__ void prep_weights(const float* __restrict__ w2, const float* __restrict__ w3,
                             u16* __restrict__ A2, u16* __restrict__ A3) {
  int idx = blockIdx.x * 256 + threadIdx.x;
  if (idx < 256 * 36 * 256) {
    int oc = idx / 9216, r = idx % 9216;
    int t = r >> 8, c = r & 255;           // A2[oc][t*256+c] = w2[oc][c][t]
    A2[idx] = f2bf(w2[(oc * 256 + c) * 36 + t]);
  } else {
    int j = idx - 256 * 36 * 256;
    if (j < 256 * 512) A3[j] = f2bf(w3[j]);
  }
}

// ---------- prep: routing weights W (fp32) -> Wb (bf16), same layout ----------
__global__ void prep_wb(const float* __restrict__ W, u16* __restrict__ Wb) {
  int idx = blockIdx.x * 256 + threadIdx.x;  // one thread per 4 elements
  const float4 v = *(const float4*)(W + idx * 4);
  ushort4 p;
  p.x = f2bf(v.x); p.y = f2bf(v.y); p.z = f2bf(v.z); p.w = f2bf(v.w);
  *(ushort4*)(Wb + idx * 4) = p;
}

// ---------- conv1: (B,1,54,54) -> x1p padded NHWC bf16 (B,30,30,256) ----------
__global__ void conv1_kernel(const float* __restrict__ x, const float* __restrict__ w1,
                             const float* __restrict__ b1, u16* __restrict__ x1p) {
  int blk = blockIdx.x;                  // 800 = 32 b * 25 rows
  int b = blk / 25, i = blk % 25;
  int f = threadIdx.x;
  float wreg[36];
#pragma unroll
  for (int k = 0; k < 36; k++) wreg[k] = w1[f * 36 + k];
  float bias = b1[f];
  const float* xb = x + b * 54 * 54 + (2 * i) * 54;
  for (int j = 0; j < 25; j++) {
    float acc = bias;
#pragma unroll
    for (int ki = 0; ki < 6; ki++)
#pragma unroll
      for (int kj = 0; kj < 6; kj++)
        acc = fmaf(xb[ki * 54 + 2 * j + kj], wreg[ki * 6 + kj], acc);
    x1p[(((b * 30 + i + 2) * 30) + (j + 2)) * 256 + f] = f2bf(fmaxf(acc, 0.f));
  }
}

// ---------- conv2 implicit GEMM, split-K=2, BK=64 per barrier ----------
// grid (2 mtile, 157 ntile, 2 kt); each kt covers 18 taps = 144 kc chunks.
__global__ __launch_bounds__(256) void conv2_gemm(const u16* __restrict__ A2,
    const u16* __restrict__ x1p, float* __restrict__ P) {
  __shared__ u16 As0[128 * 32];
  __shared__ u16 Bs0[128 * 32];
  __shared__ u16 As1[128 * 32];
  __shared__ u16 Bs1[128 * 32];
  const int tid = threadIdx.x;
  const int lane = tid & 63, wave = tid >> 6;
  const int mtile = blockIdx.x, ntile = blockIdx.y, kt = blockIdx.z;

  const int seg0 = tid, seg1 = tid + 256;
  const u16* gA0 = A2 + (mtile * 128 + (seg0 >> 2)) * K2 + (seg0 & 3) * 8 + kt * 4608;
  const u16* gA1 = A2 + (mtile * 128 + (seg1 >> 2)) * K2 + (seg1 & 3) * 8 + kt * 4608;

  auto pixbase = [&](int seg) {
    int n = ntile * 128 + (seg >> 2);
    if (n > NCAPS - 1) n = NCAPS - 1;
    int b = n / NPIX, p = n % NPIX;
    int i = p / 25, j = p % 25;
    return ((b * 30 + i) * 30 + j) * 256 + (seg & 3) * 8;
  };
  const u16* gb0 = x1p + pixbase(seg0);
  const u16* gb1 = x1p + pixbase(seg1);

  floatx4 acc[4][4] = {};
  const int wm = wave & 1, wn = wave >> 1;
  const int lrow = lane & 15, kgrp = lane >> 4;

  int kj = 0;
  int boff = 3 * kt * 30 * 256;          // ki = 3*kt, kj = 0
  for (int t = 0; t < 18; t++) {
#pragma unroll 1
    for (int cc = 0; cc < 8; cc += 2) {
      const int b0 = boff + cc * 32;
      GLDS16(gA0, As0 + seg0 * 8);
      GLDS16(gA1, As0 + seg1 * 8);
      GLDS16(gA0 + 32, As1 + seg0 * 8);
      GLDS16(gA1 + 32, As1 + seg1 * 8);
      GLDS16(gb0 + b0, Bs0 + seg0 * 8);
      GLDS16(gb1 + b0, Bs0 + seg1 * 8);
      GLDS16(gb0 + b0 + 32, Bs1 + seg0 * 8);
      GLDS16(gb1 + b0 + 32, Bs1 + seg1 * 8);
      gA0 += 64; gA1 += 64;
      __syncthreads();
      bf16x8 af[4], bfr[4];
#pragma unroll
      for (int tt = 0; tt < 4; tt++) {
        af[tt]  = *(const bf16x8*)(As0 + (wm * 64 + tt * 16 + lrow) * 32 + kgrp * 8);
        bfr[tt] = *(const bf16x8*)(Bs0 + (wn * 64 + tt * 16 + lrow) * 32 + kgrp * 8);
      }
#pragma unroll
      for (int tm = 0; tm < 4; tm++)
#pragma unroll
        for (int tn = 0; tn < 4; tn++)
          acc[tm][tn] = __builtin_amdgcn_mfma_f32_16x16x32_bf16(af[tm], bfr[tn], acc[tm][tn], 0, 0, 0);
#pragma unroll
      for (int tt = 0; tt < 4; tt++) {
        af[tt]  = *(const bf16x8*)(As1 + (wm * 64 + tt * 16 + lrow) * 32 + kgrp * 8);
        bfr[tt] = *(const bf16x8*)(Bs1 + (wn * 64 + tt * 16 + lrow) * 32 + kgrp * 8);
      }
#pragma unroll
      for (int tm = 0; tm < 4; tm++)
#pragma unroll
        for (int tn = 0; tn < 4; tn++)
          acc[tm][tn] = __builtin_amdgcn_mfma_f32_16x16x32_bf16(af[tm], bfr[tn], acc[tm][tn], 0, 0, 0);
      __syncthreads();
    }
    boff += 256;
    kj++;
    if (kj == 6) { kj = 0; boff += 6144; }   // advance to next kernel row
  }

  float* Pk = P + kt * 5120000;
  const int nb = ntile * 128 + wn * 64;
  const int ocb = mtile * 128 + wm * 64 + kgrp * 4;
#pragma unroll
  for (int tn = 0; tn < 4; tn++) {
    int n = nb + tn * 16 + lrow;
    if (n < NCAPS) {
#pragma unroll
      for (int tm = 0; tm < 4; tm++) {
        int oc = ocb + tm * 16;
        float4 v;
        v.x = acc[tm][tn][0]; v.y = acc[tm][tn][1];
        v.z = acc[tm][tn][2]; v.w = acc[tm][tn][3];
        *(float4*)(Pk + n * 256 + oc) = v;
      }
    }
  }
}

// ---------- conv2 split-K reduce: y = bf16(relu(P0+P1+bias)) ----------
__global__ void conv2_red(const float* __restrict__ P, const float* __restrict__ bias2,
                          u16* __restrict__ y) {
  const int idx = blockIdx.x * 256 + threadIdx.x;   // 1,280,000 groups of 4
  const float4 a = *(const float4*)(P + idx * 4);
  const float4 b = *(const float4*)(P + 5120000 + idx * 4);
  const float4 bs = *(const float4*)(bias2 + ((idx * 4) & 255));
  ushort4 pk;
  pk.x = f2bf(fmaxf(a.x + b.x + bs.x, 0.f));
  pk.y = f2bf(fmaxf(a.y + b.y + bs.y, 0.f));
  pk.z = f2bf(fmaxf(a.z + b.z + bs.z, 0.f));
  pk.w = f2bf(fmaxf(a.w + b.w + bs.w, 0.f));
  *(ushort4*)(y + idx * 4) = pk;
}

// ---------- conv3 1x1 GEMM: M=256(f) N=20000 K=512 (x1 | y) ----------
__global__ __launch_bounds__(256) void conv3_gemm(const u16* __restrict__ A3,
    const u16* __restrict__ x1p, const u16* __restrict__ y,
    const float* __restrict__ bias3, float* __restrict__ z) {
  __shared__ u16 As[128 * 32];
  __shared__ u16 Bs[128 * 32];
  const int tid = threadIdx.x;
  const int lane = tid & 63, wave = tid >> 6;
  const int mtile = blockIdx.x, ntile = blockIdx.y;

  const int seg0 = tid, seg1 = tid + 256;
  const u16* ga0 = A3 + (mtile * 128 + (seg0 >> 2)) * 512 + (seg0 & 3) * 8;
  const u16* ga1 = A3 + (mtile * 128 + (seg1 >> 2)) * 512 + (seg1 & 3) * 8;

  auto mkbases = [&](int seg, const u16*& gx, const u16*& gy) {
    int n = ntile * 128 + (seg >> 2);
    if (n > NCAPS - 1) n = NCAPS - 1;
    int b = n / NPIX, p = n % NPIX;
    int i = p / 25, j = p % 25;
    gx = x1p + ((b * 30 + i + 2) * 30 + (j + 2)) * 256 + (seg & 3) * 8;
    gy = y + n * 256 + (seg & 3) * 8;
  };
  const u16 *gx0, *gy0, *gx1, *gy1;
  mkbases(seg0, gx0, gy0);
  mkbases(seg1, gx1, gy1);

  floatx4 acc[4][4] = {};
  const int wm = wave & 1, wn = wave >> 1;
  const int lrow = lane & 15, kgrp = lane >> 4;

  for (int kc = 0; kc < 16; kc++) {
    const u16* s0 = (kc < 8) ? (gx0 + kc * 32) : (gy0 + (kc - 8) * 32);
    const u16* s1 = (kc < 8) ? (gx1 + kc * 32) : (gy1 + (kc - 8) * 32);
    GLDS16(ga0 + kc * 32, As + seg0 * 8);
    GLDS16(ga1 + kc * 32, As + seg1 * 8);
    GLDS16(s0, Bs + seg0 * 8);
    GLDS16(s1, Bs + seg1 * 8);
    __syncthreads();
    bf16x8 af[4], bfr[4];
#pragma unroll
    for (int tt = 0; tt < 4; tt++) {
      af[tt]  = *(const bf16x8*)(As + (wm * 64 + tt * 16 + lrow) * 32 + kgrp * 8);
      bfr[tt] = *(const bf16x8*)(Bs + (wn * 64 + tt * 16 + lrow) * 32 + kgrp * 8);
    }
#pragma unroll
    for (int tm = 0; tm < 4; tm++)
#pragma unroll
      for (int tn = 0; tn < 4; tn++)
        acc[tm][tn] = __builtin_amdgcn_mfma_f32_16x16x32_bf16(af[tm], bfr[tn], acc[tm][tn], 0, 0, 0);
    __syncthreads();
  }

  const int nb = ntile * 128 + wn * 64;
  const int fb = mtile * 128 + wm * 64 + kgrp * 4;
#pragma unroll
  for (int tn = 0; tn < 4; tn++) {
    int n = nb + tn * 16 + lrow;
    if (n < NCAPS) {
#pragma unroll
      for (int tm = 0; tm < 4; tm++) {
        int f0 = fb + tm * 16;
        float4 v;
        v.x = acc[tm][tn][0] + bias3[f0 + 0];
        v.y = acc[tm][tn][1] + bias3[f0 + 1];
        v.z = acc[tm][tn][2] + bias3[f0 + 2];
        v.w = acc[tm][tn][3] + bias3[f0 + 3];
        *(float4*)(z + n * 256 + f0) = v;
      }
    }
  }
}

// ============ caps section ============
// u layout: u[n][b*8+o]  (n-major, 256 floats per n)
// Routing thread = (b, e), tid = b*8+e.

__device__ __forceinline__ float dot8v(float4 a0, float4 a1, float4 b0, float4 b1) {
  float s = a0.x * b0.x;
  s = fmaf(a0.y, b0.y, s);
  s = fmaf(a0.z, b0.z, s);
  s = fmaf(a0.w, b0.w, s);
  s = fmaf(a1.x, b1.x, s);
  s = fmaf(a1.y, b1.y, s);
  s = fmaf(a1.z, b1.z, s);
  s = fmaf(a1.w, b1.w, s);
  return s;
}

// bf16 row (8 elements packed in uint4) dot fp32 u
__device__ __forceinline__ float dotrow(uint4 w, float4 ua, float4 ub) {
  float s = __uint_as_float(w.x << 16) * ua.x;
  s = fmaf(__uint_as_float(w.x & 0xffff0000u), ua.y, s);
  s = fmaf(__uint_as_float(w.y << 16), ua.z, s);
  s = fmaf(__uint_as_float(w.y & 0xffff0000u), ua.w, s);
  s = fmaf(__uint_as_float(w.z << 16), ub.x, s);
  s = fmaf(__uint_as_float(w.z & 0xffff0000u), ub.y, s);
  s = fmaf(__uint_as_float(w.w << 16), ub.z, s);
  s = fmaf(__uint_as_float(w.w & 0xffff0000u), ub.w, s);
  return s;
}

// u[n][b*8+o] = pcb[n][o] + caps[b][n][:] . pcw[n][o][:]
__global__ void caps_u(const float* __restrict__ z, const float* __restrict__ pcw,
                       const float* __restrict__ pcb, float* __restrict__ u) {
  const int tid = threadIdx.x;
  const int b = tid >> 3, o = tid & 7;
  for (int k = 0; k < 8; k++) {
    const int n = blockIdx.x * 8 + k;
    const int g = n / NPIX, p = n % NPIX;
    const float* zp = z + (b * NPIX + p) * 256 + g * 8;
    float4 c0 = *(const float4*)zp;
    float4 c1 = *(const float4*)(zp + 4);
    const float* pw = pcw + n * 64 + o * 8;
    float4 w0 = *(const float4*)pw;
    float4 w1 = *(const float4*)(pw + 4);
    u[n * 256 + tid] = pcb[n * 8 + o] + dot8v(w0, w1, c0, c1);
  }
}

// ---- routing pass, bf16 W: c = softmax_e(u_hat.vsum); Spart += c*u_hat ----
// 2-batch W loads (8 rows each) so VGPR fits 4 waves/SIMD.
__global__ __launch_bounds__(256, 4) void caps_accb(const float* __restrict__ u,
    const u16* __restrict__ Wb, const float* __restrict__ vsum,
    float* __restrict__ Spart) {
  const int tid = threadIdx.x;
  const int b = tid >> 3;
  const float* vp = vsum + tid * 16;
  const float4 V0 = *(const float4*)vp;
  const float4 V1 = *(const float4*)(vp + 4);
  const float4 V2 = *(const float4*)(vp + 8);
  const float4 V3 = *(const float4*)(vp + 12);
  float s0 = 0.f, s1 = 0.f, s2 = 0.f, s3 = 0.f, s4 = 0.f, s5 = 0.f, s6 = 0.f, s7 = 0.f;
  float s8 = 0.f, s9 = 0.f, s10 = 0.f, s11 = 0.f, s12 = 0.f, s13 = 0.f, s14 = 0.f, s15 = 0.f;
  const int n0 = blockIdx.x * 16;
  for (int it = 0; it < 16; it++) {
    const int n = n0 + it;
    const float* un = u + n * 256 + (b << 3);
    const float4 u0 = *(const float4*)un;
    const float4 u1 = *(const float4*)(un + 4);
    const u16* Wn = Wb + n * 1024 + (tid & 7) * 128;
    float h0, h1, h2, h3, h4, h5, h6, h7, h8, h9, h10, h11, h12, h13, h14, h15;
    {
      uint4 a0 = *(const uint4*)(Wn + 0);
      uint4 a1 = *(const uint4*)(Wn + 8);
      uint4 a2 = *(const uint4*)(Wn + 16);
      uint4 a3 = *(const uint4*)(Wn + 24);
      uint4 a4 = *(const uint4*)(Wn + 32);
      uint4 a5 = *(const uint4*)(Wn + 40);
      uint4 a6 = *(const uint4*)(Wn + 48);
      uint4 a7 = *(const uint4*)(Wn + 56);
      h0 = dotrow(a0, u0, u1); h1 = dotrow(a1, u0, u1);
      h2 = dotrow(a2, u0, u1); h3 = dotrow(a3, u0, u1);
      h4 = dotrow(a4, u0, u1); h5 = dotrow(a5, u0, u1);
      h6 = dotrow(a6, u0, u1); h7 = dotrow(a7, u0, u1);
    }
    {
      uint4 a0 = *(const uint4*)(Wn + 64);
      uint4 a1 = *(const uint4*)(Wn + 72);
      uint4 a2 = *(const uint4*)(Wn + 80);
      uint4 a3 = *(const uint4*)(Wn + 88);
      uint4 a4 = *(const uint4*)(Wn + 96);
      uint4 a5 = *(const uint4*)(Wn + 104);
      uint4 a6 = *(const uint4*)(Wn + 112);
      uint4 a7 = *(const uint4*)(Wn + 120);
      h8 = dotrow(a0, u0, u1);  h9 = dotrow(a1, u0, u1);
      h10 = dotrow(a2, u0, u1); h11 = dotrow(a3, u0, u1);
      h12 = dotrow(a4, u0, u1); h13 = dotrow(a5, u0, u1);
      h14 = dotrow(a6, u0, u1); h15 = dotrow(a7, u0, u1);
    }
    float blog = h0 * V0.x;
    blog = fmaf(h1, V0.y, blog);  blog = fmaf(h2, V0.z, blog);  blog = fmaf(h3, V0.w, blog);
    blog = fmaf(h4, V1.x, blog);  blog = fmaf(h5, V1.y, blog);  blog = fmaf(h6, V1.z, blog);
    blog = fmaf(h7, V1.w, blog);  blog = fmaf(h8, V2.x, blog);  blog = fmaf(h9, V2.y, blog);
    blog = fmaf(h10, V2.z, blog); blog = fmaf(h11, V2.w, blog); blog = fmaf(h12, V3.x, blog);
    blog = fmaf(h13, V3.y, blog); blog = fmaf(h14, V3.z, blog); blog = fmaf(h15, V3.w, blog);
    float m = blog;
    m = fmaxf(m, __shfl_xor(m, 1, 64));
    m = fmaxf(m, __shfl_xor(m, 2, 64));
    m = fmaxf(m, __shfl_xor(m, 4, 64));
    float ex = __expf(blog - m);
    float ss = ex;
    ss += __shfl_xor(ss, 1, 64);
    ss += __shfl_xor(ss, 2, 64);
    ss += __shfl_xor(ss, 4, 64);
    const float c = ex / ss;
    s0 = fmaf(c, h0, s0);   s1 = fmaf(c, h1, s1);   s2 = fmaf(c, h2, s2);   s3 = fmaf(c, h3, s3);
    s4 = fmaf(c, h4, s4);   s5 = fmaf(c, h5, s5);   s6 = fmaf(c, h6, s6);   s7 = fmaf(c, h7, s7);
    s8 = fmaf(c, h8, s8);   s9 = fmaf(c, h9, s9);   s10 = fmaf(c, h10, s10); s11 = fmaf(c, h11, s11);
    s12 = fmaf(c, h12, s12); s13 = fmaf(c, h13, s13); s14 = fmaf(c, h14, s14); s15 = fmaf(c, h15, s15);
  }
  float* Sp = Spart + blockIdx.x * 4096 + tid * 16;
  *(float4*)(Sp + 0)  = make_float4(s0, s1, s2, s3);
  *(float4*)(Sp + 4)  = make_float4(s4, s5, s6, s7);
  *(float4*)(Sp + 8)  = make_float4(s8, s9, s10, s11);
  *(float4*)(Sp + 12) = make_float4(s12, s13, s14, s15);
}

// ---- routing pass, fp32 W fallback (used when ws too small for Wb) ----
__global__ __launch_bounds__(256, 2) void caps_acc(const float* __restrict__ u,
    const float* __restrict__ W, const float* __restrict__ vsum,
    float* __restrict__ Spart) {
  const int tid = threadIdx.x;
  const int b = tid >> 3, e = tid & 7;
  const float* vp = vsum + tid * 16;
  const float4 V0 = *(const float4*)vp;
  const float4 V1 = *(const float4*)(vp + 4);
  const float4 V2 = *(const float4*)(vp + 8);
  const float4 V3 = *(const float4*)(vp + 12);
  float s0 = 0.f, s1 = 0.f, s2 = 0.f, s3 = 0.f, s4 = 0.f, s5 = 0.f, s6 = 0.f, s7 = 0.f;
  float s8 = 0.f, s9 = 0.f, s10 = 0.f, s11 = 0.f, s12 = 0.f, s13 = 0.f, s14 = 0.f, s15 = 0.f;
  const int n0 = blockIdx.x * 16;
  for (int it = 0; it < 16; it++) {
    const int n = n0 + it;
    const float* un = u + n * 256 + (b << 3);
    const float4 u0 = *(const float4*)un;
    const float4 u1 = *(const float4*)(un + 4);
    const float* Wn = W + n * 1024 + e * 128;
    float h0, h1, h2, h3, h4, h5, h6, h7, h8, h9, h10, h11, h12, h13, h14, h15;
#define OST(o, H) { float4 wa = *(const float4*)(Wn + (o) * 8); \
                    float4 wb = *(const float4*)(Wn + (o) * 8 + 4); \
                    H = dot8v(wa, wb, u0, u1); }
    OST(0, h0)  OST(1, h1)  OST(2, h2)  OST(3, h3)
    OST(4, h4)  OST(5, h5)  OST(6, h6)  OST(7, h7)
    OST(8, h8)  OST(9, h9)  OST(10, h10) OST(11, h11)
    OST(12, h12) OST(13, h13) OST(14, h14) OST(15, h15)
#undef OST
    float blog = h0 * V0.x;
    blog = fmaf(h1, V0.y, blog);  blog = fmaf(h2, V0.z, blog);  blog = fmaf(h3, V0.w, blog);
    blog = fmaf(h4, V1.x, blog);  blog = fmaf(h5, V1.y, blog);  blog = fmaf(h6, V1.z, blog);
    blog = fmaf(h7, V1.w, blog);  blog = fmaf(h8, V2.x, blog);  blog = fmaf(h9, V2.y, blog);
    blog = fmaf(h10, V2.z, blog); blog = fmaf(h11, V2.w, blog); blog = fmaf(h12, V3.x, blog);
    blog = fmaf(h13, V3.y, blog); blog = fmaf(h14, V3.z, blog); blog = fmaf(h15, V3.w, blog);
    float m = blog;
    m = fmaxf(m, __shfl_xor(m, 1, 64));
    m = fmaxf(m, __shfl_xor(m, 2, 64));
    m = fmaxf(m, __shfl_xor(m, 4, 64));
    float ex = __expf(blog - m);
    float ss = ex;
    ss += __shfl_xor(ss, 1, 64);
    ss += __shfl_xor(ss, 2, 64);
    ss += __shfl_xor(ss, 4, 64);
    const float c = ex / ss;
    s0 = fmaf(c, h0, s0);   s1 = fmaf(c, h1, s1);   s2 = fmaf(c, h2, s2);   s3 = fmaf(c, h3, s3);
    s4 = fmaf(c, h4, s4);   s5 = fmaf(c, h5, s5);   s6 = fmaf(c, h6, s6);   s7 = fmaf(c, h7, s7);
    s8 = fmaf(c, h8, s8);   s9 = fmaf(c, h9, s9);   s10 = fmaf(c, h10, s10); s11 = fmaf(c, h11, s11);
    s12 = fmaf(c, h12, s12); s13 = fmaf(c, h13, s13); s14 = fmaf(c, h14, s14); s15 = fmaf(c, h15, s15);
  }
  float* Sp = Spart + blockIdx.x * 4096 + tid * 16;
  *(float4*)(Sp + 0)  = make_float4(s0, s1, s2, s3);
  *(float4*)(Sp + 4)  = make_float4(s4, s5, s6, s7);
  *(float4*)(Sp + 8)  = make_float4(s8, s9, s10, s11);
  *(float4*)(Sp + 12) = make_float4(s12, s13, s14, s15);
}

// sum 1250 block-partials -> S[4096] via per-chunk partial + atomicAdd
// grid: (16 j-tiles, 25 row-chunks of 50); S must be zeroed before.
__global__ void caps_redA(const float* __restrict__ Spart, float* __restrict__ S) {
  const int j = blockIdx.x * 256 + threadIdx.x;
  const int r0 = blockIdx.y * 50;
  float a0 = 0.f, a1 = 0.f;
  for (int r = 0; r < 50; r += 2) {
    a0 += Spart[(r0 + r) * 4096 + j];
    a1 += Spart[(r0 + r + 1) * 4096 + j];
  }
  atomicAdd(&S[j], a0 + a1);
}

// squash(S) and set/accumulate vsum
__global__ void caps_v(const float* __restrict__ S, float* __restrict__ vsum, int add) {
  const int t = threadIdx.x;           // 256 = 32 b x 8 e
  const float* sp = S + t * 16;
  const float4 a0 = *(const float4*)sp;
  const float4 a1 = *(const float4*)(sp + 4);
  const float4 a2 = *(const float4*)(sp + 8);
  const float4 a3 = *(const float4*)(sp + 12);
  float n2 = a0.x * a0.x;
  n2 = fmaf(a0.y, a0.y, n2); n2 = fmaf(a0.z, a0.z, n2); n2 = fmaf(a0.w, a0.w, n2);
  n2 = fmaf(a1.x, a1.x, n2); n2 = fmaf(a1.y, a1.y, n2); n2 = fmaf(a1.z, a1.z, n2); n2 = fmaf(a1.w, a1.w, n2);
  n2 = fmaf(a2.x, a2.x, n2); n2 = fmaf(a2.y, a2.y, n2); n2 = fmaf(a2.z, a2.z, n2); n2 = fmaf(a2.w, a2.w, n2);
  n2 = fmaf(a3.x, a3.x, n2); n2 = fmaf(a3.y, a3.y, n2); n2 = fmaf(a3.z, a3.z, n2); n2 = fmaf(a3.w, a3.w, n2);
  const float n = sqrtf(n2);
  const float scale = n2 / ((1.f + n2) * (n + 1e-8f));
  float* vp = vsum + t * 16;
  float4 o0, o1, o2, o3;
  if (add) {
    o0 = *(float4*)(vp + 0); o1 = *(float4*)(vp + 4); o2 = *(float4*)(vp + 8); o3 = *(float4*)(vp + 12);
  } else {
    o0 = make_float4(0.f, 0.f, 0.f, 0.f); o1 = o0; o2 = o0; o3 = o0;
  }
  o0.x = fmaf(a0.x, scale, o0.x); o0.y = fmaf(a0.y, scale, o0.y);
  o0.z = fmaf(a0.z, scale, o0.z); o0.w = fmaf(a0.w, scale, o0.w);
  o1.x = fmaf(a1.x, scale, o1.x); o1.y = fmaf(a1.y, scale, o1.y);
  o1.z = fmaf(a1.z, scale, o1.z); o1.w = fmaf(a1.w, scale, o1.w);
  o2.x = fmaf(a2.x, scale, o2.x); o2.y = fmaf(a2.y, scale, o2.y);
  o2.z = fmaf(a2.z, scale, o2.z); o2.w = fmaf(a2.w, scale, o2.w);
  o3.x = fmaf(a3.x, scale, o3.x); o3.y = fmaf(a3.y, scale, o3.y);
  o3.z = fmaf(a3.z, scale, o3.z); o3.w = fmaf(a3.w, scale, o3.w);
  *(float4*)(vp + 0) = o0; *(float4*)(vp + 4) = o1;
  *(float4*)(vp + 8) = o2; *(float4*)(vp + 12) = o3;
}

// out[b*8+e] = || squash(S) ||
__global__ void caps_out(const float* __restrict__ S, float* __restrict__ out) {
  const int t = threadIdx.x;
  const float* sp = S + t * 16;
  const float4 a0 = *(const float4*)sp;
  const float4 a1 = *(const float4*)(sp + 4);
  const float4 a2 = *(const float4*)(sp + 8);
  const float4 a3 = *(const float4*)(sp + 12);
  float n2 = a0.x * a0.x;
  n2 = fmaf(a0.y, a0.y, n2); n2 = fmaf(a0.z, a0.z, n2); n2 = fmaf(a0.w, a0.w, n2);
  n2 = fmaf(a1.x, a1.x, n2); n2 = fmaf(a1.y, a1.y, n2); n2 = fmaf(a1.z, a1.z, n2); n2 = fmaf(a1.w, a1.w, n2);
  n2 = fmaf(a2.x, a2.x, n2); n2 = fmaf(a2.y, a2.y, n2); n2 = fmaf(a2.z, a2.z, n2); n2 = fmaf(a2.w, a2.w, n2);
  n2 = fmaf(a3.x, a3.x, n2); n2 = fmaf(a3.y, a3.y, n2); n2 = fmaf(a3.z, a3.z, n2); n2 = fmaf(a3.w, a3.w, n2);
  const float n = sqrtf(n2);
  out[t] = n * n2 / ((1.f + n2) * (n + 1e-8f));
}

extern "C" void kernel_launch(void* const* d_in, const int* in_sizes, int n_in,
                              void* d_out, int out_size, void* d_ws, size_t ws_size,
                              hipStream_t stream) {
  const float* x   = (const float*)d_in[0];
  const float* w1  = (const float*)d_in[1];
  const float* b1  = (const float*)d_in[2];
  const float* w2  = (const float*)d_in[3];
  const float* b2  = (const float*)d_in[4];
  const float* w3  = (const float*)d_in[5];
  const float* b3  = (const float*)d_in[6];
  const float* pcw = (const float*)d_in[7];
  const float* pcb = (const float*)d_in[8];
  const float* W   = (const float*)d_in[9];
  float* out = (float*)d_out;

  char* ws = (char*)d_ws;
  const bool use_bf16w = (ws_size >= (size_t)82000000);

  // Common early buffers (live until conv3):
  u16*   x1p = (u16*)(ws + 0);           // 14,745,600
  u16*   A2  = (u16*)(ws + 14745600);    //  4,718,592
  u16*   A3  = (u16*)(ws + 19464192);    //    262,144
  u16*   y   = (u16*)(ws + 19726336);    // 10,240,000  (ends 29,966,336)
  // conv2 split-K partials: 2 x 20,480,000 = 40,960,000 (dead after conv2_red)
  float* P   = (float*)(ws + 29966336);  // ends 70,926,336

  u16*   Wb;
  float *z, *Spart, *u, *S, *vs;
  if (use_bf16w) {
    // Wb overlays x1p/A2/A3/y/P-head (all dead after conv3); written after conv3.
    Wb    = (u16*)(ws + 0);              // 40,960,000
    z     = (float*)(ws + 40960000);     // 20,480,000 (overlays P tail; P dead)
    Spart = (float*)(ws + 40960000);     // reuses z (dead after caps_u)
    u     = (float*)(ws + 61440000);     // 20,480,000
    S     = (float*)(ws + 81920000);     // 16,384
    vs    = (float*)(ws + 81936384);     // 16,384
  } else {
    Wb    = nullptr;
    z     = (float*)(ws + 29966336);     // overlays P (dead by conv3)
    Spart = (float*)(ws + 29966336);
    u     = (float*)(ws + 50446336);
    S     = (float*)(ws + 70926336);
    vs    = (float*)(ws + 70942720);
  }

  hipMemsetAsync(x1p, 0, 14745600, stream);
  hipMemsetAsync(vs, 0, 16384, stream);

  prep_weights<<<9728, 256, 0, stream>>>(w2, w3, A2, A3);
  conv1_kernel<<<800, 256, 0, stream>>>(x, w1, b1, x1p);
  conv2_gemm<<<dim3(2, 157, 2), 256, 0, stream>>>(A2, x1p, P);
  conv2_red<<<5000, 256, 0, stream>>>(P, b2, y);
  conv3_gemm<<<dim3(2, 157), 256, 0, stream>>>(A3, x1p, y, b3, z);
  if (use_bf16w)
    prep_wb<<<20000, 256, 0, stream>>>(W, Wb);   // after conv3: x1p/A2/A3/y/P dead
  caps_u<<<2500, 256, 0, stream>>>(z, pcw, pcb, u);

  for (int pass = 0; pass < 3; pass++) {
    if (use_bf16w)
      caps_accb<<<1250, 256, 0, stream>>>(u, Wb, vs, Spart);
    else
      caps_acc<<<1250, 256, 0, stream>>>(u, W, vs, Spart);
    hipMemsetAsync(S, 0, 16384, stream);
    caps_redA<<<dim3(16, 25), 256, 0, stream>>>(Spart, S);
    if (pass == 0)      caps_v<<<1, 256, 0, stream>>>(S, vs, 0);
    else if (pass == 1) caps_v<<<1, 256, 0, stream>>>(S, vs, 1);
    else                caps_out<<<1, 256, 0, stream>>>(S, out);
  }
}

// Round 8
// 523.339 us; speedup vs baseline: 4.4067x; 1.5743x over previous
//
#include <hip/hip_runtime.h>

typedef unsigned short u16;
typedef __attribute__((ext_vector_type(8))) short bf16x8;
typedef __attribute__((ext_vector_type(4))) float floatx4;

#define NPIX 625
#define NCAPS 20000
#define K2 9216

__device__ __forceinline__ u16 f2bf(float f) {
  unsigned u = __float_as_uint(f);
  return (u16)((u + 0x7fffu + ((u >> 16) & 1u)) >> 16);
}

#define GLDS16(g, l) __builtin_amdgcn_global_load_lds( \
    (const __attribute__((address_space(1))) void*)(g), \
    (__attribute__((address_space(3))) void*)(l), 16, 0, 0)

// ---------- prep: weights -> bf16, conv2 reordered to [oc][tap][c] ----------
__global__ void prep_weights(const float* __restrict__ w2, const float* __restrict__ w3,
                             u16* __restrict__ A2, u16* __restrict__ A3) {
  int idx = blockIdx.x * 256 + threadIdx.x;
  if (idx < 256 * 36 * 256) {
    int oc = idx / 9216, r = idx % 9216;
    int t = r >> 8, c = r & 255;           // A2[oc][t*256+c] = w2[oc][c][t]
    A2[idx] = f2bf(w2[(oc * 256 + c) * 36 + t]);
  } else {
    int j = idx - 256 * 36 * 256;
    if (j < 256 * 512) A3[j] = f2bf(w3[j]);
  }
}

// ---------- prep: routing W -> bf16 swizzled+padded Wbs[n][e][136] ----------
// row (n,e,o): Wbs[n*1088 + e*136 + o*8 + i] = bf16(W[n][e][o][i]); 8 u16 pad/row-e.
__global__ void prep_wbs(const float* __restrict__ W, u16* __restrict__ Wbs) {
  int r = blockIdx.x * 256 + threadIdx.x;   // 2,560,000 rows of 8
  int n = r >> 7, eo = r & 127;
  int e = eo >> 4, o = eo & 15;
  const float* src = W + n * 1024 + eo * 8;
  const float4 v0 = *(const float4*)src;
  const float4 v1 = *(const float4*)(src + 4);
  u16* dst = Wbs + n * 1088 + e * 136 + o * 8;
  ushort4 p0, p1;
  p0.x = f2bf(v0.x); p0.y = f2bf(v0.y); p0.z = f2bf(v0.z); p0.w = f2bf(v0.w);
  p1.x = f2bf(v1.x); p1.y = f2bf(v1.y); p1.z = f2bf(v1.z); p1.w = f2bf(v1.w);
  *(ushort4*)dst = p0;
  *(ushort4*)(dst + 4) = p1;
}

// ---------- conv1: (B,1,54,54) -> x1p padded NHWC bf16 (B,30,30,256) ----------
__global__ void conv1_kernel(const float* __restrict__ x, const float* __restrict__ w1,
                             const float* __restrict__ b1, u16* __restrict__ x1p) {
  int blk = blockIdx.x;                  // 800 = 32 b * 25 rows
  int b = blk / 25, i = blk % 25;
  int f = threadIdx.x;
  float wreg[36];
#pragma unroll
  for (int k = 0; k < 36; k++) wreg[k] = w1[f * 36 + k];
  float bias = b1[f];
  const float* xb = x + b * 54 * 54 + (2 * i) * 54;
  for (int j = 0; j < 25; j++) {
    float acc = bias;
#pragma unroll
    for (int ki = 0; ki < 6; ki++)
#pragma unroll
      for (int kj = 0; kj < 6; kj++)
        acc = fmaf(xb[ki * 54 + 2 * j + kj], wreg[ki * 6 + kj], acc);
    x1p[(((b * 30 + i + 2) * 30) + (j + 2)) * 256 + f] = f2bf(fmaxf(acc, 0.f));
  }
}

// ---------- conv2 implicit GEMM, split-K=2, BK=64 per barrier ----------
__global__ __launch_bounds__(256) void conv2_gemm(const u16* __restrict__ A2,
    const u16* __restrict__ x1p, float* __restrict__ P) {
  __shared__ u16 As0[128 * 32];
  __shared__ u16 Bs0[128 * 32];
  __shared__ u16 As1[128 * 32];
  __shared__ u16 Bs1[128 * 32];
  const int tid = threadIdx.x;
  const int lane = tid & 63, wave = tid >> 6;
  const int mtile = blockIdx.x, ntile = blockIdx.y, kt = blockIdx.z;

  const int seg0 = tid, seg1 = tid + 256;
  const u16* gA0 = A2 + (mtile * 128 + (seg0 >> 2)) * K2 + (seg0 & 3) * 8 + kt * 4608;
  const u16* gA1 = A2 + (mtile * 128 + (seg1 >> 2)) * K2 + (seg1 & 3) * 8 + kt * 4608;

  auto pixbase = [&](int seg) {
    int n = ntile * 128 + (seg >> 2);
    if (n > NCAPS - 1) n = NCAPS - 1;
    int b = n / NPIX, p = n % NPIX;
    int i = p / 25, j = p % 25;
    return ((b * 30 + i) * 30 + j) * 256 + (seg & 3) * 8;
  };
  const u16* gb0 = x1p + pixbase(seg0);
  const u16* gb1 = x1p + pixbase(seg1);

  floatx4 acc[4][4] = {};
  const int wm = wave & 1, wn = wave >> 1;
  const int lrow = lane & 15, kgrp = lane >> 4;

  int kj = 0;
  int boff = 3 * kt * 30 * 256;          // ki = 3*kt, kj = 0
  for (int t = 0; t < 18; t++) {
#pragma unroll 1
    for (int cc = 0; cc < 8; cc += 2) {
      const int b0 = boff + cc * 32;
      GLDS16(gA0, As0 + seg0 * 8);
      GLDS16(gA1, As0 + seg1 * 8);
      GLDS16(gA0 + 32, As1 + seg0 * 8);
      GLDS16(gA1 + 32, As1 + seg1 * 8);
      GLDS16(gb0 + b0, Bs0 + seg0 * 8);
      GLDS16(gb1 + b0, Bs0 + seg1 * 8);
      GLDS16(gb0 + b0 + 32, Bs1 + seg0 * 8);
      GLDS16(gb1 + b0 + 32, Bs1 + seg1 * 8);
      gA0 += 64; gA1 += 64;
      __syncthreads();
      bf16x8 af[4], bfr[4];
#pragma unroll
      for (int tt = 0; tt < 4; tt++) {
        af[tt]  = *(const bf16x8*)(As0 + (wm * 64 + tt * 16 + lrow) * 32 + kgrp * 8);
        bfr[tt] = *(const bf16x8*)(Bs0 + (wn * 64 + tt * 16 + lrow) * 32 + kgrp * 8);
      }
#pragma unroll
      for (int tm = 0; tm < 4; tm++)
#pragma unroll
        for (int tn = 0; tn < 4; tn++)
          acc[tm][tn] = __builtin_amdgcn_mfma_f32_16x16x32_bf16(af[tm], bfr[tn], acc[tm][tn], 0, 0, 0);
#pragma unroll
      for (int tt = 0; tt < 4; tt++) {
        af[tt]  = *(const bf16x8*)(As1 + (wm * 64 + tt * 16 + lrow) * 32 + kgrp * 8);
        bfr[tt] = *(const bf16x8*)(Bs1 + (wn * 64 + tt * 16 + lrow) * 32 + kgrp * 8);
      }
#pragma unroll
      for (int tm = 0; tm < 4; tm++)
#pragma unroll
        for (int tn = 0; tn < 4; tn++)
          acc[tm][tn] = __builtin_amdgcn_mfma_f32_16x16x32_bf16(af[tm], bfr[tn], acc[tm][tn], 0, 0, 0);
      __syncthreads();
    }
    boff += 256;
    kj++;
    if (kj == 6) { kj = 0; boff += 6144; }   // advance to next kernel row
  }

  float* Pk = P + kt * 5120000;
  const int nb = ntile * 128 + wn * 64;
  const int ocb = mtile * 128 + wm * 64 + kgrp * 4;
#pragma unroll
  for (int tn = 0; tn < 4; tn++) {
    int n = nb + tn * 16 + lrow;
    if (n < NCAPS) {
#pragma unroll
      for (int tm = 0; tm < 4; tm++) {
        int oc = ocb + tm * 16;
        float4 v;
        v.x = acc[tm][tn][0]; v.y = acc[tm][tn][1];
        v.z = acc[tm][tn][2]; v.w = acc[tm][tn][3];
        *(float4*)(Pk + n * 256 + oc) = v;
      }
    }
  }
}

// ---------- conv2 split-K reduce: y = bf16(relu(P0+P1+bias)) ----------
__global__ void conv2_red(const float* __restrict__ P, const float* __restrict__ bias2,
                          u16* __restrict__ y) {
  const int idx = blockIdx.x * 256 + threadIdx.x;
  const float4 a = *(const float4*)(P + idx * 4);
  const float4 b = *(const float4*)(P + 5120000 + idx * 4);
  const float4 bs = *(const float4*)(bias2 + ((idx * 4) & 255));
  ushort4 pk;
  pk.x = f2bf(fmaxf(a.x + b.x + bs.x, 0.f));
  pk.y = f2bf(fmaxf(a.y + b.y + bs.y, 0.f));
  pk.z = f2bf(fmaxf(a.z + b.z + bs.z, 0.f));
  pk.w = f2bf(fmaxf(a.w + b.w + bs.w, 0.f));
  *(ushort4*)(y + idx * 4) = pk;
}

// ---------- conv3 1x1 GEMM: M=256(f) N=20000 K=512 (x1 | y) ----------
__global__ __launch_bounds__(256) void conv3_gemm(const u16* __restrict__ A3,
    const u16* __restrict__ x1p, const u16* __restrict__ y,
    const float* __restrict__ bias3, float* __restrict__ z) {
  __shared__ u16 As[128 * 32];
  __shared__ u16 Bs[128 * 32];
  const int tid = threadIdx.x;
  const int lane = tid & 63, wave = tid >> 6;
  const int mtile = blockIdx.x, ntile = blockIdx.y;

  const int seg0 = tid, seg1 = tid + 256;
  const u16* ga0 = A3 + (mtile * 128 + (seg0 >> 2)) * 512 + (seg0 & 3) * 8;
  const u16* ga1 = A3 + (mtile * 128 + (seg1 >> 2)) * 512 + (seg1 & 3) * 8;

  auto mkbases = [&](int seg, const u16*& gx, const u16*& gy) {
    int n = ntile * 128 + (seg >> 2);
    if (n > NCAPS - 1) n = NCAPS - 1;
    int b = n / NPIX, p = n % NPIX;
    int i = p / 25, j = p % 25;
    gx = x1p + ((b * 30 + i + 2) * 30 + (j + 2)) * 256 + (seg & 3) * 8;
    gy = y + n * 256 + (seg & 3) * 8;
  };
  const u16 *gx0, *gy0, *gx1, *gy1;
  mkbases(seg0, gx0, gy0);
  mkbases(seg1, gx1, gy1);

  floatx4 acc[4][4] = {};
  const int wm = wave & 1, wn = wave >> 1;
  const int lrow = lane & 15, kgrp = lane >> 4;

  for (int kc = 0; kc < 16; kc++) {
    const u16* s0 = (kc < 8) ? (gx0 + kc * 32) : (gy0 + (kc - 8) * 32);
    const u16* s1 = (kc < 8) ? (gx1 + kc * 32) : (gy1 + (kc - 8) * 32);
    GLDS16(ga0 + kc * 32, As + seg0 * 8);
    GLDS16(ga1 + kc * 32, As + seg1 * 8);
    GLDS16(s0, Bs + seg0 * 8);
    GLDS16(s1, Bs + seg1 * 8);
    __syncthreads();
    bf16x8 af[4], bfr[4];
#pragma unroll
    for (int tt = 0; tt < 4; tt++) {
      af[tt]  = *(const bf16x8*)(As + (wm * 64 + tt * 16 + lrow) * 32 + kgrp * 8);
      bfr[tt] = *(const bf16x8*)(Bs + (wn * 64 + tt * 16 + lrow) * 32 + kgrp * 8);
    }
#pragma unroll
    for (int tm = 0; tm < 4; tm++)
#pragma unroll
      for (int tn = 0; tn < 4; tn++)
        acc[tm][tn] = __builtin_amdgcn_mfma_f32_16x16x32_bf16(af[tm], bfr[tn], acc[tm][tn], 0, 0, 0);
    __syncthreads();
  }

  const int nb = ntile * 128 + wn * 64;
  const int fb = mtile * 128 + wm * 64 + kgrp * 4;
#pragma unroll
  for (int tn = 0; tn < 4; tn++) {
    int n = nb + tn * 16 + lrow;
    if (n < NCAPS) {
#pragma unroll
      for (int tm = 0; tm < 4; tm++) {
        int f0 = fb + tm * 16;
        float4 v;
        v.x = acc[tm][tn][0] + bias3[f0 + 0];
        v.y = acc[tm][tn][1] + bias3[f0 + 1];
        v.z = acc[tm][tn][2] + bias3[f0 + 2];
        v.w = acc[tm][tn][3] + bias3[f0 + 3];
        *(float4*)(z + n * 256 + f0) = v;
      }
    }
  }
}

// ============ caps section ============

__device__ __forceinline__ float dot8v(float4 a0, float4 a1, float4 b0, float4 b1) {
  float s = a0.x * b0.x;
  s = fmaf(a0.y, b0.y, s); s = fmaf(a0.z, b0.z, s); s = fmaf(a0.w, b0.w, s);
  s = fmaf(a1.x, b1.x, s); s = fmaf(a1.y, b1.y, s);
  s = fmaf(a1.z, b1.z, s); s = fmaf(a1.w, b1.w, s);
  return s;
}

// bf16 row (8 packed in uint4) dot fp32 u (as 2 float4)
__device__ __forceinline__ float dotrow(uint4 w, float4 ua, float4 ub) {
  float s = __uint_as_float(w.x << 16) * ua.x;
  s = fmaf(__uint_as_float(w.x & 0xffff0000u), ua.y, s);
  s = fmaf(__uint_as_float(w.y << 16), ua.z, s);
  s = fmaf(__uint_as_float(w.y & 0xffff0000u), ua.w, s);
  s = fmaf(__uint_as_float(w.z << 16), ub.x, s);
  s = fmaf(__uint_as_float(w.z & 0xffff0000u), ub.y, s);
  s = fmaf(__uint_as_float(w.w << 16), ub.z, s);
  s = fmaf(__uint_as_float(w.w & 0xffff0000u), ub.w, s);
  return s;
}

// ---- u (fp32 path, fallback): u[n][b*8+o] ----
__global__ void caps_u(const float* __restrict__ z, const float* __restrict__ pcw,
                       const float* __restrict__ pcb, float* __restrict__ u) {
  const int tid = threadIdx.x;
  const int b = tid >> 3, o = tid & 7;
  for (int k = 0; k < 8; k++) {
    const int n = blockIdx.x * 8 + k;
    const int g = n / NPIX, p = n % NPIX;
    const float* zp = z + (b * NPIX + p) * 256 + g * 8;
    float4 c0 = *(const float4*)zp;
    float4 c1 = *(const float4*)(zp + 4);
    const float* pw = pcw + n * 64 + o * 8;
    float4 w0 = *(const float4*)pw;
    float4 w1 = *(const float4*)(pw + 4);
    u[n * 256 + tid] = pcb[n * 8 + o] + dot8v(w0, w1, c0, c1);
  }
}

// ---- u packed bf16: u2[n][b][0..3] uints (8 bf16 per (n,b)) ----
__global__ void caps_u2(const float* __restrict__ z, const float* __restrict__ pcw,
                        const float* __restrict__ pcb, unsigned* __restrict__ u2) {
  const int tid = threadIdx.x;
  const int b = tid >> 3, o = tid & 7;
  for (int k = 0; k < 8; k++) {
    const int n = blockIdx.x * 8 + k;
    const int g = n / NPIX, p = n % NPIX;
    const float* zp = z + (b * NPIX + p) * 256 + g * 8;
    float4 c0 = *(const float4*)zp;
    float4 c1 = *(const float4*)(zp + 4);
    const float* pw = pcw + n * 64 + o * 8;
    float4 w0 = *(const float4*)pw;
    float4 w1 = *(const float4*)(pw + 4);
    const float myu = pcb[n * 8 + o] + dot8v(w0, w1, c0, c1);
    const float partner = __shfl_xor(myu, 1, 64);
    if (!(o & 1)) {
      unsigned pk = (unsigned)f2bf(myu) | ((unsigned)f2bf(partner) << 16);
      u2[n * 128 + b * 4 + (o >> 1)] = pk;
    }
  }
}

// ---- routing pass, LDS-staged bf16 W ----
// Block: 16 n; stage Wbs chunk (16*2176B = 34816B) via global_load_lds once,
// one barrier, then barrier-free loop. LDS row stride 272B -> bank 4(e+o)%32,
// conflict-free; 8x b-duplication is same-address broadcast (free).
__global__ __launch_bounds__(256, 4) void caps_accb2(const unsigned* __restrict__ u2,
    const u16* __restrict__ Wbs, const float* __restrict__ vsum,
    float* __restrict__ Spart) {
  __shared__ u16 Ws[16 * 1088];   // 34,816 B
  const int tid = threadIdx.x;
  const int b = tid >> 3, e = tid & 7;
  const int n0 = blockIdx.x * 16;

  const u16* gsrc = Wbs + n0 * 1088;
#pragma unroll
  for (int k = 0; k < 9; k++) {
    const int idx = k * 256 + tid;        // 16B units, 2176 total
    if (idx < 2176) GLDS16(gsrc + idx * 8, Ws + idx * 8);
  }

  const float* vp = vsum + tid * 16;
  const float4 V0 = *(const float4*)vp;
  const float4 V1 = *(const float4*)(vp + 4);
  const float4 V2 = *(const float4*)(vp + 8);
  const float4 V3 = *(const float4*)(vp + 12);
  float s0 = 0.f, s1 = 0.f, s2 = 0.f, s3 = 0.f, s4 = 0.f, s5 = 0.f, s6 = 0.f, s7 = 0.f;
  float s8 = 0.f, s9 = 0.f, s10 = 0.f, s11 = 0.f, s12 = 0.f, s13 = 0.f, s14 = 0.f, s15 = 0.f;

  __syncthreads();

  for (int it = 0; it < 16; it++) {
    const int n = n0 + it;
    // u: 8 bf16 packed in one uint4
    const uint4 up = *(const uint4*)(u2 + n * 128 + b * 4);
    float4 ua, ub;
    ua.x = __uint_as_float(up.x << 16); ua.y = __uint_as_float(up.x & 0xffff0000u);
    ua.z = __uint_as_float(up.y << 16); ua.w = __uint_as_float(up.y & 0xffff0000u);
    ub.x = __uint_as_float(up.z << 16); ub.y = __uint_as_float(up.z & 0xffff0000u);
    ub.z = __uint_as_float(up.w << 16); ub.w = __uint_as_float(up.w & 0xffff0000u);

    const u16* Wn = Ws + it * 1088 + e * 136;
    float h0, h1, h2, h3, h4, h5, h6, h7, h8, h9, h10, h11, h12, h13, h14, h15;
#define ROW(o, H) { uint4 w = *(const uint4*)(Wn + (o) * 8); H = dotrow(w, ua, ub); }
    ROW(0, h0)   ROW(1, h1)   ROW(2, h2)   ROW(3, h3)
    ROW(4, h4)   ROW(5, h5)   ROW(6, h6)   ROW(7, h7)
    ROW(8, h8)   ROW(9, h9)   ROW(10, h10) ROW(11, h11)
    ROW(12, h12) ROW(13, h13) ROW(14, h14) ROW(15, h15)
#undef ROW
    float blog = h0 * V0.x;
    blog = fmaf(h1, V0.y, blog);  blog = fmaf(h2, V0.z, blog);  blog = fmaf(h3, V0.w, blog);
    blog = fmaf(h4, V1.x, blog);  blog = fmaf(h5, V1.y, blog);  blog = fmaf(h6, V1.z, blog);
    blog = fmaf(h7, V1.w, blog);  blog = fmaf(h8, V2.x, blog);  blog = fmaf(h9, V2.y, blog);
    blog = fmaf(h10, V2.z, blog); blog = fmaf(h11, V2.w, blog); blog = fmaf(h12, V3.x, blog);
    blog = fmaf(h13, V3.y, blog); blog = fmaf(h14, V3.z, blog); blog = fmaf(h15, V3.w, blog);
    float m = blog;
    m = fmaxf(m, __shfl_xor(m, 1, 64));
    m = fmaxf(m, __shfl_xor(m, 2, 64));
    m = fmaxf(m, __shfl_xor(m, 4, 64));
    float ex = __expf(blog - m);
    float ss = ex;
    ss += __shfl_xor(ss, 1, 64);
    ss += __shfl_xor(ss, 2, 64);
    ss += __shfl_xor(ss, 4, 64);
    const float c = ex / ss;
    s0 = fmaf(c, h0, s0);   s1 = fmaf(c, h1, s1);   s2 = fmaf(c, h2, s2);   s3 = fmaf(c, h3, s3);
    s4 = fmaf(c, h4, s4);   s5 = fmaf(c, h5, s5);   s6 = fmaf(c, h6, s6);   s7 = fmaf(c, h7, s7);
    s8 = fmaf(c, h8, s8);   s9 = fmaf(c, h9, s9);   s10 = fmaf(c, h10, s10); s11 = fmaf(c, h11, s11);
    s12 = fmaf(c, h12, s12); s13 = fmaf(c, h13, s13); s14 = fmaf(c, h14, s14); s15 = fmaf(c, h15, s15);
  }
  float* Sp = Spart + blockIdx.x * 4096 + tid * 16;
  *(float4*)(Sp + 0)  = make_float4(s0, s1, s2, s3);
  *(float4*)(Sp + 4)  = make_float4(s4, s5, s6, s7);
  *(float4*)(Sp + 8)  = make_float4(s8, s9, s10, s11);
  *(float4*)(Sp + 12) = make_float4(s12, s13, s14, s15);
}

// ---- routing pass, fp32 W fallback (ws too small for staged path) ----
__global__ __launch_bounds__(256, 2) void caps_acc(const float* __restrict__ u,
    const float* __restrict__ W, const float* __restrict__ vsum,
    float* __restrict__ Spart) {
  const int tid = threadIdx.x;
  const int b = tid >> 3, e = tid & 7;
  const float* vp = vsum + tid * 16;
  const float4 V0 = *(const float4*)vp;
  const float4 V1 = *(const float4*)(vp + 4);
  const float4 V2 = *(const float4*)(vp + 8);
  const float4 V3 = *(const float4*)(vp + 12);
  float s0 = 0.f, s1 = 0.f, s2 = 0.f, s3 = 0.f, s4 = 0.f, s5 = 0.f, s6 = 0.f, s7 = 0.f;
  float s8 = 0.f, s9 = 0.f, s10 = 0.f, s11 = 0.f, s12 = 0.f, s13 = 0.f, s14 = 0.f, s15 = 0.f;
  const int n0 = blockIdx.x * 16;
  for (int it = 0; it < 16; it++) {
    const int n = n0 + it;
    const float* un = u + n * 256 + (b << 3);
    const float4 u0 = *(const float4*)un;
    const float4 u1 = *(const float4*)(un + 4);
    const float* Wn = W + n * 1024 + e * 128;
    float h0, h1, h2, h3, h4, h5, h6, h7, h8, h9, h10, h11, h12, h13, h14, h15;
#define OST(o, H) { float4 wa = *(const float4*)(Wn + (o) * 8); \
                    float4 wb = *(const float4*)(Wn + (o) * 8 + 4); \
                    H = dot8v(wa, wb, u0, u1); }
    OST(0, h0)  OST(1, h1)  OST(2, h2)  OST(3, h3)
    OST(4, h4)  OST(5, h5)  OST(6, h6)  OST(7, h7)
    OST(8, h8)  OST(9, h9)  OST(10, h10) OST(11, h11)
    OST(12, h12) OST(13, h13) OST(14, h14) OST(15, h15)
#undef OST
    float blog = h0 * V0.x;
    blog = fmaf(h1, V0.y, blog);  blog = fmaf(h2, V0.z, blog);  blog = fmaf(h3, V0.w, blog);
    blog = fmaf(h4, V1.x, blog);  blog = fmaf(h5, V1.y, blog);  blog = fmaf(h6, V1.z, blog);
    blog = fmaf(h7, V1.w, blog);  blog = fmaf(h8, V2.x, blog);  blog = fmaf(h9, V2.y, blog);
    blog = fmaf(h10, V2.z, blog); blog = fmaf(h11, V2.w, blog); blog = fmaf(h12, V3.x, blog);
    blog = fmaf(h13, V3.y, blog); blog = fmaf(h14, V3.z, blog); blog = fmaf(h15, V3.w, blog);
    float m = blog;
    m = fmaxf(m, __shfl_xor(m, 1, 64));
    m = fmaxf(m, __shfl_xor(m, 2, 64));
    m = fmaxf(m, __shfl_xor(m, 4, 64));
    float ex = __expf(blog - m);
    float ss = ex;
    ss += __shfl_xor(ss, 1, 64);
    ss += __shfl_xor(ss, 2, 64);
    ss += __shfl_xor(ss, 4, 64);
    const float c = ex / ss;
    s0 = fmaf(c, h0, s0);   s1 = fmaf(c, h1, s1);   s2 = fmaf(c, h2, s2);   s3 = fmaf(c, h3, s3);
    s4 = fmaf(c, h4, s4);   s5 = fmaf(c, h5, s5);   s6 = fmaf(c, h6, s6);   s7 = fmaf(c, h7, s7);
    s8 = fmaf(c, h8, s8);   s9 = fmaf(c, h9, s9);   s10 = fmaf(c, h10, s10); s11 = fmaf(c, h11, s11);
    s12 = fmaf(c, h12, s12); s13 = fmaf(c, h13, s13); s14 = fmaf(c, h14, s14); s15 = fmaf(c, h15, s15);
  }
  float* Sp = Spart + blockIdx.x * 4096 + tid * 16;
  *(float4*)(Sp + 0)  = make_float4(s0, s1, s2, s3);
  *(float4*)(Sp + 4)  = make_float4(s4, s5, s6, s7);
  *(float4*)(Sp + 8)  = make_float4(s8, s9, s10, s11);
  *(float4*)(Sp + 12) = make_float4(s12, s13, s14, s15);
}

// sum 1250 block-partials -> S[4096]; grid (16, 25); S zeroed before.
__global__ void caps_redA(const float* __restrict__ Spart, float* __restrict__ S) {
  const int j = blockIdx.x * 256 + threadIdx.x;
  const int r0 = blockIdx.y * 50;
  float a0 = 0.f, a1 = 0.f;
  for (int r = 0; r < 50; r += 2) {
    a0 += Spart[(r0 + r) * 4096 + j];
    a1 += Spart[(r0 + r + 1) * 4096 + j];
  }
  atomicAdd(&S[j], a0 + a1);
}

// squash(S) and set/accumulate vsum
__global__ void caps_v(const float* __restrict__ S, float* __restrict__ vsum, int add) {
  const int t = threadIdx.x;
  const float* sp = S + t * 16;
  const float4 a0 = *(const float4*)sp;
  const float4 a1 = *(const float4*)(sp + 4);
  const float4 a2 = *(const float4*)(sp + 8);
  const float4 a3 = *(const float4*)(sp + 12);
  float n2 = a0.x * a0.x;
  n2 = fmaf(a0.y, a0.y, n2); n2 = fmaf(a0.z, a0.z, n2); n2 = fmaf(a0.w, a0.w, n2);
  n2 = fmaf(a1.x, a1.x, n2); n2 = fmaf(a1.y, a1.y, n2); n2 = fmaf(a1.z, a1.z, n2); n2 = fmaf(a1.w, a1.w, n2);
  n2 = fmaf(a2.x, a2.x, n2); n2 = fmaf(a2.y, a2.y, n2); n2 = fmaf(a2.z, a2.z, n2); n2 = fmaf(a2.w, a2.w, n2);
  n2 = fmaf(a3.x, a3.x, n2); n2 = fmaf(a3.y, a3.y, n2); n2 = fmaf(a3.z, a3.z, n2); n2 = fmaf(a3.w, a3.w, n2);
  const float n = sqrtf(n2);
  const float scale = n2 / ((1.f + n2) * (n + 1e-8f));
  float* vp = vsum + t * 16;
  float4 o0, o1, o2, o3;
  if (add) {
    o0 = *(float4*)(vp + 0); o1 = *(float4*)(vp + 4); o2 = *(float4*)(vp + 8); o3 = *(float4*)(vp + 12);
  } else {
    o0 = make_float4(0.f, 0.f, 0.f, 0.f); o1 = o0; o2 = o0; o3 = o0;
  }
  o0.x = fmaf(a0.x, scale, o0.x); o0.y = fmaf(a0.y, scale, o0.y);
  o0.z = fmaf(a0.z, scale, o0.z); o0.w = fmaf(a0.w, scale, o0.w);
  o1.x = fmaf(a1.x, scale, o1.x); o1.y = fmaf(a1.y, scale, o1.y);
  o1.z = fmaf(a1.z, scale, o1.z); o1.w = fmaf(a1.w, scale, o1.w);
  o2.x = fmaf(a2.x, scale, o2.x); o2.y = fmaf(a2.y, scale, o2.y);
  o2.z = fmaf(a2.z, scale, o2.z); o2.w = fmaf(a2.w, scale, o2.w);
  o3.x = fmaf(a3.x, scale, o3.x); o3.y = fmaf(a3.y, scale, o3.y);
  o3.z = fmaf(a3.z, scale, o3.z); o3.w = fmaf(a3.w, scale, o3.w);
  *(float4*)(vp + 0) = o0; *(float4*)(vp + 4) = o1;
  *(float4*)(vp + 8) = o2; *(float4*)(vp + 12) = o3;
}

// out[b*8+e] = || squash(S) ||
__global__ void caps_out(const float* __restrict__ S, float* __restrict__ out) {
  const int t = threadIdx.x;
  const float* sp = S + t * 16;
  const float4 a0 = *(const float4*)sp;
  const float4 a1 = *(const float4*)(sp + 4);
  const float4 a2 = *(const float4*)(sp + 8);
  const float4 a3 = *(const float4*)(sp + 12);
  float n2 = a0.x * a0.x;
  n2 = fmaf(a0.y, a0.y, n2); n2 = fmaf(a0.z, a0.z, n2); n2 = fmaf(a0.w, a0.w, n2);
  n2 = fmaf(a1.x, a1.x, n2); n2 = fmaf(a1.y, a1.y, n2); n2 = fmaf(a1.z, a1.z, n2); n2 = fmaf(a1.w, a1.w, n2);
  n2 = fmaf(a2.x, a2.x, n2); n2 = fmaf(a2.y, a2.y, n2); n2 = fmaf(a2.z, a2.z, n2); n2 = fmaf(a2.w, a2.w, n2);
  n2 = fmaf(a3.x, a3.x, n2); n2 = fmaf(a3.y, a3.y, n2); n2 = fmaf(a3.z, a3.z, n2); n2 = fmaf(a3.w, a3.w, n2);
  const float n = sqrtf(n2);
  out[t] = n * n2 / ((1.f + n2) * (n + 1e-8f));
}

extern "C" void kernel_launch(void* const* d_in, const int* in_sizes, int n_in,
                              void* d_out, int out_size, void* d_ws, size_t ws_size,
                              hipStream_t stream) {
  const float* x   = (const float*)d_in[0];
  const float* w1  = (const float*)d_in[1];
  const float* b1  = (const float*)d_in[2];
  const float* w2  = (const float*)d_in[3];
  const float* b2  = (const float*)d_in[4];
  const float* w3  = (const float*)d_in[5];
  const float* b3  = (const float*)d_in[6];
  const float* pcw = (const float*)d_in[7];
  const float* pcb = (const float*)d_in[8];
  const float* W   = (const float*)d_in[9];
  float* out = (float*)d_out;

  char* ws = (char*)d_ws;
  const bool use_bf16w = (ws_size >= (size_t)75000000);

  // Early-phase buffers (live until conv3):
  u16*   x1p = (u16*)(ws + 0);           // 14,745,600
  u16*   A2  = (u16*)(ws + 14745600);    //  4,718,592
  u16*   A3  = (u16*)(ws + 19464192);    //    262,144
  u16*   y   = (u16*)(ws + 19726336);    // 10,240,000  (ends 29,966,336)
  float* P   = (float*)(ws + 29966336);  // 40,960,000  (ends 70,926,336; dead after conv2_red)

  u16* Wbs;
  unsigned* u2;
  float *z, *Spart, *u, *S, *vs;
  if (use_bf16w) {
    Wbs   = (u16*)(ws + 0);              // 43,520,000 (written after conv3)
    z     = (float*)(ws + 43520000);     // 20,480,000 (inside dead P; conv3 after conv2_red)
    Spart = (float*)(ws + 43520000);     // reuses z after caps_u2
    u2    = (unsigned*)(ws + 64000000);  // 10,240,000
    S     = (float*)(ws + 74240000);     // 16,384
    vs    = (float*)(ws + 74256384);     // 16,384
    u = nullptr;
  } else {
    Wbs = nullptr; u2 = nullptr;
    z     = (float*)(ws + 29966336);
    Spart = (float*)(ws + 29966336);
    u     = (float*)(ws + 50446336);
    S     = (float*)(ws + 70926336);
    vs    = (float*)(ws + 70942720);
  }

  hipMemsetAsync(x1p, 0, 14745600, stream);
  hipMemsetAsync(vs, 0, 16384, stream);

  prep_weights<<<9728, 256, 0, stream>>>(w2, w3, A2, A3);
  conv1_kernel<<<800, 256, 0, stream>>>(x, w1, b1, x1p);
  conv2_gemm<<<dim3(2, 157, 2), 256, 0, stream>>>(A2, x1p, P);
  conv2_red<<<5000, 256, 0, stream>>>(P, b2, y);
  conv3_gemm<<<dim3(2, 157), 256, 0, stream>>>(A3, x1p, y, b3, z);
  if (use_bf16w) {
    prep_wbs<<<10000, 256, 0, stream>>>(W, Wbs);  // x1p/A2/A3/y dead now
    caps_u2<<<2500, 256, 0, stream>>>(z, pcw, pcb, u2);
  } else {
    caps_u<<<2500, 256, 0, stream>>>(z, pcw, pcb, u);
  }

  for (int pass = 0; pass < 3; pass++) {
    if (use_bf16w)
      caps_accb2<<<1250, 256, 0, stream>>>(u2, Wbs, vs, Spart);
    else
      caps_acc<<<1250, 256, 0, stream>>>(u, W, vs, Spart);
    hipMemsetAsync(S, 0, 16384, stream);
    caps_redA<<<dim3(16, 25), 256, 0, stream>>>(Spart, S);
    if (pass == 0)      caps_v<<<1, 256, 0, stream>>>(S, vs, 0);
    else if (pass == 1) caps_v<<<1, 256, 0, stream>>>(S, vs, 1);
    else                caps_out<<<1, 256, 0, stream>>>(S, out);
  }
}

// Round 9
// 510.906 us; speedup vs baseline: 4.5140x; 1.0243x over previous
//
#include <hip/hip_runtime.h>

typedef unsigned short u16;
typedef __attribute__((ext_vector_type(8))) short bf16x8;
typedef __attribute__((ext_vector_type(4))) float floatx4;

#define NPIX 625
#define NCAPS 20000
#define K2 9216

__device__ __forceinline__ u16 f2bf(float f) {
  unsigned u = __float_as_uint(f);
  return (u16)((u + 0x7fffu + ((u >> 16) & 1u)) >> 16);
}

__device__ __forceinline__ float bf2f(unsigned v) {
  return __uint_as_float(v << 16);
}

#define GLDS16(g, l) __builtin_amdgcn_global_load_lds( \
    (const __attribute__((address_space(1))) void*)(g), \
    (__attribute__((address_space(3))) void*)(l), 16, 0, 0)

// ---------- prep: w2 -> A2[oc][t*256+c] (coalesced), w3 -> A3 ----------
// blocks 0..255: A2 transpose, block=oc, thread=c. Reads 36 contiguous floats
// (9 aligned float4; 144B/lane, wave footprint 9216B fully L1-reused),
// writes t-major (512B/wave coalesced). blocks 256..383: A3 straight copy.
__global__ void prep_weights2(const float* __restrict__ w2, const float* __restrict__ w3,
                              u16* __restrict__ A2, u16* __restrict__ A3) {
  if (blockIdx.x < 256) {
    const int oc = blockIdx.x, c = threadIdx.x;
    const float* src = w2 + (oc * 256 + c) * 36;
    float v[36];
#pragma unroll
    for (int k = 0; k < 9; k++) {
      const float4 q = *(const float4*)(src + k * 4);
      v[k * 4 + 0] = q.x; v[k * 4 + 1] = q.y; v[k * 4 + 2] = q.z; v[k * 4 + 3] = q.w;
    }
    u16* dst = A2 + oc * 9216 + c;
#pragma unroll
    for (int t = 0; t < 36; t++) dst[t * 256] = f2bf(v[t]);
  } else {
    const int j = (blockIdx.x - 256) * 1024 + threadIdx.x * 4;
    const float4 q = *(const float4*)(w3 + j);
    ushort4 p;
    p.x = f2bf(q.x); p.y = f2bf(q.y); p.z = f2bf(q.z); p.w = f2bf(q.w);
    *(ushort4*)(A3 + j) = p;
  }
}

// ---------- prep: routing W -> bf16 swizzled+padded Wbs[n][e][136] ----------
__global__ void prep_wbs(const float* __restrict__ W, u16* __restrict__ Wbs) {
  int r = blockIdx.x * 256 + threadIdx.x;   // 2,560,000 rows of 8
  int n = r >> 7, eo = r & 127;
  int e = eo >> 4, o = eo & 15;
  const float* src = W + n * 1024 + eo * 8;
  const float4 v0 = *(const float4*)src;
  const float4 v1 = *(const float4*)(src + 4);
  u16* dst = Wbs + n * 1088 + e * 136 + o * 8;
  ushort4 p0, p1;
  p0.x = f2bf(v0.x); p0.y = f2bf(v0.y); p0.z = f2bf(v0.z); p0.w = f2bf(v0.w);
  p1.x = f2bf(v1.x); p1.y = f2bf(v1.y); p1.z = f2bf(v1.z); p1.w = f2bf(v1.w);
  *(ushort4*)dst = p0;
  *(ushort4*)(dst + 4) = p1;
}

// ---------- conv1: (B,1,54,54) -> x1p padded NHWC bf16 (B,30,30,256) ----------
__global__ void conv1_kernel(const float* __restrict__ x, const float* __restrict__ w1,
                             const float* __restrict__ b1, u16* __restrict__ x1p) {
  int blk = blockIdx.x;                  // 800 = 32 b * 25 rows
  int b = blk / 25, i = blk % 25;
  int f = threadIdx.x;
  float wreg[36];
#pragma unroll
  for (int k = 0; k < 36; k++) wreg[k] = w1[f * 36 + k];
  float bias = b1[f];
  const float* xb = x + b * 54 * 54 + (2 * i) * 54;
  for (int j = 0; j < 25; j++) {
    float acc = bias;
#pragma unroll
    for (int ki = 0; ki < 6; ki++)
#pragma unroll
      for (int kj = 0; kj < 6; kj++)
        acc = fmaf(xb[ki * 54 + 2 * j + kj], wreg[ki * 6 + kj], acc);
    x1p[(((b * 30 + i + 2) * 30) + (j + 2)) * 256 + f] = f2bf(fmaxf(acc, 0.f));
  }
}

// ---------- conv2 implicit GEMM, split-K=4, bf16 partials, XCD-chunked ----------
// 1256 blocks = 8 xcd-combos x 157 ntiles. Block f: xcd=f&7 -> (kt,mtile)
// fixed per XCD, ntile=f>>3 marches -> per-XCD L2 holds one A2 slice (0.6MB)
// and sequential x1p windows. Each kt covers 9 taps = 36 BK64 iterations.
__global__ __launch_bounds__(256) void conv2_gemm(const u16* __restrict__ A2,
    const u16* __restrict__ x1p, u16* __restrict__ P) {
  __shared__ u16 As0[128 * 32];
  __shared__ u16 Bs0[128 * 32];
  __shared__ u16 As1[128 * 32];
  __shared__ u16 Bs1[128 * 32];
  const int tid = threadIdx.x;
  const int lane = tid & 63, wave = tid >> 6;
  const int f = blockIdx.x;
  const int xcd = f & 7, ntile = f >> 3;
  const int kt = xcd >> 1, mtile = xcd & 1;
  const int t0 = kt * 9;

  const int seg0 = tid, seg1 = tid + 256;
  const u16* gA0 = A2 + (mtile * 128 + (seg0 >> 2)) * K2 + (seg0 & 3) * 8 + t0 * 256;
  const u16* gA1 = A2 + (mtile * 128 + (seg1 >> 2)) * K2 + (seg1 & 3) * 8 + t0 * 256;

  auto pixbase = [&](int seg) {
    int n = ntile * 128 + (seg >> 2);
    if (n > NCAPS - 1) n = NCAPS - 1;
    int b = n / NPIX, p = n % NPIX;
    int i = p / 25, j = p % 25;
    return ((b * 30 + i) * 30 + j) * 256 + (seg & 3) * 8;
  };
  const u16* gb0 = x1p + pixbase(seg0);
  const u16* gb1 = x1p + pixbase(seg1);

  floatx4 acc[4][4] = {};
  const int wm = wave & 1, wn = wave >> 1;
  const int lrow = lane & 15, kgrp = lane >> 4;

  int kj = t0 % 6;
  int boff = ((t0 / 6) * 30 + kj) * 256;
  for (int t = 0; t < 9; t++) {
#pragma unroll 1
    for (int cc = 0; cc < 8; cc += 2) {
      const int b0 = boff + cc * 32;
      GLDS16(gA0, As0 + seg0 * 8);
      GLDS16(gA1, As0 + seg1 * 8);
      GLDS16(gA0 + 32, As1 + seg0 * 8);
      GLDS16(gA1 + 32, As1 + seg1 * 8);
      GLDS16(gb0 + b0, Bs0 + seg0 * 8);
      GLDS16(gb1 + b0, Bs0 + seg1 * 8);
      GLDS16(gb0 + b0 + 32, Bs1 + seg0 * 8);
      GLDS16(gb1 + b0 + 32, Bs1 + seg1 * 8);
      gA0 += 64; gA1 += 64;
      __syncthreads();
      bf16x8 af[4], bfr[4];
#pragma unroll
      for (int tt = 0; tt < 4; tt++) {
        af[tt]  = *(const bf16x8*)(As0 + (wm * 64 + tt * 16 + lrow) * 32 + kgrp * 8);
        bfr[tt] = *(const bf16x8*)(Bs0 + (wn * 64 + tt * 16 + lrow) * 32 + kgrp * 8);
      }
#pragma unroll
      for (int tm = 0; tm < 4; tm++)
#pragma unroll
        for (int tn = 0; tn < 4; tn++)
          acc[tm][tn] = __builtin_amdgcn_mfma_f32_16x16x32_bf16(af[tm], bfr[tn], acc[tm][tn], 0, 0, 0);
#pragma unroll
      for (int tt = 0; tt < 4; tt++) {
        af[tt]  = *(const bf16x8*)(As1 + (wm * 64 + tt * 16 + lrow) * 32 + kgrp * 8);
        bfr[tt] = *(const bf16x8*)(Bs1 + (wn * 64 + tt * 16 + lrow) * 32 + kgrp * 8);
      }
#pragma unroll
      for (int tm = 0; tm < 4; tm++)
#pragma unroll
        for (int tn = 0; tn < 4; tn++)
          acc[tm][tn] = __builtin_amdgcn_mfma_f32_16x16x32_bf16(af[tm], bfr[tn], acc[tm][tn], 0, 0, 0);
      __syncthreads();
    }
    boff += 256;
    kj++;
    if (kj == 6) { kj = 0; boff += 6144; }
  }

  u16* Pk = P + kt * 5120000;
  const int nb = ntile * 128 + wn * 64;
  const int ocb = mtile * 128 + wm * 64 + kgrp * 4;
#pragma unroll
  for (int tn = 0; tn < 4; tn++) {
    int n = nb + tn * 16 + lrow;
    if (n < NCAPS) {
#pragma unroll
      for (int tm = 0; tm < 4; tm++) {
        int oc = ocb + tm * 16;
        ushort4 pk;
        pk.x = f2bf(acc[tm][tn][0]);
        pk.y = f2bf(acc[tm][tn][1]);
        pk.z = f2bf(acc[tm][tn][2]);
        pk.w = f2bf(acc[tm][tn][3]);
        *(ushort4*)(Pk + n * 256 + oc) = pk;
      }
    }
  }
}

// ---------- conv2 split-K reduce: y = bf16(relu(sum P[0..3] + bias)) ----------
__global__ void conv2_red(const u16* __restrict__ P, const float* __restrict__ bias2,
                          u16* __restrict__ y) {
  const int idx = blockIdx.x * 256 + threadIdx.x;   // 1,280,000 groups of 4
  const ushort4 p0 = *(const ushort4*)(P + idx * 4);
  const ushort4 p1 = *(const ushort4*)(P + 5120000 + idx * 4);
  const ushort4 p2 = *(const ushort4*)(P + 10240000 + idx * 4);
  const ushort4 p3 = *(const ushort4*)(P + 15360000 + idx * 4);
  const float4 bs = *(const float4*)(bias2 + ((idx * 4) & 255));
  float sx = bf2f(p0.x) + bf2f(p1.x) + bf2f(p2.x) + bf2f(p3.x) + bs.x;
  float sy = bf2f(p0.y) + bf2f(p1.y) + bf2f(p2.y) + bf2f(p3.y) + bs.y;
  float sz = bf2f(p0.z) + bf2f(p1.z) + bf2f(p2.z) + bf2f(p3.z) + bs.z;
  float sw = bf2f(p0.w) + bf2f(p1.w) + bf2f(p2.w) + bf2f(p3.w) + bs.w;
  ushort4 pk;
  pk.x = f2bf(fmaxf(sx, 0.f));
  pk.y = f2bf(fmaxf(sy, 0.f));
  pk.z = f2bf(fmaxf(sz, 0.f));
  pk.w = f2bf(fmaxf(sw, 0.f));
  *(ushort4*)(y + idx * 4) = pk;
}

// ---------- conv3 1x1 GEMM: M=256(f) N=20000 K=512 (x1 | y) ----------
__global__ __launch_bounds__(256) void conv3_gemm(const u16* __restrict__ A3,
    const u16* __restrict__ x1p, const u16* __restrict__ y,
    const float* __restrict__ bias3, float* __restrict__ z) {
  __shared__ u16 As[128 * 32];
  __shared__ u16 Bs[128 * 32];
  const int tid = threadIdx.x;
  const int lane = tid & 63, wave = tid >> 6;
  const int mtile = blockIdx.x, ntile = blockIdx.y;

  const int seg0 = tid, seg1 = tid + 256;
  const u16* ga0 = A3 + (mtile * 128 + (seg0 >> 2)) * 512 + (seg0 & 3) * 8;
  const u16* ga1 = A3 + (mtile * 128 + (seg1 >> 2)) * 512 + (seg1 & 3) * 8;

  auto mkbases = [&](int seg, const u16*& gx, const u16*& gy) {
    int n = ntile * 128 + (seg >> 2);
    if (n > NCAPS - 1) n = NCAPS - 1;
    int b = n / NPIX, p = n % NPIX;
    int i = p / 25, j = p % 25;
    gx = x1p + ((b * 30 + i + 2) * 30 + (j + 2)) * 256 + (seg & 3) * 8;
    gy = y + n * 256 + (seg & 3) * 8;
  };
  const u16 *gx0, *gy0, *gx1, *gy1;
  mkbases(seg0, gx0, gy0);
  mkbases(seg1, gx1, gy1);

  floatx4 acc[4][4] = {};
  const int wm = wave & 1, wn = wave >> 1;
  const int lrow = lane & 15, kgrp = lane >> 4;

  for (int kc = 0; kc < 16; kc++) {
    const u16* s0 = (kc < 8) ? (gx0 + kc * 32) : (gy0 + (kc - 8) * 32);
    const u16* s1 = (kc < 8) ? (gx1 + kc * 32) : (gy1 + (kc - 8) * 32);
    GLDS16(ga0 + kc * 32, As + seg0 * 8);
    GLDS16(ga1 + kc * 32, As + seg1 * 8);
    GLDS16(s0, Bs + seg0 * 8);
    GLDS16(s1, Bs + seg1 * 8);
    __syncthreads();
    bf16x8 af[4], bfr[4];
#pragma unroll
    for (int tt = 0; tt < 4; tt++) {
      af[tt]  = *(const bf16x8*)(As + (wm * 64 + tt * 16 + lrow) * 32 + kgrp * 8);
      bfr[tt] = *(const bf16x8*)(Bs + (wn * 64 + tt * 16 + lrow) * 32 + kgrp * 8);
    }
#pragma unroll
    for (int tm = 0; tm < 4; tm++)
#pragma unroll
      for (int tn = 0; tn < 4; tn++)
        acc[tm][tn] = __builtin_amdgcn_mfma_f32_16x16x32_bf16(af[tm], bfr[tn], acc[tm][tn], 0, 0, 0);
    __syncthreads();
  }

  const int nb = ntile * 128 + wn * 64;
  const int fb = mtile * 128 + wm * 64 + kgrp * 4;
#pragma unroll
  for (int tn = 0; tn < 4; tn++) {
    int n = nb + tn * 16 + lrow;
    if (n < NCAPS) {
#pragma unroll
      for (int tm = 0; tm < 4; tm++) {
        int f0 = fb + tm * 16;
        float4 v;
        v.x = acc[tm][tn][0] + bias3[f0 + 0];
        v.y = acc[tm][tn][1] + bias3[f0 + 1];
        v.z = acc[tm][tn][2] + bias3[f0 + 2];
        v.w = acc[tm][tn][3] + bias3[f0 + 3];
        *(float4*)(z + n * 256 + f0) = v;
      }
    }
  }
}

// ============ caps section ============

__device__ __forceinline__ float dot8v(float4 a0, float4 a1, float4 b0, float4 b1) {
  float s = a0.x * b0.x;
  s = fmaf(a0.y, b0.y, s); s = fmaf(a0.z, b0.z, s); s = fmaf(a0.w, b0.w, s);
  s = fmaf(a1.x, b1.x, s); s = fmaf(a1.y, b1.y, s);
  s = fmaf(a1.z, b1.z, s); s = fmaf(a1.w, b1.w, s);
  return s;
}

__device__ __forceinline__ float dotrow(uint4 w, float4 ua, float4 ub) {
  float s = __uint_as_float(w.x << 16) * ua.x;
  s = fmaf(__uint_as_float(w.x & 0xffff0000u), ua.y, s);
  s = fmaf(__uint_as_float(w.y << 16), ua.z, s);
  s = fmaf(__uint_as_float(w.y & 0xffff0000u), ua.w, s);
  s = fmaf(__uint_as_float(w.z << 16), ub.x, s);
  s = fmaf(__uint_as_float(w.z & 0xffff0000u), ub.y, s);
  s = fmaf(__uint_as_float(w.w << 16), ub.z, s);
  s = fmaf(__uint_as_float(w.w & 0xffff0000u), ub.w, s);
  return s;
}

// ---- u (fp32 path, fallback): u[n][b*8+o] ----
__global__ void caps_u(const float* __restrict__ z, const float* __restrict__ pcw,
                       const float* __restrict__ pcb, float* __restrict__ u) {
  const int tid = threadIdx.x;
  const int b = tid >> 3, o = tid & 7;
  for (int k = 0; k < 8; k++) {
    const int n = blockIdx.x * 8 + k;
    const int g = n / NPIX, p = n % NPIX;
    const float* zp = z + (b * NPIX + p) * 256 + g * 8;
    float4 c0 = *(const float4*)zp;
    float4 c1 = *(const float4*)(zp + 4);
    const float* pw = pcw + n * 64 + o * 8;
    float4 w0 = *(const float4*)pw;
    float4 w1 = *(const float4*)(pw + 4);
    u[n * 256 + tid] = pcb[n * 8 + o] + dot8v(w0, w1, c0, c1);
  }
}

// ---- u packed bf16: u2[n][b][0..3] uints (8 bf16 per (n,b)) ----
__global__ void caps_u2(const float* __restrict__ z, const float* __restrict__ pcw,
                        const float* __restrict__ pcb, unsigned* __restrict__ u2) {
  const int tid = threadIdx.x;
  const int b = tid >> 3, o = tid & 7;
  for (int k = 0; k < 8; k++) {
    const int n = blockIdx.x * 8 + k;
    const int g = n / NPIX, p = n % NPIX;
    const float* zp = z + (b * NPIX + p) * 256 + g * 8;
    float4 c0 = *(const float4*)zp;
    float4 c1 = *(const float4*)(zp + 4);
    const float* pw = pcw + n * 64 + o * 8;
    float4 w0 = *(const float4*)pw;
    float4 w1 = *(const float4*)(pw + 4);
    const float myu = pcb[n * 8 + o] + dot8v(w0, w1, c0, c1);
    const float partner = __shfl_xor(myu, 1, 64);
    if (!(o & 1)) {
      unsigned pk = (unsigned)f2bf(myu) | ((unsigned)f2bf(partner) << 16);
      u2[n * 128 + b * 4 + (o >> 1)] = pk;
    }
  }
}

// ---- routing pass, LDS-staged bf16 W (conflict-free 272B e-row stride) ----
__global__ __launch_bounds__(256, 4) void caps_accb2(const unsigned* __restrict__ u2,
    const u16* __restrict__ Wbs, const float* __restrict__ vsum,
    float* __restrict__ Spart) {
  __shared__ u16 Ws[16 * 1088];   // 34,816 B
  const int tid = threadIdx.x;
  const int b = tid >> 3, e = tid & 7;
  const int n0 = blockIdx.x * 16;

  const u16* gsrc = Wbs + n0 * 1088;
#pragma unroll
  for (int k = 0; k < 9; k++) {
    const int idx = k * 256 + tid;
    if (idx < 2176) GLDS16(gsrc + idx * 8, Ws + idx * 8);
  }

  const float* vp = vsum + tid * 16;
  const float4 V0 = *(const float4*)vp;
  const float4 V1 = *(const float4*)(vp + 4);
  const float4 V2 = *(const float4*)(vp + 8);
  const float4 V3 = *(const float4*)(vp + 12);
  float s0 = 0.f, s1 = 0.f, s2 = 0.f, s3 = 0.f, s4 = 0.f, s5 = 0.f, s6 = 0.f, s7 = 0.f;
  float s8 = 0.f, s9 = 0.f, s10 = 0.f, s11 = 0.f, s12 = 0.f, s13 = 0.f, s14 = 0.f, s15 = 0.f;

  __syncthreads();

  for (int it = 0; it < 16; it++) {
    const int n = n0 + it;
    const uint4 up = *(const uint4*)(u2 + n * 128 + b * 4);
    float4 ua, ub;
    ua.x = __uint_as_float(up.x << 16); ua.y = __uint_as_float(up.x & 0xffff0000u);
    ua.z = __uint_as_float(up.y << 16); ua.w = __uint_as_float(up.y & 0xffff0000u);
    ub.x = __uint_as_float(up.z << 16); ub.y = __uint_as_float(up.z & 0xffff0000u);
    ub.z = __uint_as_float(up.w << 16); ub.w = __uint_as_float(up.w & 0xffff0000u);

    const u16* Wn = Ws + it * 1088 + e * 136;
    float h0, h1, h2, h3, h4, h5, h6, h7, h8, h9, h10, h11, h12, h13, h14, h15;
#define ROW(o, H) { uint4 w = *(const uint4*)(Wn + (o) * 8); H = dotrow(w, ua, ub); }
    ROW(0, h0)   ROW(1, h1)   ROW(2, h2)   ROW(3, h3)
    ROW(4, h4)   ROW(5, h5)   ROW(6, h6)   ROW(7, h7)
    ROW(8, h8)   ROW(9, h9)   ROW(10, h10) ROW(11, h11)
    ROW(12, h12) ROW(13, h13) ROW(14, h14) ROW(15, h15)
#undef ROW
    float blog = h0 * V0.x;
    blog = fmaf(h1, V0.y, blog);  blog = fmaf(h2, V0.z, blog);  blog = fmaf(h3, V0.w, blog);
    blog = fmaf(h4, V1.x, blog);  blog = fmaf(h5, V1.y, blog);  blog = fmaf(h6, V1.z, blog);
    blog = fmaf(h7, V1.w, blog);  blog = fmaf(h8, V2.x, blog);  blog = fmaf(h9, V2.y, blog);
    blog = fmaf(h10, V2.z, blog); blog = fmaf(h11, V2.w, blog); blog = fmaf(h12, V3.x, blog);
    blog = fmaf(h13, V3.y, blog); blog = fmaf(h14, V3.z, blog); blog = fmaf(h15, V3.w, blog);
    float m = blog;
    m = fmaxf(m, __shfl_xor(m, 1, 64));
    m = fmaxf(m, __shfl_xor(m, 2, 64));
    m = fmaxf(m, __shfl_xor(m, 4, 64));
    float ex = __expf(blog - m);
    float ss = ex;
    ss += __shfl_xor(ss, 1, 64);
    ss += __shfl_xor(ss, 2, 64);
    ss += __shfl_xor(ss, 4, 64);
    const float c = ex / ss;
    s0 = fmaf(c, h0, s0);   s1 = fmaf(c, h1, s1);   s2 = fmaf(c, h2, s2);   s3 = fmaf(c, h3, s3);
    s4 = fmaf(c, h4, s4);   s5 = fmaf(c, h5, s5);   s6 = fmaf(c, h6, s6);   s7 = fmaf(c, h7, s7);
    s8 = fmaf(c, h8, s8);   s9 = fmaf(c, h9, s9);   s10 = fmaf(c, h10, s10); s11 = fmaf(c, h11, s11);
    s12 = fmaf(c, h12, s12); s13 = fmaf(c, h13, s13); s14 = fmaf(c, h14, s14); s15 = fmaf(c, h15, s15);
  }
  float* Sp = Spart + blockIdx.x * 4096 + tid * 16;
  *(float4*)(Sp + 0)  = make_float4(s0, s1, s2, s3);
  *(float4*)(Sp + 4)  = make_float4(s4, s5, s6, s7);
  *(float4*)(Sp + 8)  = make_float4(s8, s9, s10, s11);
  *(float4*)(Sp + 12) = make_float4(s12, s13, s14, s15);
}

// ---- routing pass, fp32 W fallback ----
__global__ __launch_bounds__(256, 2) void caps_acc(const float* __restrict__ u,
    const float* __restrict__ W, const float* __restrict__ vsum,
    float* __restrict__ Spart) {
  const int tid = threadIdx.x;
  const int b = tid >> 3, e = tid & 7;
  const float* vp = vsum + tid * 16;
  const float4 V0 = *(const float4*)vp;
  const float4 V1 = *(const float4*)(vp + 4);
  const float4 V2 = *(const float4*)(vp + 8);
  const float4 V3 = *(const float4*)(vp + 12);
  float s0 = 0.f, s1 = 0.f, s2 = 0.f, s3 = 0.f, s4 = 0.f, s5 = 0.f, s6 = 0.f, s7 = 0.f;
  float s8 = 0.f, s9 = 0.f, s10 = 0.f, s11 = 0.f, s12 = 0.f, s13 = 0.f, s14 = 0.f, s15 = 0.f;
  const int n0 = blockIdx.x * 16;
  for (int it = 0; it < 16; it++) {
    const int n = n0 + it;
    const float* un = u + n * 256 + (b << 3);
    const float4 u0 = *(const float4*)un;
    const float4 u1 = *(const float4*)(un + 4);
    const float* Wn = W + n * 1024 + e * 128;
    float h0, h1, h2, h3, h4, h5, h6, h7, h8, h9, h10, h11, h12, h13, h14, h15;
#define OST(o, H) { float4 wa = *(const float4*)(Wn + (o) * 8); \
                    float4 wb = *(const float4*)(Wn + (o) * 8 + 4); \
                    H = dot8v(wa, wb, u0, u1); }
    OST(0, h0)  OST(1, h1)  OST(2, h2)  OST(3, h3)
    OST(4, h4)  OST(5, h5)  OST(6, h6)  OST(7, h7)
    OST(8, h8)  OST(9, h9)  OST(10, h10) OST(11, h11)
    OST(12, h12) OST(13, h13) OST(14, h14) OST(15, h15)
#undef OST
    float blog = h0 * V0.x;
    blog = fmaf(h1, V0.y, blog);  blog = fmaf(h2, V0.z, blog);  blog = fmaf(h3, V0.w, blog);
    blog = fmaf(h4, V1.x, blog);  blog = fmaf(h5, V1.y, blog);  blog = fmaf(h6, V1.z, blog);
    blog = fmaf(h7, V1.w, blog);  blog = fmaf(h8, V2.x, blog);  blog = fmaf(h9, V2.y, blog);
    blog = fmaf(h10, V2.z, blog); blog = fmaf(h11, V2.w, blog); blog = fmaf(h12, V3.x, blog);
    blog = fmaf(h13, V3.y, blog); blog = fmaf(h14, V3.z, blog); blog = fmaf(h15, V3.w, blog);
    float m = blog;
    m = fmaxf(m, __shfl_xor(m, 1, 64));
    m = fmaxf(m, __shfl_xor(m, 2, 64));
    m = fmaxf(m, __shfl_xor(m, 4, 64));
    float ex = __expf(blog - m);
    float ss = ex;
    ss += __shfl_xor(ss, 1, 64);
    ss += __shfl_xor(ss, 2, 64);
    ss += __shfl_xor(ss, 4, 64);
    const float c = ex / ss;
    s0 = fmaf(c, h0, s0);   s1 = fmaf(c, h1, s1);   s2 = fmaf(c, h2, s2);   s3 = fmaf(c, h3, s3);
    s4 = fmaf(c, h4, s4);   s5 = fmaf(c, h5, s5);   s6 = fmaf(c, h6, s6);   s7 = fmaf(c, h7, s7);
    s8 = fmaf(c, h8, s8);   s9 = fmaf(c, h9, s9);   s10 = fmaf(c, h10, s10); s11 = fmaf(c, h11, s11);
    s12 = fmaf(c, h12, s12); s13 = fmaf(c, h13, s13); s14 = fmaf(c, h14, s14); s15 = fmaf(c, h15, s15);
  }
  float* Sp = Spart + blockIdx.x * 4096 + tid * 16;
  *(float4*)(Sp + 0)  = make_float4(s0, s1, s2, s3);
  *(float4*)(Sp + 4)  = make_float4(s4, s5, s6, s7);
  *(float4*)(Sp + 8)  = make_float4(s8, s9, s10, s11);
  *(float4*)(Sp + 12) = make_float4(s12, s13, s14, s15);
}

// sum 1250 block-partials -> S[4096]; grid (16, 25); S zeroed before.
__global__ void caps_redA(const float* __restrict__ Spart, float* __restrict__ S) {
  const int j = blockIdx.x * 256 + threadIdx.x;
  const int r0 = blockIdx.y * 50;
  float a0 = 0.f, a1 = 0.f;
  for (int r = 0; r < 50; r += 2) {
    a0 += Spart[(r0 + r) * 4096 + j];
    a1 += Spart[(r0 + r + 1) * 4096 + j];
  }
  atomicAdd(&S[j], a0 + a1);
}

// squash(S) and set/accumulate vsum
__global__ void caps_v(const float* __restrict__ S, float* __restrict__ vsum, int add) {
  const int t = threadIdx.x;
  const float* sp = S + t * 16;
  const float4 a0 = *(const float4*)sp;
  const float4 a1 = *(const float4*)(sp + 4);
  const float4 a2 = *(const float4*)(sp + 8);
  const float4 a3 = *(const float4*)(sp + 12);
  float n2 = a0.x * a0.x;
  n2 = fmaf(a0.y, a0.y, n2); n2 = fmaf(a0.z, a0.z, n2); n2 = fmaf(a0.w, a0.w, n2);
  n2 = fmaf(a1.x, a1.x, n2); n2 = fmaf(a1.y, a1.y, n2); n2 = fmaf(a1.z, a1.z, n2); n2 = fmaf(a1.w, a1.w, n2);
  n2 = fmaf(a2.x, a2.x, n2); n2 = fmaf(a2.y, a2.y, n2); n2 = fmaf(a2.z, a2.z, n2); n2 = fmaf(a2.w, a2.w, n2);
  n2 = fmaf(a3.x, a3.x, n2); n2 = fmaf(a3.y, a3.y, n2); n2 = fmaf(a3.z, a3.z, n2); n2 = fmaf(a3.w, a3.w, n2);
  const float n = sqrtf(n2);
  const float scale = n2 / ((1.f + n2) * (n + 1e-8f));
  float* vp = vsum + t * 16;
  float4 o0, o1, o2, o3;
  if (add) {
    o0 = *(float4*)(vp + 0); o1 = *(float4*)(vp + 4); o2 = *(float4*)(vp + 8); o3 = *(float4*)(vp + 12);
  } else {
    o0 = make_float4(0.f, 0.f, 0.f, 0.f); o1 = o0; o2 = o0; o3 = o0;
  }
  o0.x = fmaf(a0.x, scale, o0.x); o0.y = fmaf(a0.y, scale, o0.y);
  o0.z = fmaf(a0.z, scale, o0.z); o0.w = fmaf(a0.w, scale, o0.w);
  o1.x = fmaf(a1.x, scale, o1.x); o1.y = fmaf(a1.y, scale, o1.y);
  o1.z = fmaf(a1.z, scale, o1.z); o1.w = fmaf(a1.w, scale, o1.w);
  o2.x = fmaf(a2.x, scale, o2.x); o2.y = fmaf(a2.y, scale, o2.y);
  o2.z = fmaf(a2.z, scale, o2.z); o2.w = fmaf(a2.w, scale, o2.w);
  o3.x = fmaf(a3.x, scale, o3.x); o3.y = fmaf(a3.y, scale, o3.y);
  o3.z = fmaf(a3.z, scale, o3.z); o3.w = fmaf(a3.w, scale, o3.w);
  *(float4*)(vp + 0) = o0; *(float4*)(vp + 4) = o1;
  *(float4*)(vp + 8) = o2; *(float4*)(vp + 12) = o3;
}

// out[b*8+e] = || squash(S) ||
__global__ void caps_out(const float* __restrict__ S, float* __restrict__ out) {
  const int t = threadIdx.x;
  const float* sp = S + t * 16;
  const float4 a0 = *(const float4*)sp;
  const float4 a1 = *(const float4*)(sp + 4);
  const float4 a2 = *(const float4*)(sp + 8);
  const float4 a3 = *(const float4*)(sp + 12);
  float n2 = a0.x * a0.x;
  n2 = fmaf(a0.y, a0.y, n2); n2 = fmaf(a0.z, a0.z, n2); n2 = fmaf(a0.w, a0.w, n2);
  n2 = fmaf(a1.x, a1.x, n2); n2 = fmaf(a1.y, a1.y, n2); n2 = fmaf(a1.z, a1.z, n2); n2 = fmaf(a1.w, a1.w, n2);
  n2 = fmaf(a2.x, a2.x, n2); n2 = fmaf(a2.y, a2.y, n2); n2 = fmaf(a2.z, a2.z, n2); n2 = fmaf(a2.w, a2.w, n2);
  n2 = fmaf(a3.x, a3.x, n2); n2 = fmaf(a3.y, a3.y, n2); n2 = fmaf(a3.z, a3.z, n2); n2 = fmaf(a3.w, a3.w, n2);
  const float n = sqrtf(n2);
  out[t] = n * n2 / ((1.f + n2) * (n + 1e-8f));
}

extern "C" void kernel_launch(void* const* d_in, const int* in_sizes, int n_in,
                              void* d_out, int out_size, void* d_ws, size_t ws_size,
                              hipStream_t stream) {
  const float* x   = (const float*)d_in[0];
  const float* w1  = (const float*)d_in[1];
  const float* b1  = (const float*)d_in[2];
  const float* w2  = (const float*)d_in[3];
  const float* b2  = (const float*)d_in[4];
  const float* w3  = (const float*)d_in[5];
  const float* b3  = (const float*)d_in[6];
  const float* pcw = (const float*)d_in[7];
  const float* pcb = (const float*)d_in[8];
  const float* W   = (const float*)d_in[9];
  float* out = (float*)d_out;

  char* ws = (char*)d_ws;
  const bool use_bf16w = (ws_size >= (size_t)75000000);

  // Early-phase buffers (live until conv3):
  u16*   x1p = (u16*)(ws + 0);           // 14,745,600
  u16*   A2  = (u16*)(ws + 14745600);    //  4,718,592
  u16*   A3  = (u16*)(ws + 19464192);    //    262,144
  u16*   y   = (u16*)(ws + 19726336);    // 10,240,000  (ends 29,966,336)
  u16*   P   = (u16*)(ws + 29966336);    // 4 x 10,240,000 B bf16 = 40,960,000 (dead after conv2_red)

  u16* Wbs;
  unsigned* u2;
  float *z, *Spart, *u, *S, *vs;
  if (use_bf16w) {
    Wbs   = (u16*)(ws + 0);              // 43,520,000 (written after conv3)
    z     = (float*)(ws + 43520000);     // 20,480,000 (inside dead P region)
    Spart = (float*)(ws + 43520000);     // reuses z after caps_u2
    u2    = (unsigned*)(ws + 64000000);  // 10,240,000
    S     = (float*)(ws + 74240000);     // 16,384
    vs    = (float*)(ws + 74256384);     // 16,384
    u = nullptr;
  } else {
    Wbs = nullptr; u2 = nullptr;
    z     = (float*)(ws + 29966336);
    Spart = (float*)(ws + 29966336);
    u     = (float*)(ws + 50446336);
    S     = (float*)(ws + 70926336);
    vs    = (float*)(ws + 70942720);
  }

  hipMemsetAsync(x1p, 0, 14745600, stream);
  hipMemsetAsync(vs, 0, 16384, stream);

  prep_weights2<<<384, 256, 0, stream>>>(w2, w3, A2, A3);
  conv1_kernel<<<800, 256, 0, stream>>>(x, w1, b1, x1p);
  conv2_gemm<<<1256, 256, 0, stream>>>(A2, x1p, P);
  conv2_red<<<5000, 256, 0, stream>>>(P, b2, y);
  conv3_gemm<<<dim3(2, 157), 256, 0, stream>>>(A3, x1p, y, b3, z);
  if (use_bf16w) {
    prep_wbs<<<10000, 256, 0, stream>>>(W, Wbs);
    caps_u2<<<2500, 256, 0, stream>>>(z, pcw, pcb, u2);
  } else {
    caps_u<<<2500, 256, 0, stream>>>(z, pcw, pcb, u);
  }

  for (int pass = 0; pass < 3; pass++) {
    if (use_bf16w)
      caps_accb2<<<1250, 256, 0, stream>>>(u2, Wbs, vs, Spart);
    else
      caps_acc<<<1250, 256, 0, stream>>>(u, W, vs, Spart);
    hipMemsetAsync(S, 0, 16384, stream);
    caps_redA<<<dim3(16, 25), 256, 0, stream>>>(Spart, S);
    if (pass == 0)      caps_v<<<1, 256, 0, stream>>>(S, vs, 0);
    else if (pass == 1) caps_v<<<1, 256, 0, stream>>>(S, vs, 1);
    else                caps_out<<<1, 256, 0, stream>>>(S, out);
  }
}

// Round 10
// 503.789 us; speedup vs baseline: 4.5778x; 1.0141x over previous
//
#include <hip/hip_runtime.h>

typedef unsigned short u16;
typedef __attribute__((ext_vector_type(8))) short bf16x8;
typedef __attribute__((ext_vector_type(4))) float floatx4;

#define NPIX 625
#define NCAPS 20000
#define K2 9216

__device__ __forceinline__ u16 f2bf(float f) {
  unsigned u = __float_as_uint(f);
  return (u16)((u + 0x7fffu + ((u >> 16) & 1u)) >> 16);
}

__device__ __forceinline__ float bf2f(unsigned v) {
  return __uint_as_float(v << 16);
}

#define GLDS16(g, l) __builtin_amdgcn_global_load_lds( \
    (const __attribute__((address_space(1))) void*)(g), \
    (__attribute__((address_space(3))) void*)(l), 16, 0, 0)

// ---------- prep: w2 -> A2c[combo][row 128][2304] (combo = kt*2+mtile) ----------
// block=oc, thread=c: reads 36 contiguous floats, scatters into per-combo
// contiguous slices so conv2 streams one 0.59MB region per block.
__global__ void prep_weights2(const float* __restrict__ w2, const float* __restrict__ w3,
                              u16* __restrict__ A2c, u16* __restrict__ A3) {
  if (blockIdx.x < 256) {
    const int oc = blockIdx.x, c = threadIdx.x;
    const float* src = w2 + (oc * 256 + c) * 36;
    float v[36];
#pragma unroll
    for (int k = 0; k < 9; k++) {
      const float4 q = *(const float4*)(src + k * 4);
      v[k * 4 + 0] = q.x; v[k * 4 + 1] = q.y; v[k * 4 + 2] = q.z; v[k * 4 + 3] = q.w;
    }
    const int mtile = oc >> 7, row = oc & 127;
#pragma unroll
    for (int t = 0; t < 36; t++) {
      const int kt = t / 9, tl = t % 9;
      A2c[(kt * 2 + mtile) * 294912 + row * 2304 + tl * 256 + c] = f2bf(v[t]);
    }
  } else {
    const int j = (blockIdx.x - 256) * 1024 + threadIdx.x * 4;
    const float4 q = *(const float4*)(w3 + j);
    ushort4 p;
    p.x = f2bf(q.x); p.y = f2bf(q.y); p.z = f2bf(q.z); p.w = f2bf(q.w);
    *(ushort4*)(A3 + j) = p;
  }
}

// ---------- prep: routing W -> bf16 swizzled+padded Wbs[n][e][136] ----------
__global__ void prep_wbs(const float* __restrict__ W, u16* __restrict__ Wbs) {
  int r = blockIdx.x * 256 + threadIdx.x;
  int n = r >> 7, eo = r & 127;
  int e = eo >> 4, o = eo & 15;
  const float* src = W + n * 1024 + eo * 8;
  const float4 v0 = *(const float4*)src;
  const float4 v1 = *(const float4*)(src + 4);
  u16* dst = Wbs + n * 1088 + e * 136 + o * 8;
  ushort4 p0, p1;
  p0.x = f2bf(v0.x); p0.y = f2bf(v0.y); p0.z = f2bf(v0.z); p0.w = f2bf(v0.w);
  p1.x = f2bf(v1.x); p1.y = f2bf(v1.y); p1.z = f2bf(v1.z); p1.w = f2bf(v1.w);
  *(ushort4*)dst = p0;
  *(ushort4*)(dst + 4) = p1;
}

// ---------- conv1: (B,1,54,54) -> x1p padded NHWC bf16 (B,30,30,256) ----------
__global__ void conv1_kernel(const float* __restrict__ x, const float* __restrict__ w1,
                             const float* __restrict__ b1, u16* __restrict__ x1p) {
  int blk = blockIdx.x;
  int b = blk / 25, i = blk % 25;
  int f = threadIdx.x;
  float wreg[36];
#pragma unroll
  for (int k = 0; k < 36; k++) wreg[k] = w1[f * 36 + k];
  float bias = b1[f];
  const float* xb = x + b * 54 * 54 + (2 * i) * 54;
  for (int j = 0; j < 25; j++) {
    float acc = bias;
#pragma unroll
    for (int ki = 0; ki < 6; ki++)
#pragma unroll
      for (int kj = 0; kj < 6; kj++)
        acc = fmaf(xb[ki * 54 + 2 * j + kj], wreg[ki * 6 + kj], acc);
    x1p[(((b * 30 + i + 2) * 30) + (j + 2)) * 256 + f] = f2bf(fmaxf(acc, 0.f));
  }
}

// ---------- conv2 implicit GEMM, split-K=4, bf16 partials ----------
// XCD-locality remap: blocks f with f&7==x (same XCD under round-robin
// dispatch) cover ~20 CONSECUTIVE ntiles x all 8 (kt,mtile) combos, so the
// shared x1p window stays in that XCD's L2 (round-9 had this inverted).
__global__ __launch_bounds__(256) void conv2_gemm(const u16* __restrict__ A2c,
    const u16* __restrict__ x1p, u16* __restrict__ P) {
  __shared__ u16 As0[128 * 32];
  __shared__ u16 Bs0[128 * 32];
  __shared__ u16 As1[128 * 32];
  __shared__ u16 Bs1[128 * 32];
  const int tid = threadIdx.x;
  const int lane = tid & 63, wave = tid >> 6;
  const int f = blockIdx.x;
  const int w = (f & 7) * 157 + (f >> 3);
  const int ntile = w >> 3, combo = w & 7;
  const int kt = combo >> 1, mtile = combo & 1;
  const int t0 = kt * 9;

  const int seg0 = tid, seg1 = tid + 256;
  const u16* gA0 = A2c + combo * 294912 + (seg0 >> 2) * 2304 + (seg0 & 3) * 8;
  const u16* gA1 = A2c + combo * 294912 + (seg1 >> 2) * 2304 + (seg1 & 3) * 8;

  auto pixbase = [&](int seg) {
    int n = ntile * 128 + (seg >> 2);
    if (n > NCAPS - 1) n = NCAPS - 1;
    int b = n / NPIX, p = n % NPIX;
    int i = p / 25, j = p % 25;
    return ((b * 30 + i) * 30 + j) * 256 + (seg & 3) * 8;
  };
  const u16* gb0 = x1p + pixbase(seg0);
  const u16* gb1 = x1p + pixbase(seg1);

  floatx4 acc[4][4] = {};
  const int wm = wave & 1, wn = wave >> 1;
  const int lrow = lane & 15, kgrp = lane >> 4;

  int kj = t0 % 6;
  int boff = ((t0 / 6) * 30 + kj) * 256;
  for (int t = 0; t < 9; t++) {
#pragma unroll 1
    for (int cc = 0; cc < 8; cc += 2) {
      const int b0 = boff + cc * 32;
      GLDS16(gA0, As0 + seg0 * 8);
      GLDS16(gA1, As0 + seg1 * 8);
      GLDS16(gA0 + 32, As1 + seg0 * 8);
      GLDS16(gA1 + 32, As1 + seg1 * 8);
      GLDS16(gb0 + b0, Bs0 + seg0 * 8);
      GLDS16(gb1 + b0, Bs0 + seg1 * 8);
      GLDS16(gb0 + b0 + 32, Bs1 + seg0 * 8);
      GLDS16(gb1 + b0 + 32, Bs1 + seg1 * 8);
      gA0 += 64; gA1 += 64;
      __syncthreads();
      bf16x8 af[4], bfr[4];
#pragma unroll
      for (int tt = 0; tt < 4; tt++) {
        af[tt]  = *(const bf16x8*)(As0 + (wm * 64 + tt * 16 + lrow) * 32 + kgrp * 8);
        bfr[tt] = *(const bf16x8*)(Bs0 + (wn * 64 + tt * 16 + lrow) * 32 + kgrp * 8);
      }
#pragma unroll
      for (int tm = 0; tm < 4; tm++)
#pragma unroll
        for (int tn = 0; tn < 4; tn++)
          acc[tm][tn] = __builtin_amdgcn_mfma_f32_16x16x32_bf16(af[tm], bfr[tn], acc[tm][tn], 0, 0, 0);
#pragma unroll
      for (int tt = 0; tt < 4; tt++) {
        af[tt]  = *(const bf16x8*)(As1 + (wm * 64 + tt * 16 + lrow) * 32 + kgrp * 8);
        bfr[tt] = *(const bf16x8*)(Bs1 + (wn * 64 + tt * 16 + lrow) * 32 + kgrp * 8);
      }
#pragma unroll
      for (int tm = 0; tm < 4; tm++)
#pragma unroll
        for (int tn = 0; tn < 4; tn++)
          acc[tm][tn] = __builtin_amdgcn_mfma_f32_16x16x32_bf16(af[tm], bfr[tn], acc[tm][tn], 0, 0, 0);
      __syncthreads();
    }
    boff += 256;
    kj++;
    if (kj == 6) { kj = 0; boff += 6144; }
  }

  u16* Pk = P + kt * 5120000;
  const int nb = ntile * 128 + wn * 64;
  const int ocb = mtile * 128 + wm * 64 + kgrp * 4;
#pragma unroll
  for (int tn = 0; tn < 4; tn++) {
    int n = nb + tn * 16 + lrow;
    if (n < NCAPS) {
#pragma unroll
      for (int tm = 0; tm < 4; tm++) {
        int oc = ocb + tm * 16;
        ushort4 pk;
        pk.x = f2bf(acc[tm][tn][0]);
        pk.y = f2bf(acc[tm][tn][1]);
        pk.z = f2bf(acc[tm][tn][2]);
        pk.w = f2bf(acc[tm][tn][3]);
        *(ushort4*)(Pk + n * 256 + oc) = pk;
      }
    }
  }
}

// ---------- conv2 split-K reduce: y = bf16(relu(sum P[0..3] + bias)) ----------
__global__ void conv2_red(const u16* __restrict__ P, const float* __restrict__ bias2,
                          u16* __restrict__ y) {
  const int idx = blockIdx.x * 256 + threadIdx.x;
  const ushort4 p0 = *(const ushort4*)(P + idx * 4);
  const ushort4 p1 = *(const ushort4*)(P + 5120000 + idx * 4);
  const ushort4 p2 = *(const ushort4*)(P + 10240000 + idx * 4);
  const ushort4 p3 = *(const ushort4*)(P + 15360000 + idx * 4);
  const float4 bs = *(const float4*)(bias2 + ((idx * 4) & 255));
  float sx = bf2f(p0.x) + bf2f(p1.x) + bf2f(p2.x) + bf2f(p3.x) + bs.x;
  float sy = bf2f(p0.y) + bf2f(p1.y) + bf2f(p2.y) + bf2f(p3.y) + bs.y;
  float sz = bf2f(p0.z) + bf2f(p1.z) + bf2f(p2.z) + bf2f(p3.z) + bs.z;
  float sw = bf2f(p0.w) + bf2f(p1.w) + bf2f(p2.w) + bf2f(p3.w) + bs.w;
  ushort4 pk;
  pk.x = f2bf(fmaxf(sx, 0.f));
  pk.y = f2bf(fmaxf(sy, 0.f));
  pk.z = f2bf(fmaxf(sz, 0.f));
  pk.w = f2bf(fmaxf(sw, 0.f));
  *(ushort4*)(y + idx * 4) = pk;
}

// ---------- conv3 1x1 GEMM: M=256(f) N=20000 K=512 (x1 | y) ----------
__global__ __launch_bounds__(256) void conv3_gemm(const u16* __restrict__ A3,
    const u16* __restrict__ x1p, const u16* __restrict__ y,
    const float* __restrict__ bias3, float* __restrict__ z) {
  __shared__ u16 As[128 * 32];
  __shared__ u16 Bs[128 * 32];
  const int tid = threadIdx.x;
  const int lane = tid & 63, wave = tid >> 6;
  const int mtile = blockIdx.x, ntile = blockIdx.y;

  const int seg0 = tid, seg1 = tid + 256;
  const u16* ga0 = A3 + (mtile * 128 + (seg0 >> 2)) * 512 + (seg0 & 3) * 8;
  const u16* ga1 = A3 + (mtile * 128 + (seg1 >> 2)) * 512 + (seg1 & 3) * 8;

  auto mkbases = [&](int seg, const u16*& gx, const u16*& gy) {
    int n = ntile * 128 + (seg >> 2);
    if (n > NCAPS - 1) n = NCAPS - 1;
    int b = n / NPIX, p = n % NPIX;
    int i = p / 25, j = p % 25;
    gx = x1p + ((b * 30 + i + 2) * 30 + (j + 2)) * 256 + (seg & 3) * 8;
    gy = y + n * 256 + (seg & 3) * 8;
  };
  const u16 *gx0, *gy0, *gx1, *gy1;
  mkbases(seg0, gx0, gy0);
  mkbases(seg1, gx1, gy1);

  floatx4 acc[4][4] = {};
  const int wm = wave & 1, wn = wave >> 1;
  const int lrow = lane & 15, kgrp = lane >> 4;

  for (int kc = 0; kc < 16; kc++) {
    const u16* s0 = (kc < 8) ? (gx0 + kc * 32) : (gy0 + (kc - 8) * 32);
    const u16* s1 = (kc < 8) ? (gx1 + kc * 32) : (gy1 + (kc - 8) * 32);
    GLDS16(ga0 + kc * 32, As + seg0 * 8);
    GLDS16(ga1 + kc * 32, As + seg1 * 8);
    GLDS16(s0, Bs + seg0 * 8);
    GLDS16(s1, Bs + seg1 * 8);
    __syncthreads();
    bf16x8 af[4], bfr[4];
#pragma unroll
    for (int tt = 0; tt < 4; tt++) {
      af[tt]  = *(const bf16x8*)(As + (wm * 64 + tt * 16 + lrow) * 32 + kgrp * 8);
      bfr[tt] = *(const bf16x8*)(Bs + (wn * 64 + tt * 16 + lrow) * 32 + kgrp * 8);
    }
#pragma unroll
    for (int tm = 0; tm < 4; tm++)
#pragma unroll
      for (int tn = 0; tn < 4; tn++)
        acc[tm][tn] = __builtin_amdgcn_mfma_f32_16x16x32_bf16(af[tm], bfr[tn], acc[tm][tn], 0, 0, 0);
    __syncthreads();
  }

  const int nb = ntile * 128 + wn * 64;
  const int fb = mtile * 128 + wm * 64 + kgrp * 4;
#pragma unroll
  for (int tn = 0; tn < 4; tn++) {
    int n = nb + tn * 16 + lrow;
    if (n < NCAPS) {
#pragma unroll
      for (int tm = 0; tm < 4; tm++) {
        int f0 = fb + tm * 16;
        float4 v;
        v.x = acc[tm][tn][0] + bias3[f0 + 0];
        v.y = acc[tm][tn][1] + bias3[f0 + 1];
        v.z = acc[tm][tn][2] + bias3[f0 + 2];
        v.w = acc[tm][tn][3] + bias3[f0 + 3];
        *(float4*)(z + n * 256 + f0) = v;
      }
    }
  }
}

// ============ caps section ============

__device__ __forceinline__ float dot8v(float4 a0, float4 a1, float4 b0, float4 b1) {
  float s = a0.x * b0.x;
  s = fmaf(a0.y, b0.y, s); s = fmaf(a0.z, b0.z, s); s = fmaf(a0.w, b0.w, s);
  s = fmaf(a1.x, b1.x, s); s = fmaf(a1.y, b1.y, s);
  s = fmaf(a1.z, b1.z, s); s = fmaf(a1.w, b1.w, s);
  return s;
}

__device__ __forceinline__ float dotrow(uint4 w, float4 ua, float4 ub) {
  float s = __uint_as_float(w.x << 16) * ua.x;
  s = fmaf(__uint_as_float(w.x & 0xffff0000u), ua.y, s);
  s = fmaf(__uint_as_float(w.y << 16), ua.z, s);
  s = fmaf(__uint_as_float(w.y & 0xffff0000u), ua.w, s);
  s = fmaf(__uint_as_float(w.z << 16), ub.x, s);
  s = fmaf(__uint_as_float(w.z & 0xffff0000u), ub.y, s);
  s = fmaf(__uint_as_float(w.w << 16), ub.z, s);
  s = fmaf(__uint_as_float(w.w & 0xffff0000u), ub.w, s);
  return s;
}

// ---- u (fp32 path, fallback): u[n][b*8+o] ----
__global__ void caps_u(const float* __restrict__ z, const float* __restrict__ pcw,
                       const float* __restrict__ pcb, float* __restrict__ u) {
  const int tid = threadIdx.x;
  const int b = tid >> 3, o = tid & 7;
  for (int k = 0; k < 8; k++) {
    const int n = blockIdx.x * 8 + k;
    const int g = n / NPIX, p = n % NPIX;
    const float* zp = z + (b * NPIX + p) * 256 + g * 8;
    float4 c0 = *(const float4*)zp;
    float4 c1 = *(const float4*)(zp + 4);
    const float* pw = pcw + n * 64 + o * 8;
    float4 w0 = *(const float4*)pw;
    float4 w1 = *(const float4*)(pw + 4);
    u[n * 256 + tid] = pcb[n * 8 + o] + dot8v(w0, w1, c0, c1);
  }
}

// ---- u packed bf16: u2[n][b][0..3] uints ----
__global__ void caps_u2(const float* __restrict__ z, const float* __restrict__ pcw,
                        const float* __restrict__ pcb, unsigned* __restrict__ u2) {
  const int tid = threadIdx.x;
  const int b = tid >> 3, o = tid & 7;
  for (int k = 0; k < 8; k++) {
    const int n = blockIdx.x * 8 + k;
    const int g = n / NPIX, p = n % NPIX;
    const float* zp = z + (b * NPIX + p) * 256 + g * 8;
    float4 c0 = *(const float4*)zp;
    float4 c1 = *(const float4*)(zp + 4);
    const float* pw = pcw + n * 64 + o * 8;
    float4 w0 = *(const float4*)pw;
    float4 w1 = *(const float4*)(pw + 4);
    const float myu = pcb[n * 8 + o] + dot8v(w0, w1, c0, c1);
    const float partner = __shfl_xor(myu, 1, 64);
    if (!(o & 1)) {
      unsigned pk = (unsigned)f2bf(myu) | ((unsigned)f2bf(partner) << 16);
      u2[n * 128 + b * 4 + (o >> 1)] = pk;
    }
  }
}

// ---- routing pass, LDS-staged bf16 W (conflict-free 272B e-row stride) ----
__global__ __launch_bounds__(256, 4) void caps_accb2(const unsigned* __restrict__ u2,
    const u16* __restrict__ Wbs, const float* __restrict__ vsum,
    float* __restrict__ Spart) {
  __shared__ u16 Ws[16 * 1088];
  const int tid = threadIdx.x;
  const int b = tid >> 3, e = tid & 7;
  const int n0 = blockIdx.x * 16;

  const u16* gsrc = Wbs + n0 * 1088;
#pragma unroll
  for (int k = 0; k < 9; k++) {
    const int idx = k * 256 + tid;
    if (idx < 2176) GLDS16(gsrc + idx * 8, Ws + idx * 8);
  }

  const float* vp = vsum + tid * 16;
  const float4 V0 = *(const float4*)vp;
  const float4 V1 = *(const float4*)(vp + 4);
  const float4 V2 = *(const float4*)(vp + 8);
  const float4 V3 = *(const float4*)(vp + 12);
  float s0 = 0.f, s1 = 0.f, s2 = 0.f, s3 = 0.f, s4 = 0.f, s5 = 0.f, s6 = 0.f, s7 = 0.f;
  float s8 = 0.f, s9 = 0.f, s10 = 0.f, s11 = 0.f, s12 = 0.f, s13 = 0.f, s14 = 0.f, s15 = 0.f;

  __syncthreads();

  for (int it = 0; it < 16; it++) {
    const int n = n0 + it;
    const uint4 up = *(const uint4*)(u2 + n * 128 + b * 4);
    float4 ua, ub;
    ua.x = __uint_as_float(up.x << 16); ua.y = __uint_as_float(up.x & 0xffff0000u);
    ua.z = __uint_as_float(up.y << 16); ua.w = __uint_as_float(up.y & 0xffff0000u);
    ub.x = __uint_as_float(up.z << 16); ub.y = __uint_as_float(up.z & 0xffff0000u);
    ub.z = __uint_as_float(up.w << 16); ub.w = __uint_as_float(up.w & 0xffff0000u);

    const u16* Wn = Ws + it * 1088 + e * 136;
    float h0, h1, h2, h3, h4, h5, h6, h7, h8, h9, h10, h11, h12, h13, h14, h15;
#define ROW(o, H) { uint4 w = *(const uint4*)(Wn + (o) * 8); H = dotrow(w, ua, ub); }
    ROW(0, h0)   ROW(1, h1)   ROW(2, h2)   ROW(3, h3)
    ROW(4, h4)   ROW(5, h5)   ROW(6, h6)   ROW(7, h7)
    ROW(8, h8)   ROW(9, h9)   ROW(10, h10) ROW(11, h11)
    ROW(12, h12) ROW(13, h13) ROW(14, h14) ROW(15, h15)
#undef ROW
    float blog = h0 * V0.x;
    blog = fmaf(h1, V0.y, blog);  blog = fmaf(h2, V0.z, blog);  blog = fmaf(h3, V0.w, blog);
    blog = fmaf(h4, V1.x, blog);  blog = fmaf(h5, V1.y, blog);  blog = fmaf(h6, V1.z, blog);
    blog = fmaf(h7, V1.w, blog);  blog = fmaf(h8, V2.x, blog);  blog = fmaf(h9, V2.y, blog);
    blog = fmaf(h10, V2.z, blog); blog = fmaf(h11, V2.w, blog); blog = fmaf(h12, V3.x, blog);
    blog = fmaf(h13, V3.y, blog); blog = fmaf(h14, V3.z, blog); blog = fmaf(h15, V3.w, blog);
    float m = blog;
    m = fmaxf(m, __shfl_xor(m, 1, 64));
    m = fmaxf(m, __shfl_xor(m, 2, 64));
    m = fmaxf(m, __shfl_xor(m, 4, 64));
    float ex = __expf(blog - m);
    float ss = ex;
    ss += __shfl_xor(ss, 1, 64);
    ss += __shfl_xor(ss, 2, 64);
    ss += __shfl_xor(ss, 4, 64);
    const float c = ex / ss;
    s0 = fmaf(c, h0, s0);   s1 = fmaf(c, h1, s1);   s2 = fmaf(c, h2, s2);   s3 = fmaf(c, h3, s3);
    s4 = fmaf(c, h4, s4);   s5 = fmaf(c, h5, s5);   s6 = fmaf(c, h6, s6);   s7 = fmaf(c, h7, s7);
    s8 = fmaf(c, h8, s8);   s9 = fmaf(c, h9, s9);   s10 = fmaf(c, h10, s10); s11 = fmaf(c, h11, s11);
    s12 = fmaf(c, h12, s12); s13 = fmaf(c, h13, s13); s14 = fmaf(c, h14, s14); s15 = fmaf(c, h15, s15);
  }
  float* Sp = Spart + blockIdx.x * 4096 + tid * 16;
  *(float4*)(Sp + 0)  = make_float4(s0, s1, s2, s3);
  *(float4*)(Sp + 4)  = make_float4(s4, s5, s6, s7);
  *(float4*)(Sp + 8)  = make_float4(s8, s9, s10, s11);
  *(float4*)(Sp + 12) = make_float4(s12, s13, s14, s15);
}

// ---- routing pass, fp32 W fallback ----
__global__ __launch_bounds__(256, 2) void caps_acc(const float* __restrict__ u,
    const float* __restrict__ W, const float* __restrict__ vsum,
    float* __restrict__ Spart) {
  const int tid = threadIdx.x;
  const int b = tid >> 3, e = tid & 7;
  const float* vp = vsum + tid * 16;
  const float4 V0 = *(const float4*)vp;
  const float4 V1 = *(const float4*)(vp + 4);
  const float4 V2 = *(const float4*)(vp + 8);
  const float4 V3 = *(const float4*)(vp + 12);
  float s0 = 0.f, s1 = 0.f, s2 = 0.f, s3 = 0.f, s4 = 0.f, s5 = 0.f, s6 = 0.f, s7 = 0.f;
  float s8 = 0.f, s9 = 0.f, s10 = 0.f, s11 = 0.f, s12 = 0.f, s13 = 0.f, s14 = 0.f, s15 = 0.f;
  const int n0 = blockIdx.x * 16;
  for (int it = 0; it < 16; it++) {
    const int n = n0 + it;
    const float* un = u + n * 256 + (b << 3);
    const float4 u0 = *(const float4*)un;
    const float4 u1 = *(const float4*)(un + 4);
    const float* Wn = W + n * 1024 + e * 128;
    float h0, h1, h2, h3, h4, h5, h6, h7, h8, h9, h10, h11, h12, h13, h14, h15;
#define OST(o, H) { float4 wa = *(const float4*)(Wn + (o) * 8); \
                    float4 wb = *(const float4*)(Wn + (o) * 8 + 4); \
                    H = dot8v(wa, wb, u0, u1); }
    OST(0, h0)  OST(1, h1)  OST(2, h2)  OST(3, h3)
    OST(4, h4)  OST(5, h5)  OST(6, h6)  OST(7, h7)
    OST(8, h8)  OST(9, h9)  OST(10, h10) OST(11, h11)
    OST(12, h12) OST(13, h13) OST(14, h14) OST(15, h15)
#undef OST
    float blog = h0 * V0.x;
    blog = fmaf(h1, V0.y, blog);  blog = fmaf(h2, V0.z, blog);  blog = fmaf(h3, V0.w, blog);
    blog = fmaf(h4, V1.x, blog);  blog = fmaf(h5, V1.y, blog);  blog = fmaf(h6, V1.z, blog);
    blog = fmaf(h7, V1.w, blog);  blog = fmaf(h8, V2.x, blog);  blog = fmaf(h9, V2.y, blog);
    blog = fmaf(h10, V2.z, blog); blog = fmaf(h11, V2.w, blog); blog = fmaf(h12, V3.x, blog);
    blog = fmaf(h13, V3.y, blog); blog = fmaf(h14, V3.z, blog); blog = fmaf(h15, V3.w, blog);
    float m = blog;
    m = fmaxf(m, __shfl_xor(m, 1, 64));
    m = fmaxf(m, __shfl_xor(m, 2, 64));
    m = fmaxf(m, __shfl_xor(m, 4, 64));
    float ex = __expf(blog - m);
    float ss = ex;
    ss += __shfl_xor(ss, 1, 64);
    ss += __shfl_xor(ss, 2, 64);
    ss += __shfl_xor(ss, 4, 64);
    const float c = ex / ss;
    s0 = fmaf(c, h0, s0);   s1 = fmaf(c, h1, s1);   s2 = fmaf(c, h2, s2);   s3 = fmaf(c, h3, s3);
    s4 = fmaf(c, h4, s4);   s5 = fmaf(c, h5, s5);   s6 = fmaf(c, h6, s6);   s7 = fmaf(c, h7, s7);
    s8 = fmaf(c, h8, s8);   s9 = fmaf(c, h9, s9);   s10 = fmaf(c, h10, s10); s11 = fmaf(c, h11, s11);
    s12 = fmaf(c, h12, s12); s13 = fmaf(c, h13, s13); s14 = fmaf(c, h14, s14); s15 = fmaf(c, h15, s15);
  }
  float* Sp = Spart + blockIdx.x * 4096 + tid * 16;
  *(float4*)(Sp + 0)  = make_float4(s0, s1, s2, s3);
  *(float4*)(Sp + 4)  = make_float4(s4, s5, s6, s7);
  *(float4*)(Sp + 8)  = make_float4(s8, s9, s10, s11);
  *(float4*)(Sp + 12) = make_float4(s12, s13, s14, s15);
}

// 1250 partials -> 25 partials (no atomics, no memset); grid (16,25)
__global__ void caps_redB(const float* __restrict__ Spart, float* __restrict__ Sp2) {
  const int j = blockIdx.x * 256 + threadIdx.x;
  const int r0 = blockIdx.y * 50;
  float a0 = 0.f, a1 = 0.f;
  for (int r = 0; r < 50; r += 2) {
    a0 += Spart[(r0 + r) * 4096 + j];
    a1 += Spart[(r0 + r + 1) * 4096 + j];
  }
  Sp2[blockIdx.y * 4096 + j] = a0 + a1;
}

// sum 25 partials -> squash -> vsum (set/add)
__global__ void caps_v2(const float* __restrict__ Sp2, float* __restrict__ vsum, int add) {
  const int t = threadIdx.x;
  float4 a0 = make_float4(0.f, 0.f, 0.f, 0.f), a1 = a0, a2 = a0, a3 = a0;
  for (int r = 0; r < 25; r++) {
    const float* sp = Sp2 + r * 4096 + t * 16;
    const float4 q0 = *(const float4*)sp;
    const float4 q1 = *(const float4*)(sp + 4);
    const float4 q2 = *(const float4*)(sp + 8);
    const float4 q3 = *(const float4*)(sp + 12);
    a0.x += q0.x; a0.y += q0.y; a0.z += q0.z; a0.w += q0.w;
    a1.x += q1.x; a1.y += q1.y; a1.z += q1.z; a1.w += q1.w;
    a2.x += q2.x; a2.y += q2.y; a2.z += q2.z; a2.w += q2.w;
    a3.x += q3.x; a3.y += q3.y; a3.z += q3.z; a3.w += q3.w;
  }
  float n2 = a0.x * a0.x;
  n2 = fmaf(a0.y, a0.y, n2); n2 = fmaf(a0.z, a0.z, n2); n2 = fmaf(a0.w, a0.w, n2);
  n2 = fmaf(a1.x, a1.x, n2); n2 = fmaf(a1.y, a1.y, n2); n2 = fmaf(a1.z, a1.z, n2); n2 = fmaf(a1.w, a1.w, n2);
  n2 = fmaf(a2.x, a2.x, n2); n2 = fmaf(a2.y, a2.y, n2); n2 = fmaf(a2.z, a2.z, n2); n2 = fmaf(a2.w, a2.w, n2);
  n2 = fmaf(a3.x, a3.x, n2); n2 = fmaf(a3.y, a3.y, n2); n2 = fmaf(a3.z, a3.z, n2); n2 = fmaf(a3.w, a3.w, n2);
  const float n = sqrtf(n2);
  const float scale = n2 / ((1.f + n2) * (n + 1e-8f));
  float* vp = vsum + t * 16;
  float4 o0, o1, o2, o3;
  if (add) {
    o0 = *(float4*)(vp + 0); o1 = *(float4*)(vp + 4); o2 = *(float4*)(vp + 8); o3 = *(float4*)(vp + 12);
  } else {
    o0 = make_float4(0.f, 0.f, 0.f, 0.f); o1 = o0; o2 = o0; o3 = o0;
  }
  o0.x = fmaf(a0.x, scale, o0.x); o0.y = fmaf(a0.y, scale, o0.y);
  o0.z = fmaf(a0.z, scale, o0.z); o0.w = fmaf(a0.w, scale, o0.w);
  o1.x = fmaf(a1.x, scale, o1.x); o1.y = fmaf(a1.y, scale, o1.y);
  o1.z = fmaf(a1.z, scale, o1.z); o1.w = fmaf(a1.w, scale, o1.w);
  o2.x = fmaf(a2.x, scale, o2.x); o2.y = fmaf(a2.y, scale, o2.y);
  o2.z = fmaf(a2.z, scale, o2.z); o2.w = fmaf(a2.w, scale, o2.w);
  o3.x = fmaf(a3.x, scale, o3.x); o3.y = fmaf(a3.y, scale, o3.y);
  o3.z = fmaf(a3.z, scale, o3.z); o3.w = fmaf(a3.w, scale, o3.w);
  *(float4*)(vp + 0) = o0; *(float4*)(vp + 4) = o1;
  *(float4*)(vp + 8) = o2; *(float4*)(vp + 12) = o3;
}

// sum 25 partials -> out = ||squash(S)||
__global__ void caps_out2(const float* __restrict__ Sp2, float* __restrict__ out) {
  const int t = threadIdx.x;
  float4 a0 = make_float4(0.f, 0.f, 0.f, 0.f), a1 = a0, a2 = a0, a3 = a0;
  for (int r = 0; r < 25; r++) {
    const float* sp = Sp2 + r * 4096 + t * 16;
    const float4 q0 = *(const float4*)sp;
    const float4 q1 = *(const float4*)(sp + 4);
    const float4 q2 = *(const float4*)(sp + 8);
    const float4 q3 = *(const float4*)(sp + 12);
    a0.x += q0.x; a0.y += q0.y; a0.z += q0.z; a0.w += q0.w;
    a1.x += q1.x; a1.y += q1.y; a1.z += q1.z; a1.w += q1.w;
    a2.x += q2.x; a2.y += q2.y; a2.z += q2.z; a2.w += q2.w;
    a3.x += q3.x; a3.y += q3.y; a3.z += q3.z; a3.w += q3.w;
  }
  float n2 = a0.x * a0.x;
  n2 = fmaf(a0.y, a0.y, n2); n2 = fmaf(a0.z, a0.z, n2); n2 = fmaf(a0.w, a0.w, n2);
  n2 = fmaf(a1.x, a1.x, n2); n2 = fmaf(a1.y, a1.y, n2); n2 = fmaf(a1.z, a1.z, n2); n2 = fmaf(a1.w, a1.w, n2);
  n2 = fmaf(a2.x, a2.x, n2); n2 = fmaf(a2.y, a2.y, n2); n2 = fmaf(a2.z, a2.z, n2); n2 = fmaf(a2.w, a2.w, n2);
  n2 = fmaf(a3.x, a3.x, n2); n2 = fmaf(a3.y, a3.y, n2); n2 = fmaf(a3.z, a3.z, n2); n2 = fmaf(a3.w, a3.w, n2);
  const float n = sqrtf(n2);
  out[t] = n * n2 / ((1.f + n2) * (n + 1e-8f));
}

// atomic variant for fp32 fallback path (needs S memset)
__global__ void caps_redA(const float* __restrict__ Spart, float* __restrict__ S) {
  const int j = blockIdx.x * 256 + threadIdx.x;
  const int r0 = blockIdx.y * 50;
  float a0 = 0.f, a1 = 0.f;
  for (int r = 0; r < 50; r += 2) {
    a0 += Spart[(r0 + r) * 4096 + j];
    a1 += Spart[(r0 + r + 1) * 4096 + j];
  }
  atomicAdd(&S[j], a0 + a1);
}

__global__ void caps_v(const float* __restrict__ S, float* __restrict__ vsum, int add) {
  const int t = threadIdx.x;
  const float* sp = S + t * 16;
  const float4 a0 = *(const float4*)sp;
  const float4 a1 = *(const float4*)(sp + 4);
  const float4 a2 = *(const float4*)(sp + 8);
  const float4 a3 = *(const float4*)(sp + 12);
  float n2 = a0.x * a0.x;
  n2 = fmaf(a0.y, a0.y, n2); n2 = fmaf(a0.z, a0.z, n2); n2 = fmaf(a0.w, a0.w, n2);
  n2 = fmaf(a1.x, a1.x, n2); n2 = fmaf(a1.y, a1.y, n2); n2 = fmaf(a1.z, a1.z, n2); n2 = fmaf(a1.w, a1.w, n2);
  n2 = fmaf(a2.x, a2.x, n2); n2 = fmaf(a2.y, a2.y, n2); n2 = fmaf(a2.z, a2.z, n2); n2 = fmaf(a2.w, a2.w, n2);
  n2 = fmaf(a3.x, a3.x, n2); n2 = fmaf(a3.y, a3.y, n2); n2 = fmaf(a3.z, a3.z, n2); n2 = fmaf(a3.w, a3.w, n2);
  const float n = sqrtf(n2);
  const float scale = n2 / ((1.f + n2) * (n + 1e-8f));
  float* vp = vsum + t * 16;
  float4 o0, o1, o2, o3;
  if (add) {
    o0 = *(float4*)(vp + 0); o1 = *(float4*)(vp + 4); o2 = *(float4*)(vp + 8); o3 = *(float4*)(vp + 12);
  } else {
    o0 = make_float4(0.f, 0.f, 0.f, 0.f); o1 = o0; o2 = o0; o3 = o0;
  }
  o0.x = fmaf(a0.x, scale, o0.x); o0.y = fmaf(a0.y, scale, o0.y);
  o0.z = fmaf(a0.z, scale, o0.z); o0.w = fmaf(a0.w, scale, o0.w);
  o1.x = fmaf(a1.x, scale, o1.x); o1.y = fmaf(a1.y, scale, o1.y);
  o1.z = fmaf(a1.z, scale, o1.z); o1.w = fmaf(a1.w, scale, o1.w);
  o2.x = fmaf(a2.x, scale, o2.x); o2.y = fmaf(a2.y, scale, o2.y);
  o2.z = fmaf(a2.z, scale, o2.z); o2.w = fmaf(a2.w, scale, o2.w);
  o3.x = fmaf(a3.x, scale, o3.x); o3.y = fmaf(a3.y, scale, o3.y);
  o3.z = fmaf(a3.z, scale, o3.z); o3.w = fmaf(a3.w, scale, o3.w);
  *(float4*)(vp + 0) = o0; *(float4*)(vp + 4) = o1;
  *(float4*)(vp + 8) = o2; *(float4*)(vp + 12) = o3;
}

__global__ void caps_out(const float* __restrict__ S, float* __restrict__ out) {
  const int t = threadIdx.x;
  const float* sp = S + t * 16;
  const float4 a0 = *(const float4*)sp;
  const float4 a1 = *(const float4*)(sp + 4);
  const float4 a2 = *(const float4*)(sp + 8);
  const float4 a3 = *(const float4*)(sp + 12);
  float n2 = a0.x * a0.x;
  n2 = fmaf(a0.y, a0.y, n2); n2 = fmaf(a0.z, a0.z, n2); n2 = fmaf(a0.w, a0.w, n2);
  n2 = fmaf(a1.x, a1.x, n2); n2 = fmaf(a1.y, a1.y, n2); n2 = fmaf(a1.z, a1.z, n2); n2 = fmaf(a1.w, a1.w, n2);
  n2 = fmaf(a2.x, a2.x, n2); n2 = fmaf(a2.y, a2.y, n2); n2 = fmaf(a2.z, a2.z, n2); n2 = fmaf(a2.w, a2.w, n2);
  n2 = fmaf(a3.x, a3.x, n2); n2 = fmaf(a3.y, a3.y, n2); n2 = fmaf(a3.z, a3.z, n2); n2 = fmaf(a3.w, a3.w, n2);
  const float n = sqrtf(n2);
  out[t] = n * n2 / ((1.f + n2) * (n + 1e-8f));
}

extern "C" void kernel_launch(void* const* d_in, const int* in_sizes, int n_in,
                              void* d_out, int out_size, void* d_ws, size_t ws_size,
                              hipStream_t stream) {
  const float* x   = (const float*)d_in[0];
  const float* w1  = (const float*)d_in[1];
  const float* b1  = (const float*)d_in[2];
  const float* w2  = (const float*)d_in[3];
  const float* b2  = (const float*)d_in[4];
  const float* w3  = (const float*)d_in[5];
  const float* b3  = (const float*)d_in[6];
  const float* pcw = (const float*)d_in[7];
  const float* pcb = (const float*)d_in[8];
  const float* W   = (const float*)d_in[9];
  float* out = (float*)d_out;

  char* ws = (char*)d_ws;
  const bool use_bf16w = (ws_size >= (size_t)75000000);

  u16*   x1p = (u16*)(ws + 0);           // 14,745,600
  u16*   A2  = (u16*)(ws + 14745600);    //  4,718,592 (combo-sliced layout)
  u16*   A3  = (u16*)(ws + 19464192);    //    262,144
  u16*   y   = (u16*)(ws + 19726336);    // 10,240,000  (ends 29,966,336)
  u16*   P   = (u16*)(ws + 29966336);    // 40,960,000 bf16 (dead after conv2_red)

  u16* Wbs;
  unsigned* u2;
  float *z, *Spart, *u, *S, *vs, *Sp2;
  if (use_bf16w) {
    Wbs   = (u16*)(ws + 0);              // 43,520,000 (written after conv3)
    z     = (float*)(ws + 43520000);     // 20,480,000
    Spart = (float*)(ws + 43520000);     // reuses z after caps_u2
    u2    = (unsigned*)(ws + 64000000);  // 10,240,000
    Sp2   = (float*)(ws + 74240000);     // 409,600 (25 x 16 KB)
    vs    = (float*)(ws + 74649600);     // 16,384
    u = nullptr; S = nullptr;
  } else {
    Wbs = nullptr; u2 = nullptr; Sp2 = nullptr;
    z     = (float*)(ws + 29966336);
    Spart = (float*)(ws + 29966336);
    u     = (float*)(ws + 50446336);
    S     = (float*)(ws + 70926336);
    vs    = (float*)(ws + 70942720);
  }

  hipMemsetAsync(x1p, 0, 14745600, stream);
  hipMemsetAsync(vs, 0, 16384, stream);

  prep_weights2<<<384, 256, 0, stream>>>(w2, w3, A2, A3);
  conv1_kernel<<<800, 256, 0, stream>>>(x, w1, b1, x1p);
  conv2_gemm<<<1256, 256, 0, stream>>>(A2, x1p, P);
  conv2_red<<<5000, 256, 0, stream>>>(P, b2, y);
  conv3_gemm<<<dim3(2, 157), 256, 0, stream>>>(A3, x1p, y, b3, z);
  if (use_bf16w) {
    prep_wbs<<<10000, 256, 0, stream>>>(W, Wbs);
    caps_u2<<<2500, 256, 0, stream>>>(z, pcw, pcb, u2);
  } else {
    caps_u<<<2500, 256, 0, stream>>>(z, pcw, pcb, u);
  }

  for (int pass = 0; pass < 3; pass++) {
    if (use_bf16w) {
      caps_accb2<<<1250, 256, 0, stream>>>(u2, Wbs, vs, Spart);
      caps_redB<<<dim3(16, 25), 256, 0, stream>>>(Spart, Sp2);
      if (pass == 0)      caps_v2<<<1, 256, 0, stream>>>(Sp2, vs, 0);
      else if (pass == 1) caps_v2<<<1, 256, 0, stream>>>(Sp2, vs, 1);
      else                caps_out2<<<1, 256, 0, stream>>>(Sp2, out);
    } else {
      caps_acc<<<1250, 256, 0, stream>>>(u, W, vs, Spart);
      hipMemsetAsync(S, 0, 16384, stream);
      caps_redA<<<dim3(16, 25), 256, 0, stream>>>(Spart, S);
      if (pass == 0)      caps_v<<<1, 256, 0, stream>>>(S, vs, 0);
      else if (pass == 1) caps_v<<<1, 256, 0, stream>>>(S, vs, 1);
      else                caps_out<<<1, 256, 0, stream>>>(S, out);
    }
  }
}

// Round 11
// 454.138 us; speedup vs baseline: 5.0782x; 1.1093x over previous
//
#include <hip/hip_runtime.h>
#include <hip/hip_fp16.h>

typedef unsigned short u16;
typedef __attribute__((ext_vector_type(8))) short bf16x8;
typedef __attribute__((ext_vector_type(4))) float floatx4;
typedef __attribute__((ext_vector_type(2))) _Float16 half2v;

#define NPIX 625
#define NCAPS 20000
#define K2 9216

__device__ __forceinline__ u16 f2bf(float f) {
  unsigned u = __float_as_uint(f);
  return (u16)((u + 0x7fffu + ((u >> 16) & 1u)) >> 16);
}

__device__ __forceinline__ unsigned h16(float f) {
  union { _Float16 h; u16 b; } c;
  c.h = (_Float16)f;
  return (unsigned)c.b;
}

__device__ __forceinline__ half2v as_h2(unsigned u) {
  union { unsigned i; half2v h; } c;
  c.i = u;
  return c.h;
}

__device__ __forceinline__ float dot2f(unsigned a, unsigned b, float c) {
#if __has_builtin(__builtin_amdgcn_fdot2)
  return __builtin_amdgcn_fdot2(as_h2(a), as_h2(b), c, false);
#else
  half2v x = as_h2(a), y = as_h2(b);
  return fmaf((float)x[1], (float)y[1], fmaf((float)x[0], (float)y[0], c));
#endif
}

__device__ __forceinline__ float dotrow16(uint4 w, uint4 u) {
  float s = dot2f(w.x, u.x, 0.f);
  s = dot2f(w.y, u.y, s);
  s = dot2f(w.z, u.z, s);
  s = dot2f(w.w, u.w, s);
  return s;
}

__device__ __forceinline__ float dot8v(float4 a0, float4 a1, float4 b0, float4 b1) {
  float s = a0.x * b0.x;
  s = fmaf(a0.y, b0.y, s); s = fmaf(a0.z, b0.z, s); s = fmaf(a0.w, b0.w, s);
  s = fmaf(a1.x, b1.x, s); s = fmaf(a1.y, b1.y, s);
  s = fmaf(a1.z, b1.z, s); s = fmaf(a1.w, b1.w, s);
  return s;
}

#define GLDS16(g, l) __builtin_amdgcn_global_load_lds( \
    (const __attribute__((address_space(1))) void*)(g), \
    (__attribute__((address_space(3))) void*)(l), 16, 0, 0)

// ---------- prep: w2 -> A2c[combo][row 128][2304] (combo = kt*2+mtile) ----------
__global__ void prep_weights2(const float* __restrict__ w2, const float* __restrict__ w3,
                              u16* __restrict__ A2c, u16* __restrict__ A3) {
  if (blockIdx.x < 256) {
    const int oc = blockIdx.x, c = threadIdx.x;
    const float* src = w2 + (oc * 256 + c) * 36;
    float v[36];
#pragma unroll
    for (int k = 0; k < 9; k++) {
      const float4 q = *(const float4*)(src + k * 4);
      v[k * 4 + 0] = q.x; v[k * 4 + 1] = q.y; v[k * 4 + 2] = q.z; v[k * 4 + 3] = q.w;
    }
    const int mtile = oc >> 7, row = oc & 127;
#pragma unroll
    for (int t = 0; t < 36; t++) {
      const int kt = t / 9, tl = t % 9;
      A2c[(kt * 2 + mtile) * 294912 + row * 2304 + tl * 256 + c] = f2bf(v[t]);
    }
  } else {
    const int j = (blockIdx.x - 256) * 1024 + threadIdx.x * 4;
    const float4 q = *(const float4*)(w3 + j);
    ushort4 p;
    p.x = f2bf(q.x); p.y = f2bf(q.y); p.z = f2bf(q.z); p.w = f2bf(q.w);
    *(ushort4*)(A3 + j) = p;
  }
}

// ---------- prep: routing W -> f16 swizzled+padded Wbs[n][e][136] ----------
__global__ void prep_wbs(const float* __restrict__ W, u16* __restrict__ Wbs) {
  int r = blockIdx.x * 256 + threadIdx.x;
  int n = r >> 7, eo = r & 127;
  int e = eo >> 4, o = eo & 15;
  const float* src = W + n * 1024 + eo * 8;
  const float4 v0 = *(const float4*)src;
  const float4 v1 = *(const float4*)(src + 4);
  u16* dst = Wbs + n * 1088 + e * 136 + o * 8;
  ushort4 p0, p1;
  p0.x = (u16)h16(v0.x); p0.y = (u16)h16(v0.y); p0.z = (u16)h16(v0.z); p0.w = (u16)h16(v0.w);
  p1.x = (u16)h16(v1.x); p1.y = (u16)h16(v1.y); p1.z = (u16)h16(v1.z); p1.w = (u16)h16(v1.w);
  *(ushort4*)dst = p0;
  *(ushort4*)(dst + 4) = p1;
}

// ---------- conv1: (B,1,54,54) -> x1p padded NHWC bf16 (B,30,30,256) ----------
__global__ void conv1_kernel(const float* __restrict__ x, const float* __restrict__ w1,
                             const float* __restrict__ b1, u16* __restrict__ x1p) {
  int blk = blockIdx.x;
  int b = blk / 25, i = blk % 25;
  int f = threadIdx.x;
  float wreg[36];
#pragma unroll
  for (int k = 0; k < 36; k++) wreg[k] = w1[f * 36 + k];
  float bias = b1[f];
  const float* xb = x + b * 54 * 54 + (2 * i) * 54;
  for (int j = 0; j < 25; j++) {
    float acc = bias;
#pragma unroll
    for (int ki = 0; ki < 6; ki++)
#pragma unroll
      for (int kj = 0; kj < 6; kj++)
        acc = fmaf(xb[ki * 54 + 2 * j + kj], wreg[ki * 6 + kj], acc);
    x1p[(((b * 30 + i + 2) * 30) + (j + 2)) * 256 + f] = f2bf(fmaxf(acc, 0.f));
  }
}

// ---------- conv2 implicit GEMM, split-K=4, bf16 partials, XCD-local ----------
__global__ __launch_bounds__(256) void conv2_gemm(const u16* __restrict__ A2c,
    const u16* __restrict__ x1p, u16* __restrict__ P) {
  __shared__ u16 As0[128 * 32];
  __shared__ u16 Bs0[128 * 32];
  __shared__ u16 As1[128 * 32];
  __shared__ u16 Bs1[128 * 32];
  const int tid = threadIdx.x;
  const int lane = tid & 63, wave = tid >> 6;
  const int f = blockIdx.x;
  const int w = (f & 7) * 157 + (f >> 3);
  const int ntile = w >> 3, combo = w & 7;
  const int kt = combo >> 1, mtile = combo & 1;
  const int t0 = kt * 9;

  const int seg0 = tid, seg1 = tid + 256;
  const u16* gA0 = A2c + combo * 294912 + (seg0 >> 2) * 2304 + (seg0 & 3) * 8;
  const u16* gA1 = A2c + combo * 294912 + (seg1 >> 2) * 2304 + (seg1 & 3) * 8;

  auto pixbase = [&](int seg) {
    int n = ntile * 128 + (seg >> 2);
    if (n > NCAPS - 1) n = NCAPS - 1;
    int b = n / NPIX, p = n % NPIX;
    int i = p / 25, j = p % 25;
    return ((b * 30 + i) * 30 + j) * 256 + (seg & 3) * 8;
  };
  const u16* gb0 = x1p + pixbase(seg0);
  const u16* gb1 = x1p + pixbase(seg1);

  floatx4 acc[4][4] = {};
  const int wm = wave & 1, wn = wave >> 1;
  const int lrow = lane & 15, kgrp = lane >> 4;

  int kj = t0 % 6;
  int boff = ((t0 / 6) * 30 + kj) * 256;
  for (int t = 0; t < 9; t++) {
#pragma unroll 1
    for (int cc = 0; cc < 8; cc += 2) {
      const int b0 = boff + cc * 32;
      GLDS16(gA0, As0 + seg0 * 8);
      GLDS16(gA1, As0 + seg1 * 8);
      GLDS16(gA0 + 32, As1 + seg0 * 8);
      GLDS16(gA1 + 32, As1 + seg1 * 8);
      GLDS16(gb0 + b0, Bs0 + seg0 * 8);
      GLDS16(gb1 + b0, Bs0 + seg1 * 8);
      GLDS16(gb0 + b0 + 32, Bs1 + seg0 * 8);
      GLDS16(gb1 + b0 + 32, Bs1 + seg1 * 8);
      gA0 += 64; gA1 += 64;
      __syncthreads();
      bf16x8 af[4], bfr[4];
#pragma unroll
      for (int tt = 0; tt < 4; tt++) {
        af[tt]  = *(const bf16x8*)(As0 + (wm * 64 + tt * 16 + lrow) * 32 + kgrp * 8);
        bfr[tt] = *(const bf16x8*)(Bs0 + (wn * 64 + tt * 16 + lrow) * 32 + kgrp * 8);
      }
#pragma unroll
      for (int tm = 0; tm < 4; tm++)
#pragma unroll
        for (int tn = 0; tn < 4; tn++)
          acc[tm][tn] = __builtin_amdgcn_mfma_f32_16x16x32_bf16(af[tm], bfr[tn], acc[tm][tn], 0, 0, 0);
#pragma unroll
      for (int tt = 0; tt < 4; tt++) {
        af[tt]  = *(const bf16x8*)(As1 + (wm * 64 + tt * 16 + lrow) * 32 + kgrp * 8);
        bfr[tt] = *(const bf16x8*)(Bs1 + (wn * 64 + tt * 16 + lrow) * 32 + kgrp * 8);
      }
#pragma unroll
      for (int tm = 0; tm < 4; tm++)
#pragma unroll
        for (int tn = 0; tn < 4; tn++)
          acc[tm][tn] = __builtin_amdgcn_mfma_f32_16x16x32_bf16(af[tm], bfr[tn], acc[tm][tn], 0, 0, 0);
      __syncthreads();
    }
    boff += 256;
    kj++;
    if (kj == 6) { kj = 0; boff += 6144; }
  }

  u16* Pk = P + kt * 5120000;
  const int nb = ntile * 128 + wn * 64;
  const int ocb = mtile * 128 + wm * 64 + kgrp * 4;
#pragma unroll
  for (int tn = 0; tn < 4; tn++) {
    int n = nb + tn * 16 + lrow;
    if (n < NCAPS) {
#pragma unroll
      for (int tm = 0; tm < 4; tm++) {
        int oc = ocb + tm * 16;
        ushort4 pk;
        pk.x = f2bf(acc[tm][tn][0]);
        pk.y = f2bf(acc[tm][tn][1]);
        pk.z = f2bf(acc[tm][tn][2]);
        pk.w = f2bf(acc[tm][tn][3]);
        *(ushort4*)(Pk + n * 256 + oc) = pk;
      }
    }
  }
}

// ---------- conv2 split-K reduce: y = bf16(relu(sum P[0..3] + bias)) ----------
__global__ void conv2_red(const u16* __restrict__ P, const float* __restrict__ bias2,
                          u16* __restrict__ y) {
  const int idx = blockIdx.x * 256 + threadIdx.x;
  const ushort4 p0 = *(const ushort4*)(P + idx * 4);
  const ushort4 p1 = *(const ushort4*)(P + 5120000 + idx * 4);
  const ushort4 p2 = *(const ushort4*)(P + 10240000 + idx * 4);
  const ushort4 p3 = *(const ushort4*)(P + 15360000 + idx * 4);
  const float4 bs = *(const float4*)(bias2 + ((idx * 4) & 255));
  auto bf = [](unsigned v) { return __uint_as_float(v << 16); };
  float sx = bf(p0.x) + bf(p1.x) + bf(p2.x) + bf(p3.x) + bs.x;
  float sy = bf(p0.y) + bf(p1.y) + bf(p2.y) + bf(p3.y) + bs.y;
  float sz = bf(p0.z) + bf(p1.z) + bf(p2.z) + bf(p3.z) + bs.z;
  float sw = bf(p0.w) + bf(p1.w) + bf(p2.w) + bf(p3.w) + bs.w;
  ushort4 pk;
  pk.x = f2bf(fmaxf(sx, 0.f));
  pk.y = f2bf(fmaxf(sy, 0.f));
  pk.z = f2bf(fmaxf(sz, 0.f));
  pk.w = f2bf(fmaxf(sw, 0.f));
  *(ushort4*)(y + idx * 4) = pk;
}

// ---------- conv3 1x1 GEMM, split-K=2 (kt0: x1 half, kt1: y half) ----------
// grid (2 mtile, 157 ntile, 2 kt) = 628 blocks; bf16 partials P3 (no bias —
// bias3 added in caps_u2, which also does the split-K sum).
__global__ __launch_bounds__(256) void conv3_gemm(const u16* __restrict__ A3,
    const u16* __restrict__ x1p, const u16* __restrict__ y, u16* __restrict__ P3) {
  __shared__ u16 As[128 * 32];
  __shared__ u16 Bs[128 * 32];
  const int tid = threadIdx.x;
  const int lane = tid & 63, wave = tid >> 6;
  const int mtile = blockIdx.x, ntile = blockIdx.y, kt = blockIdx.z;

  const int seg0 = tid, seg1 = tid + 256;
  const u16* ga0 = A3 + (mtile * 128 + (seg0 >> 2)) * 512 + (seg0 & 3) * 8 + kt * 256;
  const u16* ga1 = A3 + (mtile * 128 + (seg1 >> 2)) * 512 + (seg1 & 3) * 8 + kt * 256;

  auto mkbase = [&](int seg) {
    int n = ntile * 128 + (seg >> 2);
    if (n > NCAPS - 1) n = NCAPS - 1;
    if (kt == 0) {
      int b = n / NPIX, p = n % NPIX;
      int i = p / 25, j = p % 25;
      return x1p + ((b * 30 + i + 2) * 30 + (j + 2)) * 256 + (seg & 3) * 8;
    }
    return y + n * 256 + (seg & 3) * 8;
  };
  const u16* gs0 = mkbase(seg0);
  const u16* gs1 = mkbase(seg1);

  floatx4 acc[4][4] = {};
  const int wm = wave & 1, wn = wave >> 1;
  const int lrow = lane & 15, kgrp = lane >> 4;

  for (int kc = 0; kc < 8; kc++) {
    GLDS16(ga0 + kc * 32, As + seg0 * 8);
    GLDS16(ga1 + kc * 32, As + seg1 * 8);
    GLDS16(gs0 + kc * 32, Bs + seg0 * 8);
    GLDS16(gs1 + kc * 32, Bs + seg1 * 8);
    __syncthreads();
    bf16x8 af[4], bfr[4];
#pragma unroll
    for (int tt = 0; tt < 4; tt++) {
      af[tt]  = *(const bf16x8*)(As + (wm * 64 + tt * 16 + lrow) * 32 + kgrp * 8);
      bfr[tt] = *(const bf16x8*)(Bs + (wn * 64 + tt * 16 + lrow) * 32 + kgrp * 8);
    }
#pragma unroll
    for (int tm = 0; tm < 4; tm++)
#pragma unroll
      for (int tn = 0; tn < 4; tn++)
        acc[tm][tn] = __builtin_amdgcn_mfma_f32_16x16x32_bf16(af[tm], bfr[tn], acc[tm][tn], 0, 0, 0);
    __syncthreads();
  }

  u16* Pk = P3 + kt * 5120000;
  const int nb = ntile * 128 + wn * 64;
  const int fb = mtile * 128 + wm * 64 + kgrp * 4;
#pragma unroll
  for (int tn = 0; tn < 4; tn++) {
    int n = nb + tn * 16 + lrow;
    if (n < NCAPS) {
#pragma unroll
      for (int tm = 0; tm < 4; tm++) {
        int f0 = fb + tm * 16;
        ushort4 pk;
        pk.x = f2bf(acc[tm][tn][0]);
        pk.y = f2bf(acc[tm][tn][1]);
        pk.z = f2bf(acc[tm][tn][2]);
        pk.w = f2bf(acc[tm][tn][3]);
        *(ushort4*)(Pk + n * 256 + f0) = pk;
      }
    }
  }
}

// ============ caps section ============

// ---- u: sum conv3 partials + bias3 -> caps -> u = pcb + caps.pcw, f16-packed ----
__global__ void caps_u2(const u16* __restrict__ P3, const float* __restrict__ b3,
                        const float* __restrict__ pcw, const float* __restrict__ pcb,
                        unsigned* __restrict__ u2) {
  const int tid = threadIdx.x;
  const int b = tid >> 3, o = tid & 7;
  for (int k = 0; k < 8; k++) {
    const int n = blockIdx.x * 8 + k;
    const int g = n / NPIX, p = n % NPIX;
    const u16* pa = P3 + ((b * NPIX + p) * 256 + g * 8);
    const uint4 qa = *(const uint4*)pa;
    const uint4 qb = *(const uint4*)(pa + 5120000);
    const float* bp = b3 + g * 8;
    const float4 bb0 = *(const float4*)bp;
    const float4 bb1 = *(const float4*)(bp + 4);
    float4 c0, c1;
    c0.x = __uint_as_float(qa.x << 16) + __uint_as_float(qb.x << 16) + bb0.x;
    c0.y = __uint_as_float(qa.x & 0xffff0000u) + __uint_as_float(qb.x & 0xffff0000u) + bb0.y;
    c0.z = __uint_as_float(qa.y << 16) + __uint_as_float(qb.y << 16) + bb0.z;
    c0.w = __uint_as_float(qa.y & 0xffff0000u) + __uint_as_float(qb.y & 0xffff0000u) + bb0.w;
    c1.x = __uint_as_float(qa.z << 16) + __uint_as_float(qb.z << 16) + bb1.x;
    c1.y = __uint_as_float(qa.z & 0xffff0000u) + __uint_as_float(qb.z & 0xffff0000u) + bb1.y;
    c1.z = __uint_as_float(qa.w << 16) + __uint_as_float(qb.w << 16) + bb1.z;
    c1.w = __uint_as_float(qa.w & 0xffff0000u) + __uint_as_float(qb.w & 0xffff0000u) + bb1.w;
    const float* pw = pcw + n * 64 + o * 8;
    float4 w0 = *(const float4*)pw;
    float4 w1 = *(const float4*)(pw + 4);
    const float myu = pcb[n * 8 + o] + dot8v(w0, w1, c0, c1);
    const float partner = __shfl_xor(myu, 1, 64);
    if (!(o & 1)) {
      unsigned pk = h16(myu) | (h16(partner) << 16);
      u2[n * 128 + b * 4 + (o >> 1)] = pk;
    }
  }
}

// ---- routing pass, LDS-staged f16 W, fdot2 inner product ----
__global__ __launch_bounds__(256, 4) void caps_accb2(const unsigned* __restrict__ u2,
    const u16* __restrict__ Wbs, const float* __restrict__ vsum,
    float* __restrict__ Spart) {
  __shared__ u16 Ws[16 * 1088];
  const int tid = threadIdx.x;
  const int b = tid >> 3, e = tid & 7;
  const int n0 = blockIdx.x * 16;

  const u16* gsrc = Wbs + n0 * 1088;
#pragma unroll
  for (int k = 0; k < 9; k++) {
    const int idx = k * 256 + tid;
    if (idx < 2176) GLDS16(gsrc + idx * 8, Ws + idx * 8);
  }

  const float* vp = vsum + tid * 16;
  const float4 V0 = *(const float4*)vp;
  const float4 V1 = *(const float4*)(vp + 4);
  const float4 V2 = *(const float4*)(vp + 8);
  const float4 V3 = *(const float4*)(vp + 12);
  float s0 = 0.f, s1 = 0.f, s2 = 0.f, s3 = 0.f, s4 = 0.f, s5 = 0.f, s6 = 0.f, s7 = 0.f;
  float s8 = 0.f, s9 = 0.f, s10 = 0.f, s11 = 0.f, s12 = 0.f, s13 = 0.f, s14 = 0.f, s15 = 0.f;

  __syncthreads();

  for (int it = 0; it < 16; it++) {
    const int n = n0 + it;
    const uint4 up = *(const uint4*)(u2 + n * 128 + b * 4);
    const u16* Wn = Ws + it * 1088 + e * 136;
    float h0, h1, h2, h3, h4, h5, h6, h7, h8, h9, h10, h11, h12, h13, h14, h15;
#define ROW(o, H) { uint4 w = *(const uint4*)(Wn + (o) * 8); H = dotrow16(w, up); }
    ROW(0, h0)   ROW(1, h1)   ROW(2, h2)   ROW(3, h3)
    ROW(4, h4)   ROW(5, h5)   ROW(6, h6)   ROW(7, h7)
    ROW(8, h8)   ROW(9, h9)   ROW(10, h10) ROW(11, h11)
    ROW(12, h12) ROW(13, h13) ROW(14, h14) ROW(15, h15)
#undef ROW
    float blog = h0 * V0.x;
    blog = fmaf(h1, V0.y, blog);  blog = fmaf(h2, V0.z, blog);  blog = fmaf(h3, V0.w, blog);
    blog = fmaf(h4, V1.x, blog);  blog = fmaf(h5, V1.y, blog);  blog = fmaf(h6, V1.z, blog);
    blog = fmaf(h7, V1.w, blog);  blog = fmaf(h8, V2.x, blog);  blog = fmaf(h9, V2.y, blog);
    blog = fmaf(h10, V2.z, blog); blog = fmaf(h11, V2.w, blog); blog = fmaf(h12, V3.x, blog);
    blog = fmaf(h13, V3.y, blog); blog = fmaf(h14, V3.z, blog); blog = fmaf(h15, V3.w, blog);
    float m = blog;
    m = fmaxf(m, __shfl_xor(m, 1, 64));
    m = fmaxf(m, __shfl_xor(m, 2, 64));
    m = fmaxf(m, __shfl_xor(m, 4, 64));
    float ex = __expf(blog - m);
    float ss = ex;
    ss += __shfl_xor(ss, 1, 64);
    ss += __shfl_xor(ss, 2, 64);
    ss += __shfl_xor(ss, 4, 64);
    const float c = ex / ss;
    s0 = fmaf(c, h0, s0);   s1 = fmaf(c, h1, s1);   s2 = fmaf(c, h2, s2);   s3 = fmaf(c, h3, s3);
    s4 = fmaf(c, h4, s4);   s5 = fmaf(c, h5, s5);   s6 = fmaf(c, h6, s6);   s7 = fmaf(c, h7, s7);
    s8 = fmaf(c, h8, s8);   s9 = fmaf(c, h9, s9);   s10 = fmaf(c, h10, s10); s11 = fmaf(c, h11, s11);
    s12 = fmaf(c, h12, s12); s13 = fmaf(c, h13, s13); s14 = fmaf(c, h14, s14); s15 = fmaf(c, h15, s15);
  }
  float* Sp = Spart + blockIdx.x * 4096 + tid * 16;
  *(float4*)(Sp + 0)  = make_float4(s0, s1, s2, s3);
  *(float4*)(Sp + 4)  = make_float4(s4, s5, s6, s7);
  *(float4*)(Sp + 8)  = make_float4(s8, s9, s10, s11);
  *(float4*)(Sp + 12) = make_float4(s12, s13, s14, s15);
}

// 1250 partials -> 25 partials (no atomics, no memset); grid (16,25)
__global__ void caps_redB(const float* __restrict__ Spart, float* __restrict__ Sp2) {
  const int j = blockIdx.x * 256 + threadIdx.x;
  const int r0 = blockIdx.y * 50;
  float a0 = 0.f, a1 = 0.f;
  for (int r = 0; r < 50; r += 2) {
    a0 += Spart[(r0 + r) * 4096 + j];
    a1 += Spart[(r0 + r + 1) * 4096 + j];
  }
  Sp2[blockIdx.y * 4096 + j] = a0 + a1;
}

// sum 25 partials -> squash -> vsum (set/add)
__global__ void caps_v2(const float* __restrict__ Sp2, float* __restrict__ vsum, int add) {
  const int t = threadIdx.x;
  float4 a0 = make_float4(0.f, 0.f, 0.f, 0.f), a1 = a0, a2 = a0, a3 = a0;
  for (int r = 0; r < 25; r++) {
    const float* sp = Sp2 + r * 4096 + t * 16;
    const float4 q0 = *(const float4*)sp;
    const float4 q1 = *(const float4*)(sp + 4);
    const float4 q2 = *(const float4*)(sp + 8);
    const float4 q3 = *(const float4*)(sp + 12);
    a0.x += q0.x; a0.y += q0.y; a0.z += q0.z; a0.w += q0.w;
    a1.x += q1.x; a1.y += q1.y; a1.z += q1.z; a1.w += q1.w;
    a2.x += q2.x; a2.y += q2.y; a2.z += q2.z; a2.w += q2.w;
    a3.x += q3.x; a3.y += q3.y; a3.z += q3.z; a3.w += q3.w;
  }
  float n2 = a0.x * a0.x;
  n2 = fmaf(a0.y, a0.y, n2); n2 = fmaf(a0.z, a0.z, n2); n2 = fmaf(a0.w, a0.w, n2);
  n2 = fmaf(a1.x, a1.x, n2); n2 = fmaf(a1.y, a1.y, n2); n2 = fmaf(a1.z, a1.z, n2); n2 = fmaf(a1.w, a1.w, n2);
  n2 = fmaf(a2.x, a2.x, n2); n2 = fmaf(a2.y, a2.y, n2); n2 = fmaf(a2.z, a2.z, n2); n2 = fmaf(a2.w, a2.w, n2);
  n2 = fmaf(a3.x, a3.x, n2); n2 = fmaf(a3.y, a3.y, n2); n2 = fmaf(a3.z, a3.z, n2); n2 = fmaf(a3.w, a3.w, n2);
  const float n = sqrtf(n2);
  const float scale = n2 / ((1.f + n2) * (n + 1e-8f));
  float* vp = vsum + t * 16;
  float4 o0, o1, o2, o3;
  if (add) {
    o0 = *(float4*)(vp + 0); o1 = *(float4*)(vp + 4); o2 = *(float4*)(vp + 8); o3 = *(float4*)(vp + 12);
  } else {
    o0 = make_float4(0.f, 0.f, 0.f, 0.f); o1 = o0; o2 = o0; o3 = o0;
  }
  o0.x = fmaf(a0.x, scale, o0.x); o0.y = fmaf(a0.y, scale, o0.y);
  o0.z = fmaf(a0.z, scale, o0.z); o0.w = fmaf(a0.w, scale, o0.w);
  o1.x = fmaf(a1.x, scale, o1.x); o1.y = fmaf(a1.y, scale, o1.y);
  o1.z = fmaf(a1.z, scale, o1.z); o1.w = fmaf(a1.w, scale, o1.w);
  o2.x = fmaf(a2.x, scale, o2.x); o2.y = fmaf(a2.y, scale, o2.y);
  o2.z = fmaf(a2.z, scale, o2.z); o2.w = fmaf(a2.w, scale, o2.w);
  o3.x = fmaf(a3.x, scale, o3.x); o3.y = fmaf(a3.y, scale, o3.y);
  o3.z = fmaf(a3.z, scale, o3.z); o3.w = fmaf(a3.w, scale, o3.w);
  *(float4*)(vp + 0) = o0; *(float4*)(vp + 4) = o1;
  *(float4*)(vp + 8) = o2; *(float4*)(vp + 12) = o3;
}

// sum 25 partials -> out = ||squash(S)||
__global__ void caps_out2(const float* __restrict__ Sp2, float* __restrict__ out) {
  const int t = threadIdx.x;
  float4 a0 = make_float4(0.f, 0.f, 0.f, 0.f), a1 = a0, a2 = a0, a3 = a0;
  for (int r = 0; r < 25; r++) {
    const float* sp = Sp2 + r * 4096 + t * 16;
    const float4 q0 = *(const float4*)sp;
    const float4 q1 = *(const float4*)(sp + 4);
    const float4 q2 = *(const float4*)(sp + 8);
    const float4 q3 = *(const float4*)(sp + 12);
    a0.x += q0.x; a0.y += q0.y; a0.z += q0.z; a0.w += q0.w;
    a1.x += q1.x; a1.y += q1.y; a1.z += q1.z; a1.w += q1.w;
    a2.x += q2.x; a2.y += q2.y; a2.z += q2.z; a2.w += q2.w;
    a3.x += q3.x; a3.y += q3.y; a3.z += q3.z; a3.w += q3.w;
  }
  float n2 = a0.x * a0.x;
  n2 = fmaf(a0.y, a0.y, n2); n2 = fmaf(a0.z, a0.z, n2); n2 = fmaf(a0.w, a0.w, n2);
  n2 = fmaf(a1.x, a1.x, n2); n2 = fmaf(a1.y, a1.y, n2); n2 = fmaf(a1.z, a1.z, n2); n2 = fmaf(a1.w, a1.w, n2);
  n2 = fmaf(a2.x, a2.x, n2); n2 = fmaf(a2.y, a2.y, n2); n2 = fmaf(a2.z, a2.z, n2); n2 = fmaf(a2.w, a2.w, n2);
  n2 = fmaf(a3.x, a3.x, n2); n2 = fmaf(a3.y, a3.y, n2); n2 = fmaf(a3.z, a3.z, n2); n2 = fmaf(a3.w, a3.w, n2);
  const float n = sqrtf(n2);
  out[t] = n * n2 / ((1.f + n2) * (n + 1e-8f));
}

extern "C" void kernel_launch(void* const* d_in, const int* in_sizes, int n_in,
                              void* d_out, int out_size, void* d_ws, size_t ws_size,
                              hipStream_t stream) {
  const float* x   = (const float*)d_in[0];
  const float* w1  = (const float*)d_in[1];
  const float* b1  = (const float*)d_in[2];
  const float* w2  = (const float*)d_in[3];
  const float* b2  = (const float*)d_in[4];
  const float* w3  = (const float*)d_in[5];
  const float* b3  = (const float*)d_in[6];
  const float* pcw = (const float*)d_in[7];
  const float* pcb = (const float*)d_in[8];
  const float* W   = (const float*)d_in[9];
  float* out = (float*)d_out;

  char* ws = (char*)d_ws;

  // Phase 1 (convs):
  u16*   x1p = (u16*)(ws + 0);           // 14,745,600 (dead after conv3)
  u16*   A2  = (u16*)(ws + 14745600);    //  4,718,592 (dead after conv2)
  u16*   A3  = (u16*)(ws + 19464192);    //    262,144 (dead after conv3)
  u16*   y   = (u16*)(ws + 19726336);    // 10,240,000 (dead after conv3)
  u16*   P   = (u16*)(ws + 29966336);    // 40,960,000 (dead after conv2_red)
  // Phase 2 (caps):
  u16*   P3  = (u16*)(ws + 43520000);    // 20,480,000 conv3 bf16 partials (in dead P tail)
  u16*   Wbs = (u16*)(ws + 0);           // 43,520,000 f16 (written after conv3)
  float* Spart = (float*)(ws + 43520000);// 20,480,000 (reuses P3 after caps_u2)
  unsigned* u2 = (unsigned*)(ws + 64000000); // 10,240,000
  float* Sp2 = (float*)(ws + 74240000);  // 409,600
  float* vs  = (float*)(ws + 74649600);  // 16,384

  hipMemsetAsync(x1p, 0, 14745600, stream);
  hipMemsetAsync(vs, 0, 16384, stream);

  prep_weights2<<<384, 256, 0, stream>>>(w2, w3, A2, A3);
  conv1_kernel<<<800, 256, 0, stream>>>(x, w1, b1, x1p);
  conv2_gemm<<<1256, 256, 0, stream>>>(A2, x1p, P);
  conv2_red<<<5000, 256, 0, stream>>>(P, b2, y);
  conv3_gemm<<<dim3(2, 157, 2), 256, 0, stream>>>(A3, x1p, y, P3);
  prep_wbs<<<10000, 256, 0, stream>>>(W, Wbs);
  caps_u2<<<2500, 256, 0, stream>>>(P3, b3, pcw, pcb, u2);

  for (int pass = 0; pass < 3; pass++) {
    caps_accb2<<<1250, 256, 0, stream>>>(u2, Wbs, vs, Spart);
    caps_redB<<<dim3(16, 25), 256, 0, stream>>>(Spart, Sp2);
    if (pass == 0)      caps_v2<<<1, 256, 0, stream>>>(Sp2, vs, 0);
    else if (pass == 1) caps_v2<<<1, 256, 0, stream>>>(Sp2, vs, 1);
    else                caps_out2<<<1, 256, 0, stream>>>(Sp2, out);
  }
}

// Round 13
// 446.658 us; speedup vs baseline: 5.1633x; 1.0167x over previous
//
#include <hip/hip_runtime.h>
#include <hip/hip_fp16.h>

typedef unsigned short u16;
typedef __attribute__((ext_vector_type(8))) short bf16x8;
typedef __attribute__((ext_vector_type(4))) float floatx4;
typedef __attribute__((ext_vector_type(2))) _Float16 half2v;

#define NPIX 625
#define NCAPS 20000
#define K2 9216

__device__ __forceinline__ u16 f2bf(float f) {
  unsigned u = __float_as_uint(f);
  return (u16)((u + 0x7fffu + ((u >> 16) & 1u)) >> 16);
}

__device__ __forceinline__ unsigned h16(float f) {
  union { _Float16 h; u16 b; } c;
  c.h = (_Float16)f;
  return (unsigned)c.b;
}

__device__ __forceinline__ half2v as_h2(unsigned u) {
  union { unsigned i; half2v h; } c;
  c.i = u;
  return c.h;
}

__device__ __forceinline__ float dot2f(unsigned a, unsigned b, float c) {
#if __has_builtin(__builtin_amdgcn_fdot2)
  return __builtin_amdgcn_fdot2(as_h2(a), as_h2(b), c, false);
#else
  half2v x = as_h2(a), y = as_h2(b);
  return fmaf((float)x[1], (float)y[1], fmaf((float)x[0], (float)y[0], c));
#endif
}

__device__ __forceinline__ float dotrow16(uint4 w, uint4 u) {
  float s = dot2f(w.x, u.x, 0.f);
  s = dot2f(w.y, u.y, s);
  s = dot2f(w.z, u.z, s);
  s = dot2f(w.w, u.w, s);
  return s;
}

__device__ __forceinline__ float dot8v(float4 a0, float4 a1, float4 b0, float4 b1) {
  float s = a0.x * b0.x;
  s = fmaf(a0.y, b0.y, s); s = fmaf(a0.z, b0.z, s); s = fmaf(a0.w, b0.w, s);
  s = fmaf(a1.x, b1.x, s); s = fmaf(a1.y, b1.y, s);
  s = fmaf(a1.z, b1.z, s); s = fmaf(a1.w, b1.w, s);
  return s;
}

#define GLDS16(g, l) __builtin_amdgcn_global_load_lds( \
    (const __attribute__((address_space(1))) void*)(g), \
    (__attribute__((address_space(3))) void*)(l), 16, 0, 0)

// ---------- merged: w2/w3 prep (blocks 0..383) + conv1 (blocks 384..1183) ----------
__global__ void prep_conv1(const float* __restrict__ w2, const float* __restrict__ w3,
                           u16* __restrict__ A2c, u16* __restrict__ A3,
                           const float* __restrict__ x, const float* __restrict__ w1,
                           const float* __restrict__ b1, u16* __restrict__ x1p) {
  if (blockIdx.x < 256) {
    const int oc = blockIdx.x, c = threadIdx.x;
    const float* src = w2 + (oc * 256 + c) * 36;
    float v[36];
#pragma unroll
    for (int k = 0; k < 9; k++) {
      const float4 q = *(const float4*)(src + k * 4);
      v[k * 4 + 0] = q.x; v[k * 4 + 1] = q.y; v[k * 4 + 2] = q.z; v[k * 4 + 3] = q.w;
    }
    const int mtile = oc >> 7, row = oc & 127;
#pragma unroll
    for (int t = 0; t < 36; t++) {
      const int kt = t / 9, tl = t % 9;
      A2c[(kt * 2 + mtile) * 294912 + row * 2304 + tl * 256 + c] = f2bf(v[t]);
    }
  } else if (blockIdx.x < 384) {
    const int j = (blockIdx.x - 256) * 1024 + threadIdx.x * 4;
    const float4 q = *(const float4*)(w3 + j);
    ushort4 p;
    p.x = f2bf(q.x); p.y = f2bf(q.y); p.z = f2bf(q.z); p.w = f2bf(q.w);
    *(ushort4*)(A3 + j) = p;
  } else {
    const int blk = blockIdx.x - 384;     // 800 = 32 b * 25 rows
    const int b = blk / 25, i = blk % 25;
    const int f = threadIdx.x;
    float wreg[36];
#pragma unroll
    for (int k = 0; k < 36; k++) wreg[k] = w1[f * 36 + k];
    float bias = b1[f];
    const float* xb = x + b * 54 * 54 + (2 * i) * 54;
    for (int j = 0; j < 25; j++) {
      float acc = bias;
#pragma unroll
      for (int ki = 0; ki < 6; ki++)
#pragma unroll
        for (int kj = 0; kj < 6; kj++)
          acc = fmaf(xb[ki * 54 + 2 * j + kj], wreg[ki * 6 + kj], acc);
      x1p[(((b * 30 + i + 2) * 30) + (j + 2)) * 256 + f] = f2bf(fmaxf(acc, 0.f));
    }
  }
}

// ---------- conv2 implicit GEMM, split-K=4, bf16 partials, XCD-local ----------
__global__ __launch_bounds__(256) void conv2_gemm(const u16* __restrict__ A2c,
    const u16* __restrict__ x1p, u16* __restrict__ P) {
  __shared__ u16 As0[128 * 32];
  __shared__ u16 Bs0[128 * 32];
  __shared__ u16 As1[128 * 32];
  __shared__ u16 Bs1[128 * 32];
  const int tid = threadIdx.x;
  const int lane = tid & 63, wave = tid >> 6;
  const int f = blockIdx.x;
  const int w = (f & 7) * 157 + (f >> 3);
  const int ntile = w >> 3, combo = w & 7;
  const int kt = combo >> 1, mtile = combo & 1;
  const int t0 = kt * 9;

  const int seg0 = tid, seg1 = tid + 256;
  const u16* gA0 = A2c + combo * 294912 + (seg0 >> 2) * 2304 + (seg0 & 3) * 8;
  const u16* gA1 = A2c + combo * 294912 + (seg1 >> 2) * 2304 + (seg1 & 3) * 8;

  auto pixbase = [&](int seg) {
    int n = ntile * 128 + (seg >> 2);
    if (n > NCAPS - 1) n = NCAPS - 1;
    int b = n / NPIX, p = n % NPIX;
    int i = p / 25, j = p % 25;
    return ((b * 30 + i) * 30 + j) * 256 + (seg & 3) * 8;
  };
  const u16* gb0 = x1p + pixbase(seg0);
  const u16* gb1 = x1p + pixbase(seg1);

  floatx4 acc[4][4] = {};
  const int wm = wave & 1, wn = wave >> 1;
  const int lrow = lane & 15, kgrp = lane >> 4;

  int kj = t0 % 6;
  int boff = ((t0 / 6) * 30 + kj) * 256;
  for (int t = 0; t < 9; t++) {
#pragma unroll 1
    for (int cc = 0; cc < 8; cc += 2) {
      const int b0 = boff + cc * 32;
      GLDS16(gA0, As0 + seg0 * 8);
      GLDS16(gA1, As0 + seg1 * 8);
      GLDS16(gA0 + 32, As1 + seg0 * 8);
      GLDS16(gA1 + 32, As1 + seg1 * 8);
      GLDS16(gb0 + b0, Bs0 + seg0 * 8);
      GLDS16(gb1 + b0, Bs0 + seg1 * 8);
      GLDS16(gb0 + b0 + 32, Bs1 + seg0 * 8);
      GLDS16(gb1 + b0 + 32, Bs1 + seg1 * 8);
      gA0 += 64; gA1 += 64;
      __syncthreads();
      bf16x8 af[4], bfr[4];
#pragma unroll
      for (int tt = 0; tt < 4; tt++) {
        af[tt]  = *(const bf16x8*)(As0 + (wm * 64 + tt * 16 + lrow) * 32 + kgrp * 8);
        bfr[tt] = *(const bf16x8*)(Bs0 + (wn * 64 + tt * 16 + lrow) * 32 + kgrp * 8);
      }
#pragma unroll
      for (int tm = 0; tm < 4; tm++)
#pragma unroll
        for (int tn = 0; tn < 4; tn++)
          acc[tm][tn] = __builtin_amdgcn_mfma_f32_16x16x32_bf16(af[tm], bfr[tn], acc[tm][tn], 0, 0, 0);
#pragma unroll
      for (int tt = 0; tt < 4; tt++) {
        af[tt]  = *(const bf16x8*)(As1 + (wm * 64 + tt * 16 + lrow) * 32 + kgrp * 8);
        bfr[tt] = *(const bf16x8*)(Bs1 + (wn * 64 + tt * 16 + lrow) * 32 + kgrp * 8);
      }
#pragma unroll
      for (int tm = 0; tm < 4; tm++)
#pragma unroll
        for (int tn = 0; tn < 4; tn++)
          acc[tm][tn] = __builtin_amdgcn_mfma_f32_16x16x32_bf16(af[tm], bfr[tn], acc[tm][tn], 0, 0, 0);
      __syncthreads();
    }
    boff += 256;
    kj++;
    if (kj == 6) { kj = 0; boff += 6144; }
  }

  u16* Pk = P + kt * 5120000;
  const int nb = ntile * 128 + wn * 64;
  const int ocb = mtile * 128 + wm * 64 + kgrp * 4;
#pragma unroll
  for (int tn = 0; tn < 4; tn++) {
    int n = nb + tn * 16 + lrow;
    if (n < NCAPS) {
#pragma unroll
      for (int tm = 0; tm < 4; tm++) {
        int oc = ocb + tm * 16;
        ushort4 pk;
        pk.x = f2bf(acc[tm][tn][0]);
        pk.y = f2bf(acc[tm][tn][1]);
        pk.z = f2bf(acc[tm][tn][2]);
        pk.w = f2bf(acc[tm][tn][3]);
        *(ushort4*)(Pk + n * 256 + oc) = pk;
      }
    }
  }
}

// ---------- conv2 split-K reduce: y = bf16(relu(sum P[0..3] + bias)) ----------
__global__ void conv2_red(const u16* __restrict__ P, const float* __restrict__ bias2,
                          u16* __restrict__ y) {
  const int idx = blockIdx.x * 256 + threadIdx.x;
  const ushort4 p0 = *(const ushort4*)(P + idx * 4);
  const ushort4 p1 = *(const ushort4*)(P + 5120000 + idx * 4);
  const ushort4 p2 = *(const ushort4*)(P + 10240000 + idx * 4);
  const ushort4 p3 = *(const ushort4*)(P + 15360000 + idx * 4);
  const float4 bs = *(const float4*)(bias2 + ((idx * 4) & 255));
  auto bf = [](unsigned v) { return __uint_as_float(v << 16); };
  float sx = bf(p0.x) + bf(p1.x) + bf(p2.x) + bf(p3.x) + bs.x;
  float sy = bf(p0.y) + bf(p1.y) + bf(p2.y) + bf(p3.y) + bs.y;
  float sz = bf(p0.z) + bf(p1.z) + bf(p2.z) + bf(p3.z) + bs.z;
  float sw = bf(p0.w) + bf(p1.w) + bf(p2.w) + bf(p3.w) + bs.w;
  ushort4 pk;
  pk.x = f2bf(fmaxf(sx, 0.f));
  pk.y = f2bf(fmaxf(sy, 0.f));
  pk.z = f2bf(fmaxf(sz, 0.f));
  pk.w = f2bf(fmaxf(sw, 0.f));
  *(ushort4*)(y + idx * 4) = pk;
}

// ---------- conv3 1x1 GEMM, split-K=2 (kt0: x1 half, kt1: y half) ----------
__global__ __launch_bounds__(256) void conv3_gemm(const u16* __restrict__ A3,
    const u16* __restrict__ x1p, const u16* __restrict__ y, u16* __restrict__ P3) {
  __shared__ u16 As[128 * 32];
  __shared__ u16 Bs[128 * 32];
  const int tid = threadIdx.x;
  const int lane = tid & 63, wave = tid >> 6;
  const int mtile = blockIdx.x, ntile = blockIdx.y, kt = blockIdx.z;

  const int seg0 = tid, seg1 = tid + 256;
  const u16* ga0 = A3 + (mtile * 128 + (seg0 >> 2)) * 512 + (seg0 & 3) * 8 + kt * 256;
  const u16* ga1 = A3 + (mtile * 128 + (seg1 >> 2)) * 512 + (seg1 & 3) * 8 + kt * 256;

  auto mkbase = [&](int seg) {
    int n = ntile * 128 + (seg >> 2);
    if (n > NCAPS - 1) n = NCAPS - 1;
    if (kt == 0) {
      int b = n / NPIX, p = n % NPIX;
      int i = p / 25, j = p % 25;
      return x1p + ((b * 30 + i + 2) * 30 + (j + 2)) * 256 + (seg & 3) * 8;
    }
    return y + n * 256 + (seg & 3) * 8;
  };
  const u16* gs0 = mkbase(seg0);
  const u16* gs1 = mkbase(seg1);

  floatx4 acc[4][4] = {};
  const int wm = wave & 1, wn = wave >> 1;
  const int lrow = lane & 15, kgrp = lane >> 4;

  for (int kc = 0; kc < 8; kc++) {
    GLDS16(ga0 + kc * 32, As + seg0 * 8);
    GLDS16(ga1 + kc * 32, As + seg1 * 8);
    GLDS16(gs0 + kc * 32, Bs + seg0 * 8);
    GLDS16(gs1 + kc * 32, Bs + seg1 * 8);
    __syncthreads();
    bf16x8 af[4], bfr[4];
#pragma unroll
    for (int tt = 0; tt < 4; tt++) {
      af[tt]  = *(const bf16x8*)(As + (wm * 64 + tt * 16 + lrow) * 32 + kgrp * 8);
      bfr[tt] = *(const bf16x8*)(Bs + (wn * 64 + tt * 16 + lrow) * 32 + kgrp * 8);
    }
#pragma unroll
    for (int tm = 0; tm < 4; tm++)
#pragma unroll
      for (int tn = 0; tn < 4; tn++)
        acc[tm][tn] = __builtin_amdgcn_mfma_f32_16x16x32_bf16(af[tm], bfr[tn], acc[tm][tn], 0, 0, 0);
    __syncthreads();
  }

  u16* Pk = P3 + kt * 5120000;
  const int nb = ntile * 128 + wn * 64;
  const int fb = mtile * 128 + wm * 64 + kgrp * 4;
#pragma unroll
  for (int tn = 0; tn < 4; tn++) {
    int n = nb + tn * 16 + lrow;
    if (n < NCAPS) {
#pragma unroll
      for (int tm = 0; tm < 4; tm++) {
        int f0 = fb + tm * 16;
        ushort4 pk;
        pk.x = f2bf(acc[tm][tn][0]);
        pk.y = f2bf(acc[tm][tn][1]);
        pk.z = f2bf(acc[tm][tn][2]);
        pk.w = f2bf(acc[tm][tn][3]);
        *(ushort4*)(Pk + n * 256 + f0) = pk;
      }
    }
  }
}

// ---------- merged: W->f16 swizzle (blocks 0..9999) + u (blocks 10000..12499) ----------
__global__ void prep_caps(const float* __restrict__ W, u16* __restrict__ Wbs,
                          const u16* __restrict__ P3, const float* __restrict__ b3,
                          const float* __restrict__ pcw, const float* __restrict__ pcb,
                          unsigned* __restrict__ u2) {
  const int tid = threadIdx.x;
  if (blockIdx.x < 10000) {
    int r = blockIdx.x * 256 + tid;
    int n = r >> 7, eo = r & 127;
    int e = eo >> 4, o = eo & 15;
    const float* src = W + n * 1024 + eo * 8;
    const float4 v0 = *(const float4*)src;
    const float4 v1 = *(const float4*)(src + 4);
    u16* dst = Wbs + n * 1088 + e * 136 + o * 8;
    ushort4 p0, p1;
    p0.x = (u16)h16(v0.x); p0.y = (u16)h16(v0.y); p0.z = (u16)h16(v0.z); p0.w = (u16)h16(v0.w);
    p1.x = (u16)h16(v1.x); p1.y = (u16)h16(v1.y); p1.z = (u16)h16(v1.z); p1.w = (u16)h16(v1.w);
    *(ushort4*)dst = p0;
    *(ushort4*)(dst + 4) = p1;
  } else {
    const int blk = blockIdx.x - 10000;
    const int b = tid >> 3, o = tid & 7;
    for (int k = 0; k < 8; k++) {
      const int n = blk * 8 + k;
      const int g = n / NPIX, p = n % NPIX;
      const u16* pa = P3 + ((b * NPIX + p) * 256 + g * 8);
      const uint4 qa = *(const uint4*)pa;
      const uint4 qb = *(const uint4*)(pa + 5120000);
      const float* bp = b3 + g * 8;
      const float4 bb0 = *(const float4*)bp;
      const float4 bb1 = *(const float4*)(bp + 4);
      float4 c0, c1;
      c0.x = __uint_as_float(qa.x << 16) + __uint_as_float(qb.x << 16) + bb0.x;
      c0.y = __uint_as_float(qa.x & 0xffff0000u) + __uint_as_float(qb.x & 0xffff0000u) + bb0.y;
      c0.z = __uint_as_float(qa.y << 16) + __uint_as_float(qb.y << 16) + bb0.z;
      c0.w = __uint_as_float(qa.y & 0xffff0000u) + __uint_as_float(qb.y & 0xffff0000u) + bb0.w;
      c1.x = __uint_as_float(qa.z << 16) + __uint_as_float(qb.z << 16) + bb1.x;
      c1.y = __uint_as_float(qa.z & 0xffff0000u) + __uint_as_float(qb.z & 0xffff0000u) + bb1.y;
      c1.z = __uint_as_float(qa.w << 16) + __uint_as_float(qb.w << 16) + bb1.z;
      c1.w = __uint_as_float(qa.w & 0xffff0000u) + __uint_as_float(qb.w & 0xffff0000u) + bb1.w;
      const float* pw = pcw + n * 64 + o * 8;
      float4 w0 = *(const float4*)pw;
      float4 w1 = *(const float4*)(pw + 4);
      const float myu = pcb[n * 8 + o] + dot8v(w0, w1, c0, c1);
      const float partner = __shfl_xor(myu, 1, 64);
      if (!(o & 1)) {
        unsigned pk = h16(myu) | (h16(partner) << 16);
        u2[n * 128 + b * 4 + (o >> 1)] = pk;
      }
    }
  }
}

// ---- routing pass, LDS-staged f16 W, fdot2; zero_v=1 -> c == 1/8 exactly ----
__global__ __launch_bounds__(256, 4) void caps_accb2(const unsigned* __restrict__ u2,
    const u16* __restrict__ Wbs, const float* __restrict__ vsum,
    float* __restrict__ Spart, int zero_v) {
  __shared__ u16 Ws[16 * 1088];
  const int tid = threadIdx.x;
  const int b = tid >> 3, e = tid & 7;
  const int n0 = blockIdx.x * 16;

  const u16* gsrc = Wbs + n0 * 1088;
#pragma unroll
  for (int k = 0; k < 9; k++) {
    const int idx = k * 256 + tid;
    if (idx < 2176) GLDS16(gsrc + idx * 8, Ws + idx * 8);
  }

  float4 V0 = make_float4(0.f, 0.f, 0.f, 0.f), V1 = V0, V2 = V0, V3 = V0;
  if (!zero_v) {
    const float* vp = vsum + tid * 16;
    V0 = *(const float4*)vp;
    V1 = *(const float4*)(vp + 4);
    V2 = *(const float4*)(vp + 8);
    V3 = *(const float4*)(vp + 12);
  }
  float s0 = 0.f, s1 = 0.f, s2 = 0.f, s3 = 0.f, s4 = 0.f, s5 = 0.f, s6 = 0.f, s7 = 0.f;
  float s8 = 0.f, s9 = 0.f, s10 = 0.f, s11 = 0.f, s12 = 0.f, s13 = 0.f, s14 = 0.f, s15 = 0.f;

  __syncthreads();

  for (int it = 0; it < 16; it++) {
    const int n = n0 + it;
    const uint4 up = *(const uint4*)(u2 + n * 128 + b * 4);
    const u16* Wn = Ws + it * 1088 + e * 136;
    float h0, h1, h2, h3, h4, h5, h6, h7, h8, h9, h10, h11, h12, h13, h14, h15;
#define ROW(o, H) { uint4 w = *(const uint4*)(Wn + (o) * 8); H = dotrow16(w, up); }
    ROW(0, h0)   ROW(1, h1)   ROW(2, h2)   ROW(3, h3)
    ROW(4, h4)   ROW(5, h5)   ROW(6, h6)   ROW(7, h7)
    ROW(8, h8)   ROW(9, h9)   ROW(10, h10) ROW(11, h11)
    ROW(12, h12) ROW(13, h13) ROW(14, h14) ROW(15, h15)
#undef ROW
    float c;
    if (zero_v) {
      c = 0.125f;
    } else {
      float blog = h0 * V0.x;
      blog = fmaf(h1, V0.y, blog);  blog = fmaf(h2, V0.z, blog);  blog = fmaf(h3, V0.w, blog);
      blog = fmaf(h4, V1.x, blog);  blog = fmaf(h5, V1.y, blog);  blog = fmaf(h6, V1.z, blog);
      blog = fmaf(h7, V1.w, blog);  blog = fmaf(h8, V2.x, blog);  blog = fmaf(h9, V2.y, blog);
      blog = fmaf(h10, V2.z, blog); blog = fmaf(h11, V2.w, blog); blog = fmaf(h12, V3.x, blog);
      blog = fmaf(h13, V3.y, blog); blog = fmaf(h14, V3.z, blog); blog = fmaf(h15, V3.w, blog);
      float m = blog;
      m = fmaxf(m, __shfl_xor(m, 1, 64));
      m = fmaxf(m, __shfl_xor(m, 2, 64));
      m = fmaxf(m, __shfl_xor(m, 4, 64));
      float ex = __expf(blog - m);
      float ss = ex;
      ss += __shfl_xor(ss, 1, 64);
      ss += __shfl_xor(ss, 2, 64);
      ss += __shfl_xor(ss, 4, 64);
      c = ex / ss;
    }
    s0 = fmaf(c, h0, s0);   s1 = fmaf(c, h1, s1);   s2 = fmaf(c, h2, s2);   s3 = fmaf(c, h3, s3);
    s4 = fmaf(c, h4, s4);   s5 = fmaf(c, h5, s5);   s6 = fmaf(c, h6, s6);   s7 = fmaf(c, h7, s7);
    s8 = fmaf(c, h8, s8);   s9 = fmaf(c, h9, s9);   s10 = fmaf(c, h10, s10); s11 = fmaf(c, h11, s11);
    s12 = fmaf(c, h12, s12); s13 = fmaf(c, h13, s13); s14 = fmaf(c, h14, s14); s15 = fmaf(c, h15, s15);
  }
  float* Sp = Spart + blockIdx.x * 4096 + tid * 16;
  *(float4*)(Sp + 0)  = make_float4(s0, s1, s2, s3);
  *(float4*)(Sp + 4)  = make_float4(s4, s5, s6, s7);
  *(float4*)(Sp + 8)  = make_float4(s8, s9, s10, s11);
  *(float4*)(Sp + 12) = make_float4(s12, s13, s14, s15);
}

// 1250 partials -> 25 partials (no atomics, no memset); grid (16,25)
__global__ void caps_redB(const float* __restrict__ Spart, float* __restrict__ Sp2) {
  const int j = blockIdx.x * 256 + threadIdx.x;
  const int r0 = blockIdx.y * 50;
  float a0 = 0.f, a1 = 0.f;
  for (int r = 0; r < 50; r += 2) {
    a0 += Spart[(r0 + r) * 4096 + j];
    a1 += Spart[(r0 + r + 1) * 4096 + j];
  }
  Sp2[blockIdx.y * 4096 + j] = a0 + a1;
}

// sum 25 partials -> squash -> vsum (set/add)
__global__ void caps_v2(const float* __restrict__ Sp2, float* __restrict__ vsum, int add) {
  const int t = threadIdx.x;
  float4 a0 = make_float4(0.f, 0.f, 0.f, 0.f), a1 = a0, a2 = a0, a3 = a0;
  for (int r = 0; r < 25; r++) {
    const float* sp = Sp2 + r * 4096 + t * 16;
    const float4 q0 = *(const float4*)sp;
    const float4 q1 = *(const float4*)(sp + 4);
    const float4 q2 = *(const float4*)(sp + 8);
    const float4 q3 = *(const float4*)(sp + 12);
    a0.x += q0.x; a0.y += q0.y; a0.z += q0.z; a0.w += q0.w;
    a1.x += q1.x; a1.y += q1.y; a1.z += q1.z; a1.w += q1.w;
    a2.x += q2.x; a2.y += q2.y; a2.z += q2.z; a2.w += q2.w;
    a3.x += q3.x; a3.y += q3.y; a3.z += q3.z; a3.w += q3.w;
  }
  float n2 = a0.x * a0.x;
  n2 = fmaf(a0.y, a0.y, n2); n2 = fmaf(a0.z, a0.z, n2); n2 = fmaf(a0.w, a0.w, n2);
  n2 = fmaf(a1.x, a1.x, n2); n2 = fmaf(a1.y, a1.y, n2); n2 = fmaf(a1.z, a1.z, n2); n2 = fmaf(a1.w, a1.w, n2);
  n2 = fmaf(a2.x, a2.x, n2); n2 = fmaf(a2.y, a2.y, n2); n2 = fmaf(a2.z, a2.z, n2); n2 = fmaf(a2.w, a2.w, n2);
  n2 = fmaf(a3.x, a3.x, n2); n2 = fmaf(a3.y, a3.y, n2); n2 = fmaf(a3.z, a3.z, n2); n2 = fmaf(a3.w, a3.w, n2);
  const float n = sqrtf(n2);
  const float scale = n2 / ((1.f + n2) * (n + 1e-8f));
  float* vp = vsum + t * 16;
  float4 o0, o1, o2, o3;
  if (add) {
    o0 = *(float4*)(vp + 0); o1 = *(float4*)(vp + 4); o2 = *(float4*)(vp + 8); o3 = *(float4*)(vp + 12);
  } else {
    o0 = make_float4(0.f, 0.f, 0.f, 0.f); o1 = o0; o2 = o0; o3 = o0;
  }
  o0.x = fmaf(a0.x, scale, o0.x); o0.y = fmaf(a0.y, scale, o0.y);
  o0.z = fmaf(a0.z, scale, o0.z); o0.w = fmaf(a0.w, scale, o0.w);
  o1.x = fmaf(a1.x, scale, o1.x); o1.y = fmaf(a1.y, scale, o1.y);
  o1.z = fmaf(a1.z, scale, o1.z); o1.w = fmaf(a1.w, scale, o1.w);
  o2.x = fmaf(a2.x, scale, o2.x); o2.y = fmaf(a2.y, scale, o2.y);
  o2.z = fmaf(a2.z, scale, o2.z); o2.w = fmaf(a2.w, scale, o2.w);
  o3.x = fmaf(a3.x, scale, o3.x); o3.y = fmaf(a3.y, scale, o3.y);
  o3.z = fmaf(a3.z, scale, o3.z); o3.w = fmaf(a3.w, scale, o3.w);
  *(float4*)(vp + 0) = o0; *(float4*)(vp + 4) = o1;
  *(float4*)(vp + 8) = o2; *(float4*)(vp + 12) = o3;
}

// sum 25 partials -> out = ||squash(S)||
__global__ void caps_out2(const float* __restrict__ Sp2, float* __restrict__ out) {
  const int t = threadIdx.x;
  float4 a0 = make_float4(0.f, 0.f, 0.f, 0.f), a1 = a0, a2 = a0, a3 = a0;
  for (int r = 0; r < 25; r++) {
    const float* sp = Sp2 + r * 4096 + t * 16;
    const float4 q0 = *(const float4*)sp;
    const float4 q1 = *(const float4*)(sp + 4);
    const float4 q2 = *(const float4*)(sp + 8);
    const float4 q3 = *(const float4*)(sp + 12);
    a0.x += q0.x; a0.y += q0.y; a0.z += q0.z; a0.w += q0.w;
    a1.x += q1.x; a1.y += q1.y; a1.z += q1.z; a1.w += q1.w;
    a2.x += q2.x; a2.y += q2.y; a2.z += q2.z; a2.w += q2.w;
    a3.x += q3.x; a3.y += q3.y; a3.z += q3.z; a3.w += q3.w;
  }
  float n2 = a0.x * a0.x;
  n2 = fmaf(a0.y, a0.y, n2); n2 = fmaf(a0.z, a0.z, n2); n2 = fmaf(a0.w, a0.w, n2);
  n2 = fmaf(a1.x, a1.x, n2); n2 = fmaf(a1.y, a1.y, n2); n2 = fmaf(a1.z, a1.z, n2); n2 = fmaf(a1.w, a1.w, n2);
  n2 = fmaf(a2.x, a2.x, n2); n2 = fmaf(a2.y, a2.y, n2); n2 = fmaf(a2.z, a2.z, n2); n2 = fmaf(a2.w, a2.w, n2);
  n2 = fmaf(a3.x, a3.x, n2); n2 = fmaf(a3.y, a3.y, n2); n2 = fmaf(a3.z, a3.z, n2); n2 = fmaf(a3.w, a3.w, n2);
  const float n = sqrtf(n2);
  out[t] = n * n2 / ((1.f + n2) * (n + 1e-8f));
}

extern "C" void kernel_launch(void* const* d_in, const int* in_sizes, int n_in,
                              void* d_out, int out_size, void* d_ws, size_t ws_size,
                              hipStream_t stream) {
  const float* x   = (const float*)d_in[0];
  const float* w1  = (const float*)d_in[1];
  const float* b1  = (const float*)d_in[2];
  const float* w2  = (const float*)d_in[3];
  const float* b2  = (const float*)d_in[4];
  const float* w3  = (const float*)d_in[5];
  const float* b3  = (const float*)d_in[6];
  const float* pcw = (const float*)d_in[7];
  const float* pcb = (const float*)d_in[8];
  const float* W   = (const float*)d_in[9];
  float* out = (float*)d_out;

  char* ws = (char*)d_ws;

  // Phase 1 (convs):
  u16*   x1p = (u16*)(ws + 0);           // 14,745,600 (dead after conv3)
  u16*   A2  = (u16*)(ws + 14745600);    //  4,718,592 (dead after conv2)
  u16*   A3  = (u16*)(ws + 19464192);    //    262,144 (dead after conv3)
  u16*   y   = (u16*)(ws + 19726336);    // 10,240,000 (dead after conv3)
  u16*   P   = (u16*)(ws + 29966336);    // 40,960,000 (dead after conv2_red)
  // Phase 2 (caps):
  u16*   P3  = (u16*)(ws + 43520000);    // 20,480,000 conv3 bf16 partials
  u16*   Wbs = (u16*)(ws + 0);           // 43,520,000 f16 (written after conv3)
  float* Spart = (float*)(ws + 43520000);// 20,480,000 (reuses P3 after prep_caps)
  unsigned* u2 = (unsigned*)(ws + 64000000); // 10,240,000
  float* Sp2 = (float*)(ws + 74240000);  // 409,600
  float* vs  = (float*)(ws + 74649600);  // 16,384

  hipMemsetAsync(x1p, 0, 14745600, stream);

  prep_conv1<<<1184, 256, 0, stream>>>(w2, w3, A2, A3, x, w1, b1, x1p);
  conv2_gemm<<<1256, 256, 0, stream>>>(A2, x1p, P);
  conv2_red<<<5000, 256, 0, stream>>>(P, b2, y);
  conv3_gemm<<<dim3(2, 157, 2), 256, 0, stream>>>(A3, x1p, y, P3);
  prep_caps<<<12500, 256, 0, stream>>>(W, Wbs, P3, b3, pcw, pcb, u2);

  for (int pass = 0; pass < 3; pass++) {
    caps_accb2<<<1250, 256, 0, stream>>>(u2, Wbs, vs, Spart, pass == 0 ? 1 : 0);
    caps_redB<<<dim3(16, 25), 256, 0, stream>>>(Spart, Sp2);
    if (pass == 0)      caps_v2<<<1, 256, 0, stream>>>(Sp2, vs, 0);
    else if (pass == 1) caps_v2<<<1, 256, 0, stream>>>(Sp2, vs, 1);
    else                caps_out2<<<1, 256, 0, stream>>>(Sp2, out);
  }
}